// Round 10
// baseline (648.610 us; speedup 1.0000x reference)
//
#include <hip/hip_runtime.h>
#include <hip/hip_bf16.h>
#include <math.h>

#define DMODEL 256
#define KNB 32
#define NHEAD 8
#define FIN 95
#define FPD 95        // dense part of pair features
#define KPAD 104      // padded K for pair/feat MFMA staging
#define FOUT 1024
#define DHID 512
#define BTS 36        // BigT kk-stride (pad 32->36: 8B-aligned frags, no 16-way banks)
#define PRS 72        // pairR row stride (144B: 16B-aligned b128 frags)

typedef __hip_bfloat16 bf16;
typedef __attribute__((ext_vector_type(8))) short short8;
typedef __attribute__((ext_vector_type(4))) float floatx4;

__device__ inline float B2F(bf16 x) { return __bfloat162float(x); }
__device__ inline bf16 F2B(float x) { return __float2bfloat16(x); }
__device__ inline unsigned short f2bs(float x) {
    bf16 h = __float2bfloat16(x);
    return *reinterpret_cast<unsigned short*>(&h);
}
__device__ inline float bs2f(short s) {
    return __uint_as_float(((unsigned)(unsigned short)s) << 16);
}

// fast gelu: tanh(y) = 1 - 2/(1+e^{2y}); e^{2y} via __expf (v_exp)
__device__ inline float gelu_f(float x) {
    float u = 1.5957691216057308f * x * (1.f + 0.044715f * x * x);   // 2*0.79788456*(x+0.044715x^3)
    float t = 1.f - 2.f / (1.f + __expf(u));
    return 0.5f * x * (1.f + t);
}

// ---- weight transpose buffer layout (bf16 elements) ----
#define OFF_WALL 0          // [1344][256]  q|k|v|qp|kp|vp columns
#define OFF_WO   344064     // [256][1024]
#define OFF_WG   606208     // [512][256]
#define OFF_WVM  737280     // [512][256]
#define OFF_WOM  868352     // [256][512]
#define OFF_WP   999424     // [64][KPAD]
#define OFF_WIN  1006080    // [256][KPAD]  w_in transposed
#define OFF_WBM  1032704    // [16][64]     wbm transposed (heads 8..15 zero)
#define WT_TOTAL 1033728

// Kernel T: transpose/convert all weights to bf16 [n][k] (k-contiguous)
__global__ __launch_bounds__(256) void kT(const float* __restrict__ wq, const float* __restrict__ wk,
                                          const float* __restrict__ wv, const float* __restrict__ wqp,
                                          const float* __restrict__ wkp, const float* __restrict__ wvp,
                                          const float* __restrict__ wo, const float* __restrict__ wg,
                                          const float* __restrict__ wvm, const float* __restrict__ wom,
                                          const float* __restrict__ w_pair, const float* __restrict__ w_in,
                                          const float* __restrict__ wbm,
                                          unsigned short* __restrict__ wt) {
    int stride = gridDim.x * 256;
    for (int e = blockIdx.x * 256 + threadIdx.x; e < WT_TOTAL; e += stride) {
        float v;
        if (e < OFF_WO) {
            int n = e >> 8, k = e & 255;
            if (n < 256) v = wq[k * 256 + n];
            else if (n < 512) v = wk[k * 256 + n - 256];
            else if (n < 768) v = wv[k * 256 + n - 512];
            else if (n < 960) v = wqp[k * 192 + n - 768];
            else if (n < 1152) v = wkp[k * 192 + n - 960];
            else v = wvp[k * 192 + n - 1152];
        } else if (e < OFF_WG) {
            int u = e - OFF_WO; int n = u >> 10, k = u & 1023;
            v = wo[k * 256 + n];
        } else if (e < OFF_WVM) {
            int u = e - OFF_WG; int n = u >> 8, k = u & 255;
            v = wg[k * 512 + n];
        } else if (e < OFF_WOM) {
            int u = e - OFF_WVM; int n = u >> 8, k = u & 255;
            v = wvm[k * 512 + n];
        } else if (e < OFF_WP) {
            int u = e - OFF_WOM; int n = u >> 9, k = u & 511;
            v = wom[k * 256 + n];
        } else if (e < OFF_WIN) {
            int u = e - OFF_WP; int n = u / KPAD, k = u % KPAD;
            v = (k < FPD) ? w_pair[k * 64 + n] : 0.f;
        } else if (e < OFF_WBM) {
            int u = e - OFF_WIN; int n = u / KPAD, k = u % KPAD;
            v = (k < FIN) ? w_in[k * 256 + n] : 0.f;
        } else {
            int u = e - OFF_WBM; int n = u >> 6, k = u & 63;
            v = (n < NHEAD) ? wbm[k * 8 + n] : 0.f;
        }
        wt[e] = f2bs(v);
    }
}

// Kernel A1: frames + feat (bf16, 104-padded). 8 residues/block, 32 threads each.
__global__ __launch_bounds__(256) void kA1(const float* __restrict__ pos,
                                           float* __restrict__ Rw,
                                           float* __restrict__ lpw,
                                           unsigned short* __restrict__ featb) {
    int tid = threadIdx.x;
    int res = tid >> 5, lt = tid & 31;
    int ri = blockIdx.x * 8 + res;
    const float* pp = pos + (size_t)ri * 15;
    float nx = pp[0], ny = pp[1], nz = pp[2];
    float cax = pp[3], cay = pp[4], caz = pp[5];
    float cx = pp[6], cy = pp[7], cz = pp[8];
    float e1x = cx - cax, e1y = cy - cay, e1z = cz - caz;
    float inv = rsqrtf(e1x * e1x + e1y * e1y + e1z * e1z + 1e-6f);
    e1x *= inv; e1y *= inv; e1z *= inv;
    float ux = nx - cax, uy = ny - cay, uz = nz - caz;
    float d = ux * e1x + uy * e1y + uz * e1z;
    float wx = ux - d * e1x, wy = uy - d * e1y, wz = uz - d * e1z;
    inv = rsqrtf(wx * wx + wy * wy + wz * wz + 1e-6f);
    float e2x = wx * inv, e2y = wy * inv, e2z = wz * inv;
    float e3x = e1y * e2z - e1z * e2y;
    float e3y = e1z * e2x - e1x * e2z;
    float e3z = e1x * e2y - e1y * e2x;
    float R[9] = {e1x, e2x, e3x, e1y, e2y, e3y, e1z, e2z, e3z};

    __shared__ float lpS[8][15];
    __shared__ float ddS[8][5], dinvS[8][5];

    if (lt < 9) Rw[(size_t)ri * 9 + lt] = R[lt];
    if (lt < 15) {
        int a = lt / 3, ii = lt % 3;
        float px = pp[a * 3 + 0] - cax, py = pp[a * 3 + 1] - cay, pz = pp[a * 3 + 2] - caz;
        float v = R[0 * 3 + ii] * px + R[1 * 3 + ii] * py + R[2 * 3 + ii] * pz;
        lpS[res][lt] = v;
        lpw[(size_t)ri * 15 + lt] = v;
    }
    __syncthreads();
    if (lt < 5) {
        float s = lpS[res][lt * 3] * lpS[res][lt * 3] + lpS[res][lt * 3 + 1] * lpS[res][lt * 3 + 1] +
                  lpS[res][lt * 3 + 2] * lpS[res][lt * 3 + 2];
        ddS[res][lt] = sqrtf(s + 1e-12f);
        dinvS[res][lt] = rsqrtf(s + 1e-6f);
    }
    __syncthreads();
    for (int e = lt; e < KPAD; e += 32) {
        float v;
        if (e < 15) v = lpS[res][e] * dinvS[res][e / 3];
        else if (e < 95) {
            int u = e - 15, a = u >> 4, b = u & 15;
            float z = (ddS[res][a] - (float)b * (10.f / 15.f)) * (1.f / 0.625f);
            v = __expf(-z * z);
        } else v = 0.f;
        featb[(size_t)ri * KPAD + e] = f2bs(v);
    }
}

// Kernel B (v1): lup = local + feat@w_inT (MFMA) -> dlocal; LN1; 6 projections via MFMA. 32 rows/block.
__global__ __launch_bounds__(256) void kB(const float* __restrict__ local,
                                          const unsigned short* __restrict__ featb,
                                          const float* __restrict__ ln1_s,
                                          const float* __restrict__ ln1_o,
                                          const unsigned short* __restrict__ wAllT,
                                          const unsigned short* __restrict__ w_inT,
                                          float* __restrict__ dlocal,
                                          bf16* __restrict__ qbh, bf16* __restrict__ kvb,
                                          bf16* __restrict__ qpl, bf16* __restrict__ kpl,
                                          bf16* __restrict__ vpl) {
    int r0 = blockIdx.x * 32;
    int tid = threadIdx.x;
    __shared__ __align__(16) unsigned short featA[32 * KPAD];
    __shared__ __align__(16) unsigned short xbf[32 * 264];
    __shared__ float statsS[32 * 4];

    {
        const short8* src = reinterpret_cast<const short8*>(featb + (size_t)r0 * KPAD);
        short8* dst = reinterpret_cast<short8*>(featA);
        for (int c = tid; c < 32 * KPAD / 8; c += 256) dst[c] = src[c];
    }
    __syncthreads();

    int lane = tid & 63, w = tid >> 6;
    int mtile = w & 1, par = w >> 1;
    int m = lane & 15, quad = lane >> 4;

    short8 fa[3];
#pragma unroll
    for (int ks = 0; ks < 3; ks++)
        fa[ks] = *reinterpret_cast<const short8*>(&featA[(mtile * 16 + m) * KPAD + ks * 32 + quad * 8]);
    float lupv[8][4];
#pragma unroll
    for (int j = 0; j < 8; j++) {
        int nt = par + 2 * j;
        floatx4 c = {0.f, 0.f, 0.f, 0.f};
        const short8* bp = reinterpret_cast<const short8*>(w_inT + (size_t)(nt * 16 + m) * KPAD);
#pragma unroll
        for (int ks = 0; ks < 3; ks++)
            c = __builtin_amdgcn_mfma_f32_16x16x32_bf16(fa[ks], bp[ks * 4 + quad], c, 0, 0, 0);
        int col = nt * 16 + m;
#pragma unroll
        for (int r = 0; r < 4; r++) {
            int row = mtile * 16 + quad * 4 + r;
            float lv = local[(size_t)(r0 + row) * 256 + col] + c[r];
            lupv[j][r] = lv;
            dlocal[(size_t)(r0 + row) * 256 + col] = lv;
        }
    }
    {
        float s[4] = {0.f, 0.f, 0.f, 0.f}, ss[4] = {0.f, 0.f, 0.f, 0.f};
#pragma unroll
        for (int j = 0; j < 8; j++)
#pragma unroll
            for (int r = 0; r < 4; r++) { s[r] += lupv[j][r]; ss[r] += lupv[j][r] * lupv[j][r]; }
#pragma unroll
        for (int mask = 1; mask < 16; mask <<= 1)
#pragma unroll
            for (int r = 0; r < 4; r++) { s[r] += __shfl_xor(s[r], mask); ss[r] += __shfl_xor(ss[r], mask); }
        if (m == 0) {
#pragma unroll
            for (int r = 0; r < 4; r++) {
                int row = mtile * 16 + quad * 4 + r;
                statsS[row * 4 + par * 2 + 0] = s[r];
                statsS[row * 4 + par * 2 + 1] = ss[r];
            }
        }
    }
    __syncthreads();
    {
        float mu[4], rs_[4];
#pragma unroll
        for (int r = 0; r < 4; r++) {
            int row = mtile * 16 + quad * 4 + r;
            float S = statsS[row * 4 + 0] + statsS[row * 4 + 2];
            float SS = statsS[row * 4 + 1] + statsS[row * 4 + 3];
            float m_ = S * (1.f / 256.f);
            mu[r] = m_;
            rs_[r] = rsqrtf(SS * (1.f / 256.f) - m_ * m_ + 1e-5f);
        }
#pragma unroll
        for (int j = 0; j < 8; j++) {
            int col = (par + 2 * j) * 16 + m;
            float g = ln1_s[col], o = ln1_o[col];
#pragma unroll
            for (int r = 0; r < 4; r++) {
                int row = mtile * 16 + quad * 4 + r;
                xbf[row * 264 + col] = f2bs((lupv[j][r] - mu[r]) * rs_[r] * g + o);
            }
        }
    }
    __syncthreads();

    short8 afr[8];
#pragma unroll
    for (int ks = 0; ks < 8; ks++)
        afr[ks] = *reinterpret_cast<const short8*>(&xbf[(mtile * 16 + m) * 264 + ks * 32 + quad * 8]);
    for (int nt = par; nt < 84; nt += 2) {
        floatx4 c = {0.f, 0.f, 0.f, 0.f};
        const short8* bp = reinterpret_cast<const short8*>(wAllT + (size_t)(nt * 16 + m) * 256);
#pragma unroll
        for (int ks = 0; ks < 8; ks++)
            c = __builtin_amdgcn_mfma_f32_16x16x32_bf16(afr[ks], bp[ks * 4 + quad], c, 0, 0, 0);
        int colg = nt * 16 + m;
        bf16* O; int c0, ncol;
        if (colg < 256)       { O = qbh; c0 = colg;        ncol = 256; }
        else if (colg < 768)  { O = kvb; c0 = colg - 256;  ncol = 512; }
        else if (colg < 960)  { O = qpl; c0 = colg - 768;  ncol = 192; }
        else if (colg < 1152) { O = kpl; c0 = colg - 960;  ncol = 192; }
        else                  { O = vpl; c0 = colg - 1152; ncol = 192; }
#pragma unroll
        for (int r = 0; r < 4; r++) {
            int rg = r0 + mtile * 16 + quad * 4 + r;
            O[(size_t)rg * ncol + c0] = F2B(c[r]);
        }
    }
}

// Kernel P: rotate local-frame points to global frame.
__global__ __launch_bounds__(256) void kP(const bf16* __restrict__ qpl,
                                          const bf16* __restrict__ kpl,
                                          const bf16* __restrict__ vpl,
                                          const float* __restrict__ Rw,
                                          const float* __restrict__ pos,
                                          float* __restrict__ qpg,
                                          bf16* __restrict__ kvpgh) {
    int r0 = blockIdx.x * 4;
    int tid = threadIdx.x;
    for (int u = tid; u < 4 * 192; u += 256) {
        int r = u / 192, e = u % 192, hp = e / 3, ii = e % 3;
        int ri = r0 + r;
        float R0 = Rw[(size_t)ri * 9 + ii * 3 + 0];
        float R1 = Rw[(size_t)ri * 9 + ii * 3 + 1];
        float R2 = Rw[(size_t)ri * 9 + ii * 3 + 2];
        float tt = pos[(size_t)ri * 15 + 3 + ii];
        size_t base = (size_t)ri * 192 + hp * 3;
        qpg[(size_t)ri * 192 + e] = R0 * B2F(qpl[base]) + R1 * B2F(qpl[base + 1]) + R2 * B2F(qpl[base + 2]) + tt;
        kvpgh[(size_t)ri * 384 + e] = F2B(R0 * B2F(kpl[base]) + R1 * B2F(kpl[base + 1]) + R2 * B2F(kpl[base + 2]));
        kvpgh[(size_t)ri * 384 + 192 + e] = F2B(R0 * B2F(vpl[base]) + R1 * B2F(vpl[base + 1]) + R2 * B2F(vpl[base + 2]));
    }
}

// Kernel C v7: v6 + k/kp gather prefetch hoisted to kernel top (hides L2/HBM latency
// under pfA trig + pair MLP instead of just the V transpose-store).
__global__ __launch_bounds__(256, 4) void kC(const float* __restrict__ pos,
                                          const int* __restrict__ nbr,
                                          const int* __restrict__ resi,
                                          const int* __restrict__ chain,
                                          const int* __restrict__ batch,
                                          const int* __restrict__ mask,
                                          const float* __restrict__ Rw,
                                          const float* __restrict__ w_pair,
                                          const unsigned short* __restrict__ wT,
                                          const float* __restrict__ b_pair,
                                          const unsigned short* __restrict__ wbmT,
                                          const float* __restrict__ gamma,
                                          const bf16* __restrict__ qbh,
                                          const bf16* __restrict__ kvb,
                                          const float* __restrict__ qpg,
                                          const bf16* __restrict__ kvpgh,
                                          bf16* __restrict__ ipab,
                                          int N) {
    int i = blockIdx.x;
    int tid = threadIdx.x;
    __shared__ __align__(16) unsigned short BigT[256 * BTS];
    __shared__ __align__(16) unsigned short pairR[32 * PRS];
    __shared__ __align__(16) unsigned short attb[16 * 40];
    __shared__ __align__(16) float qS[256];
    __shared__ __align__(16) float qpS[192];
    __shared__ __align__(16) float pbS[256];     // pb -> logits -> att (f32), all in place
    __shared__ float spS[NHEAD];
    __shared__ float tjS[KNB][3];
    __shared__ float attjS[24];
    __shared__ int idxS[KNB], rpS[KNB], scS[KNB], sbS[KNB], pmS[KNB];
    __shared__ __align__(16) union UShare {
        unsigned short pfA[32 * KPAD];                    // 6656 B, dies after pair MLP
        struct { float ipaS[FOUT]; float optg[192]; } o;  // 4864 B, born at pass-1 extraction
    } uS;

    // ---- top-of-kernel prefetch: BOTH the v/vp_rel gathers (consumed at staging / pass 2)
    //      AND the k/kp gathers (consumed at logits) — all latency hides under pfA + pair MLP.
    int kk_s = tid & 31, seg = tid >> 5;
    int jpre;
    {
        int nb = nbr[(size_t)i * KNB + kk_s];
        jpre = min(max(nb, 0), N - 1);
    }
    short8 pv0, pv1, pv2, pv3, pp0, pp1, pp2;
    {
        const short8* vsrc = reinterpret_cast<const short8*>(kvb + (size_t)jpre * 512 + 256 + seg * 32);
        pv0 = vsrc[0]; pv1 = vsrc[1]; pv2 = vsrc[2]; pv3 = vsrc[3];
        const unsigned short* vpb = reinterpret_cast<const unsigned short*>(kvpgh) + (size_t)jpre * 384 + 192 + seg * 24;
        const short8* vpsrc = reinterpret_cast<const short8*>(vpb);
        pp0 = vpsrc[0]; pp1 = vpsrc[1]; pp2 = vpsrc[2];
    }
    short8 pk0, pk1, pk2, pk3, pq0, pq1, pq2;
    {
        int kk2 = tid >> 3, h2 = tid & 7;
        int nb2 = nbr[(size_t)i * KNB + kk2];
        int j2 = min(max(nb2, 0), N - 1);
        const short8* ksrc = reinterpret_cast<const short8*>(kvb + (size_t)j2 * 512 + h2 * 32);
        pk0 = ksrc[0]; pk1 = ksrc[1]; pk2 = ksrc[2]; pk3 = ksrc[3];
        const unsigned short* kpb = reinterpret_cast<const unsigned short*>(kvpgh) + (size_t)j2 * 384 + h2 * 24;
        const short8* kpsrc = reinterpret_cast<const short8*>(kpb);
        pq0 = kpsrc[0]; pq1 = kpsrc[1]; pq2 = kpsrc[2];
    }

    float R[9];
#pragma unroll
    for (int u = 0; u < 9; u++) R[u] = Rw[(size_t)i * 9 + u];
    float t0 = pos[(size_t)i * 15 + 3];
    float t1 = pos[(size_t)i * 15 + 4];
    float t2 = pos[(size_t)i * 15 + 5];

    qS[tid] = B2F(qbh[(size_t)i * 256 + tid]);
    if (tid < 192) qpS[tid] = qpg[(size_t)i * 192 + tid];
    if (tid < NHEAD) spS[tid] = log1pf(__expf(gamma[tid]));
    if (tid < KNB) {
        int nb = nbr[(size_t)i * KNB + tid];
        int j = min(max(nb, 0), N - 1);
        idxS[tid] = j;
        int rp = resi[j] - resi[i];
        rp = min(max(rp, -32), 32) + 32;
        rpS[tid] = rp;
        scS[tid] = (chain[j] == chain[i]) ? 1 : 0;
        sbS[tid] = (batch[j] == batch[i]) ? 1 : 0;
        pmS[tid] = (mask[i] != 0 && mask[j] != 0 && nb >= 0 && batch[j] == batch[i]) ? 1 : 0;
    }
    __syncthreads();
    if (tid < 160) {
        int kk = tid & 31, a = tid >> 5;
        int j = idxS[kk];
        const float* pj = pos + (size_t)j * 15 + a * 3;
        float pj0 = pj[0], pj1 = pj[1], pj2 = pj[2];
        if (a == 1) { tjS[kk][0] = pj0; tjS[kk][1] = pj1; tjS[kk][2] = pj2; }   // t_j = CA of j
        float px = pj0 - t0, py = pj1 - t1, pz = pj2 - t2;
        float r0_ = R[0] * px + R[3] * py + R[6] * pz;
        float r1_ = R[1] * px + R[4] * py + R[7] * pz;
        float r2_ = R[2] * px + R[5] * py + R[8] * pz;
        float s = r0_ * r0_ + r1_ * r1_ + r2_ * r2_;
        float dij = sqrtf(s + 1e-12f);
        float di = 1.f / (dij + 1e-6f);
        uS.pfA[kk * KPAD + a * 3 + 0] = f2bs(r0_ * di);
        uS.pfA[kk * KPAD + a * 3 + 1] = f2bs(r1_ * di);
        uS.pfA[kk * KPAD + a * 3 + 2] = f2bs(r2_ * di);
        for (int b = 0; b < 16; b++) {
            float z = (dij - (float)b * (10.f / 15.f)) * (1.f / 0.625f);
            uS.pfA[kk * KPAD + 15 + a * 16 + b] = f2bs(__expf(-z * z));
        }
    }
    if (tid < KNB) uS.pfA[tid * KPAD + FPD] = 0;
    __syncthreads();

    // ---- pair MLP via MFMA; epilogue writes pairR (row-major)
    {
        int lane = tid & 63;
        int wv = tid >> 6;
        int n0 = wv * 16;
        int mrow = lane & 15;
        int quad = lane >> 4;
        floatx4 c0 = {0.f, 0.f, 0.f, 0.f};
        floatx4 c1 = {0.f, 0.f, 0.f, 0.f};
#pragma unroll
        for (int ks = 0; ks < 3; ks++) {
            int k0 = ks * 32 + quad * 8;
            short8 a0 = *reinterpret_cast<const short8*>(&uS.pfA[mrow * KPAD + k0]);
            short8 a1 = *reinterpret_cast<const short8*>(&uS.pfA[(16 + mrow) * KPAD + k0]);
            short8 bb = *reinterpret_cast<const short8*>(&wT[(n0 + mrow) * KPAD + k0]);
            c0 = __builtin_amdgcn_mfma_f32_16x16x32_bf16(a0, bb, c0, 0, 0, 0);
            c1 = __builtin_amdgcn_mfma_f32_16x16x32_bf16(a1, bb, c1, 0, 0, 0);
        }
        int col = n0 + mrow;
        float bp = b_pair[col];
        float w160 = w_pair[160 * 64 + col];
        float w161 = w_pair[161 * 64 + col];
#pragma unroll
        for (int mt = 0; mt < 2; mt++) {
            floatx4 cc = mt ? c1 : c0;
#pragma unroll
            for (int r = 0; r < 4; r++) {
                int row = mt * 16 + quad * 4 + r;
                float s = cc[r] + bp + w_pair[(95 + rpS[row]) * 64 + col] +
                          (scS[row] ? w160 : 0.f) + (sbS[row] ? w161 : 0.f);
                pairR[row * PRS + col] = f2bs(gelu_f(s));
            }
        }
    }
    __syncthreads();

    // ---- staging phase: write prefetched V to BigT, pb MFMA
    {   // V: cols 0..255 (transpose-store the top prefetch)
        int kk = kk_s;
#pragma unroll
        for (int c = 0; c < 8; c++) BigT[(seg * 32 + c) * BTS + kk] = (unsigned short)pv0[c];
#pragma unroll
        for (int c = 0; c < 8; c++) BigT[(seg * 32 + 8 + c) * BTS + kk] = (unsigned short)pv1[c];
#pragma unroll
        for (int c = 0; c < 8; c++) BigT[(seg * 32 + 16 + c) * BTS + kk] = (unsigned short)pv2[c];
#pragma unroll
        for (int c = 0; c < 8; c++) BigT[(seg * 32 + 24 + c) * BTS + kk] = (unsigned short)pv3[c];
    }
    {   // pb = pair @ wbm via MFMA: D[m=kk][n=h], K=64
        int w = tid >> 6;
        if (w < 2) {
            int lane = tid & 63, la = lane & 15, quad = lane >> 4;
            floatx4 c = {0.f, 0.f, 0.f, 0.f};
#pragma unroll
            for (int ks = 0; ks < 2; ks++) {
                short8 a = *reinterpret_cast<const short8*>(&pairR[(w * 16 + la) * PRS + ks * 32 + quad * 8]);
                short8 b = *reinterpret_cast<const short8*>(wbmT + la * 64 + ks * 32 + quad * 8);
                c = __builtin_amdgcn_mfma_f32_16x16x32_bf16(a, b, c, 0, 0, 0);
            }
            if (la < NHEAD) {
#pragma unroll
                for (int r = 0; r < 4; r++)
                    pbS[(w * 16 + quad * 4 + r) * 8 + la] = c[r];
            }
        }
    }
    __syncthreads();

    // ---- logits: qk + d2 from top-prefetched registers; pb from MFMA; store into pbS in place
    {
        int kk = tid >> 3, h = tid & 7;
        float qk = 0.f;
        const floatx4* qh4 = reinterpret_cast<const floatx4*>(qS + h * 32);
        short8 kvv[4] = {pk0, pk1, pk2, pk3};
#pragma unroll
        for (int e = 0; e < 4; e++) {
            short8 kv = kvv[e];
            floatx4 qa = qh4[2 * e], qb = qh4[2 * e + 1];
            qk += qa[0] * bs2f(kv[0]) + qa[1] * bs2f(kv[1]) + qa[2] * bs2f(kv[2]) + qa[3] * bs2f(kv[3]) +
                  qb[0] * bs2f(kv[4]) + qb[1] * bs2f(kv[5]) + qb[2] * bs2f(kv[6]) + qb[3] * bs2f(kv[7]);
        }
        qk *= 0.17677669529663687f;
        float d2 = 0.f;
        const float* qp = qpS + h * 24;
        float tj[3] = {tjS[kk][0], tjS[kk][1], tjS[kk][2]};
        short8 kpv[3] = {pq0, pq1, pq2};
#pragma unroll
        for (int e8 = 0; e8 < 3; e8++)
#pragma unroll
            for (int c8 = 0; c8 < 8; c8++) {
                int x = e8 * 8 + c8;
                float df = (qp[x] - tj[x % 3]) - bs2f(kpv[e8][c8]);
                d2 += df * df;
            }
        float pb = pbS[kk * 8 + h];
        float lgt = 0.5773502691896258f * (qk + pb - (1.f / 12.f) * spS[h] * d2);
        pbS[kk * 8 + h] = pmS[kk] ? lgt : -1e9f;
    }
    __syncthreads();

    // ---- softmax over kk per head; write att to attb (bf16) AND pbS (f32, for t_j sums)
    if (tid < 64) {
        int h = tid >> 3, sub = tid & 7;
        float m = -INFINITY;
        float lv[4];
#pragma unroll
        for (int q = 0; q < 4; q++) {
            lv[q] = pbS[(sub + 8 * q) * 8 + h];
            m = fmaxf(m, lv[q]);
        }
#pragma unroll
        for (int mk = 1; mk < 8; mk <<= 1) m = fmaxf(m, __shfl_xor(m, mk));
        float s = 0.f, ex[4];
#pragma unroll
        for (int q = 0; q < 4; q++) { ex[q] = __expf(lv[q] - m); s += ex[q]; }
#pragma unroll
        for (int mk = 1; mk < 8; mk <<= 1) s += __shfl_xor(s, mk);
        float invs = 1.f / s;
#pragma unroll
        for (int q = 0; q < 4; q++) {
            int kk = sub + 8 * q;
            float a = pmS[kk] ? ex[q] * invs : 0.f;
            attb[h * 40 + kk] = f2bs(a);
            pbS[kk * 8 + h] = a;
        }
    } else if (tid < 128) {
        int t2 = tid - 64;
        int h2 = 8 + (t2 >> 3);
        int k0 = (t2 & 7) * 4;
#pragma unroll
        for (int q = 0; q < 4; q++) attb[h2 * 40 + k0 + q] = 0;
    }
    __syncthreads();

    int la_ = (tid & 63) & 15, quad_ = (tid & 63) >> 4, w_ = tid >> 6;
    short8 af = *reinterpret_cast<const short8*>(&attb[la_ * 40 + quad_ * 8]);

    // ---- PASS 1: D[16 x 256] = att @ BigT(V); extract o_s diag blocks
#pragma unroll
    for (int n4 = 0; n4 < 4; n4++) {
        int colg = (w_ * 4 + n4) * 16 + la_;
        union { short8 s; unsigned long long u[2]; } bb;
        const unsigned long long* bp = reinterpret_cast<const unsigned long long*>(&BigT[colg * BTS + quad_ * 8]);
        bb.u[0] = bp[0]; bb.u[1] = bp[1];
        floatx4 z = {0.f, 0.f, 0.f, 0.f};
        floatx4 d = __builtin_amdgcn_mfma_f32_16x16x32_bf16(af, bb.s, z, 0, 0, 0);
        int h_req = colg >> 5;
        if (quad_ == (h_req >> 2)) {
#pragma unroll
            for (int r = 0; r < 4; r++)
                if ((h_req & 3) == r) uS.o.ipaS[(h_req << 5) + (colg & 31)] = d[r];
        }
    }
    // att @ t_j (f32): 24 outputs [h][c]
    if (tid < 24) {
        int h = tid / 3, c = tid % 3;
        float s = 0.f;
#pragma unroll
        for (int kk = 0; kk < KNB; kk++) s += pbS[kk * 8 + h] * tjS[kk][c];
        attjS[tid] = s;
    }
    __syncthreads();

    // ---- PASS 2 staging: overwrite BigT cols 0..191 with vp_rel (regs), 192..255 with pair (pairR)
    {
        int kk = kk_s;
#pragma unroll
        for (int c = 0; c < 8; c++) BigT[(seg * 24 + c) * BTS + kk] = (unsigned short)pp0[c];
#pragma unroll
        for (int c = 0; c < 8; c++) BigT[(seg * 24 + 8 + c) * BTS + kk] = (unsigned short)pp1[c];
#pragma unroll
        for (int c = 0; c < 8; c++) BigT[(seg * 24 + 16 + c) * BTS + kk] = (unsigned short)pp2[c];
    }
    // pair transpose, conflict-free mapping: 8 threads/row, 8 cols each (read+write banks spread)
#pragma unroll
    for (int q = 0; q < 8; q++) {
        int row = tid >> 3;                 // 0..31
        int col = (tid & 7) + q * 8;        // 0..63
        BigT[(192 + col) * BTS + row] = pairR[row * PRS + col];
    }
    __syncthreads();

    // ---- PASS 2: D[16 x 256] = att @ BigT(vp|pair); extract optg + o_pr
#pragma unroll
    for (int n4 = 0; n4 < 4; n4++) {
        int colg = (w_ * 4 + n4) * 16 + la_;
        union { short8 s; unsigned long long u[2]; } bb;
        const unsigned long long* bp = reinterpret_cast<const unsigned long long*>(&BigT[colg * BTS + quad_ * 8]);
        bb.u[0] = bp[0]; bb.u[1] = bp[1];
        floatx4 z = {0.f, 0.f, 0.f, 0.f};
        floatx4 d = __builtin_amdgcn_mfma_f32_16x16x32_bf16(af, bb.s, z, 0, 0, 0);
        if (colg < 192) {
            int h_req = colg / 24;
            if (quad_ == (h_req >> 2)) {
#pragma unroll
                for (int r = 0; r < 4; r++)
                    if ((h_req & 3) == r) uS.o.optg[colg] = d[r];
            }
        } else if (quad_ < 2) {
            int c = colg - 192;
#pragma unroll
            for (int r = 0; r < 4; r++)
                uS.o.ipaS[256 + (quad_ * 4 + r) * 64 + c] = d[r];
        }
    }
    __syncthreads();

    // ---- rotate o_pt back to local frame: v = sum(att*vp_rel) + sum(att*t_j) - t_i
    if (tid < 192) {
        int hp = tid / 3, ii = tid % 3;
        int h = hp >> 3;
        float v0 = uS.o.optg[hp * 3 + 0] + attjS[h * 3 + 0] - t0;
        float v1 = uS.o.optg[hp * 3 + 1] + attjS[h * 3 + 1] - t1;
        float v2 = uS.o.optg[hp * 3 + 2] + attjS[h * 3 + 2] - t2;
        uS.o.ipaS[768 + tid] = R[0 + ii] * v0 + R[3 + ii] * v1 + R[6 + ii] * v2;
    }
    __syncthreads();
    if (tid < 64) {
        float a0 = uS.o.ipaS[768 + tid * 3], a1 = uS.o.ipaS[768 + tid * 3 + 1], a2 = uS.o.ipaS[768 + tid * 3 + 2];
        uS.o.ipaS[960 + tid] = sqrtf(a0 * a0 + a1 * a1 + a2 * a2 + 1e-8f);
    }
    __syncthreads();
    for (int u = tid; u < FOUT; u += 256) ipab[(size_t)i * FOUT + u] = F2B(uS.o.ipaS[u]);
}

// Kernel DEF: output projection + LN2 + transition MLP + LN3 + wpos + frame transform.
// 32 rows/block. Final local kept in registers for LN3; x3 staged f32 in hbf (stride 259,
// gcd(3,32)=1 -> conflict-free column reads). kF eliminated.
__global__ __launch_bounds__(256) void kDEF(const bf16* __restrict__ ipab,
                                            const unsigned short* __restrict__ woT,
                                            const float* __restrict__ bo,
                                            const float* __restrict__ ln2_s,
                                            const float* __restrict__ ln2_o,
                                            const unsigned short* __restrict__ wgT,
                                            const unsigned short* __restrict__ wvmT,
                                            const unsigned short* __restrict__ womT,
                                            float* __restrict__ dlocal,
                                            const float* __restrict__ ln3_s,
                                            const float* __restrict__ ln3_o,
                                            const float* __restrict__ wpos,
                                            const float* __restrict__ lpw,
                                            const float* __restrict__ Rw,
                                            const float* __restrict__ pos,
                                            const int* __restrict__ umask,
                                            float* __restrict__ outp) {
    int r0 = blockIdx.x * 32;
    int tid = threadIdx.x;
    __shared__ __align__(16) unsigned short xbf[32 * 264];
    __shared__ __align__(16) unsigned short hbf[32 * 520];   // reused as f32 x3F[32][259] after GEMM2
    __shared__ float statsS[32 * 4];
    __shared__ float nlS[32][15];
    int lane = tid & 63, w = tid >> 6;
    int mtile = w & 1, par = w >> 1, m = lane & 15, quad = lane >> 4;

    floatx4 l2[8];
#pragma unroll
    for (int j = 0; j < 8; j++) l2[j] = {0.f, 0.f, 0.f, 0.f};
    const short8* arow = reinterpret_cast<const short8*>(ipab + (size_t)(r0 + mtile * 16 + m) * 1024);
    for (int ks = 0; ks < 32; ks++) {
        short8 a = arow[ks * 4 + quad];
#pragma unroll
        for (int j = 0; j < 8; j++) {
            int nt = par + 2 * j;
            const short8* bp = reinterpret_cast<const short8*>(woT + (size_t)(nt * 16 + m) * 1024);
            l2[j] = __builtin_amdgcn_mfma_f32_16x16x32_bf16(a, bp[ks * 4 + quad], l2[j], 0, 0, 0);
        }
    }
#pragma unroll
    for (int j = 0; j < 8; j++) {
        int colg = (par + 2 * j) * 16 + m;
        float bov = bo[colg];
#pragma unroll
        for (int r = 0; r < 4; r++) {
            int row = mtile * 16 + quad * 4 + r;
            l2[j][r] += dlocal[(size_t)(r0 + row) * 256 + colg] + bov;
        }
    }
    // LN2 stats
    {
        float s[4] = {0.f, 0.f, 0.f, 0.f}, ss[4] = {0.f, 0.f, 0.f, 0.f};
#pragma unroll
        for (int j = 0; j < 8; j++)
#pragma unroll
            for (int r = 0; r < 4; r++) { s[r] += l2[j][r]; ss[r] += l2[j][r] * l2[j][r]; }
#pragma unroll
        for (int mask = 1; mask < 16; mask <<= 1)
#pragma unroll
            for (int r = 0; r < 4; r++) { s[r] += __shfl_xor(s[r], mask); ss[r] += __shfl_xor(ss[r], mask); }
        if (m == 0) {
#pragma unroll
            for (int r = 0; r < 4; r++) {
                int row = mtile * 16 + quad * 4 + r;
                statsS[row * 4 + par * 2 + 0] = s[r];
                statsS[row * 4 + par * 2 + 1] = ss[r];
            }
        }
    }
    __syncthreads();
    {
        float mu[4], rs_[4];
#pragma unroll
        for (int r = 0; r < 4; r++) {
            int row = mtile * 16 + quad * 4 + r;
            float S = statsS[row * 4 + 0] + statsS[row * 4 + 2];
            float SS = statsS[row * 4 + 1] + statsS[row * 4 + 3];
            float m_ = S * (1.f / 256.f);
            mu[r] = m_;
            rs_[r] = rsqrtf(SS * (1.f / 256.f) - m_ * m_ + 1e-5f);
        }
#pragma unroll
        for (int j = 0; j < 8; j++) {
            int colg = (par + 2 * j) * 16 + m;
            float g = ln2_s[colg], o = ln2_o[colg];
#pragma unroll
            for (int r = 0; r < 4; r++) {
                int row = mtile * 16 + quad * 4 + r;
                xbf[row * 264 + colg] = f2bs((l2[j][r] - mu[r]) * rs_[r] * g + o);
            }
        }
    }
    __syncthreads();
    // GEMM1: x @ [wg|wvm] -> h = gelu(ag)*av
    short8 afr[8];
#pragma unroll
    for (int ks = 0; ks < 8; ks++)
        afr[ks] = *reinterpret_cast<const short8*>(&xbf[(mtile * 16 + m) * 264 + ks * 32 + quad * 8]);
    for (int nt = par; nt < 32; nt += 2) {
        floatx4 cg = {0.f, 0.f, 0.f, 0.f};
        floatx4 cv = {0.f, 0.f, 0.f, 0.f};
        const short8* bg = reinterpret_cast<const short8*>(wgT + (size_t)(nt * 16 + m) * 256);
        const short8* bv = reinterpret_cast<const short8*>(wvmT + (size_t)(nt * 16 + m) * 256);
#pragma unroll
        for (int ks = 0; ks < 8; ks++) {
            cg = __builtin_amdgcn_mfma_f32_16x16x32_bf16(afr[ks], bg[ks * 4 + quad], cg, 0, 0, 0);
            cv = __builtin_amdgcn_mfma_f32_16x16x32_bf16(afr[ks], bv[ks * 4 + quad], cv, 0, 0, 0);
        }
#pragma unroll
        for (int r = 0; r < 4; r++) {
            int row = mtile * 16 + quad * 4 + r;
            hbf[row * 520 + nt * 16 + m] = f2bs(gelu_f(cg[r]) * cv[r]);
        }
    }
    __syncthreads();
    // GEMM2: h @ wom; final = l2 + acc
    floatx4 acc[8];
#pragma unroll
    for (int j = 0; j < 8; j++) acc[j] = {0.f, 0.f, 0.f, 0.f};
    for (int ks = 0; ks < 16; ks++) {
        short8 a = *reinterpret_cast<const short8*>(&hbf[(mtile * 16 + m) * 520 + ks * 32 + quad * 8]);
#pragma unroll
        for (int j = 0; j < 8; j++) {
            int nt = par + 2 * j;
            const short8* bp = reinterpret_cast<const short8*>(womT + (size_t)(nt * 16 + m) * 512);
            acc[j] = __builtin_amdgcn_mfma_f32_16x16x32_bf16(a, bp[ks * 4 + quad], acc[j], 0, 0, 0);
        }
    }
    // final values: write out_local, keep in regs for LN3
    float fin[8][4];
#pragma unroll
    for (int j = 0; j < 8; j++) {
        int colg = (par + 2 * j) * 16 + m;
#pragma unroll
        for (int r = 0; r < 4; r++) {
            int row = mtile * 16 + quad * 4 + r;
            float fv = l2[j][r] + acc[j][r];
            fin[j][r] = fv;
            dlocal[(size_t)(r0 + row) * 256 + colg] = fv;
        }
    }
    // ---- LN3 stats (same pattern as LN2)
    {
        float s[4] = {0.f, 0.f, 0.f, 0.f}, ss[4] = {0.f, 0.f, 0.f, 0.f};
#pragma unroll
        for (int j = 0; j < 8; j++)
#pragma unroll
            for (int r = 0; r < 4; r++) { s[r] += fin[j][r]; ss[r] += fin[j][r] * fin[j][r]; }
#pragma unroll
        for (int mask = 1; mask < 16; mask <<= 1)
#pragma unroll
            for (int r = 0; r < 4; r++) { s[r] += __shfl_xor(s[r], mask); ss[r] += __shfl_xor(ss[r], mask); }
        if (m == 0) {
#pragma unroll
            for (int r = 0; r < 4; r++) {
                int row = mtile * 16 + quad * 4 + r;
                statsS[row * 4 + par * 2 + 0] = s[r];
                statsS[row * 4 + par * 2 + 1] = ss[r];
            }
        }
    }
    __syncthreads();   // also fences hbf reads (GEMM2) before x3F overwrite
    float* x3F = reinterpret_cast<float*>(hbf);   // [32][259] f32 = 33152 B <= 33280 B
    {
        float mu[4], rs_[4];
#pragma unroll
        for (int r = 0; r < 4; r++) {
            int row = mtile * 16 + quad * 4 + r;
            float S = statsS[row * 4 + 0] + statsS[row * 4 + 2];
            float SS = statsS[row * 4 + 1] + statsS[row * 4 + 3];
            float m_ = S * (1.f / 256.f);
            mu[r] = m_;
            rs_[r] = rsqrtf(SS * (1.f / 256.f) - m_ * m_ + 1e-5f);
        }
#pragma unroll
        for (int j = 0; j < 8; j++) {
            int colg = (par + 2 * j) * 16 + m;
            float g = ln3_s[colg], o = ln3_o[colg];
#pragma unroll
            for (int r = 0; r < 4; r++) {
                int row = mtile * 16 + quad * 4 + r;
                x3F[row * 259 + colg] = (fin[j][r] - mu[r]) * rs_[r] * g + o;
            }
        }
    }
    __syncthreads();
    // ---- nl = lpw + x3 @ wpos  (480 outputs: row 0..31, e 0..14)
    for (int o = tid; o < 480; o += 256) {
        int row = o & 31, e = o >> 5;
        const float* xr = x3F + row * 259;
        float sum = 0.f;
        for (int f = 0; f < 256; f++) sum += xr[f] * wpos[f * 15 + e];
        nlS[row][e] = lpw[(size_t)(r0 + row) * 15 + e] + sum;
    }
    __syncthreads();
    // ---- frame transform + update_mask
    for (int o = tid; o < 480; o += 256) {
        int row = o & 31, e = o >> 5;
        int rj = r0 + row;
        int a2 = e / 3, ii = e % 3;
        float R0 = Rw[(size_t)rj * 9 + ii * 3 + 0];
        float R1 = Rw[(size_t)rj * 9 + ii * 3 + 1];
        float R2 = Rw[(size_t)rj * 9 + ii * 3 + 2];
        float tt = pos[(size_t)rj * 15 + 3 + ii];
        float np = R0 * nlS[row][a2 * 3 + 0] + R1 * nlS[row][a2 * 3 + 1] + R2 * nlS[row][a2 * 3 + 2] + tt;
        float old = pos[(size_t)rj * 15 + e];
        outp[(size_t)rj * 15 + e] = (umask[rj] != 0) ? np : old;
    }
}

extern "C" void kernel_launch(void* const* d_in, const int* in_sizes, int n_in,
                              void* d_out, int out_size, void* d_ws, size_t ws_size,
                              hipStream_t stream) {
    static const int map_dict[31] = {0, 1, 2, 3, 4, 5, 6, 7, 8, 9, 10, 11, 12, 13, 14, 15,
                                     16, 17, 18, 19, 20, 21, 22, 23, 24, 25, 26, 27, 28, 29, 30};
    static const int map_sig[31] = {0, 1, 25, 26, 27, 28, 29, 30, 2, 3, 4, 5, 6, 7, 8, 9,
                                    10, 11, 12, 13, 14, 15, 16, 17, 18, 19, 20, 21, 22, 23, 24};
    const int* M = (in_sizes[2] == FIN * DMODEL) ? map_sig : map_dict;

    const float* local = (const float*)d_in[M[0]];
    const float* pos = (const float*)d_in[M[1]];
    const int* nbr = (const int*)d_in[M[2]];
    const int* resi = (const int*)d_in[M[3]];
    const int* chain = (const int*)d_in[M[4]];
    const int* batch = (const int*)d_in[M[5]];
    const int* umask = (const int*)d_in[M[6]];
    const int* mask = (const int*)d_in[M[7]];
    const float* w_in = (const float*)d_in[M[8]];
    const float* w_pair = (const float*)d_in[M[9]];
    const float* b_pair = (const float*)d_in[M[10]];
    const float* ln1_s = (const float*)d_in[M[11]];
    const float* ln1_o = (const float*)d_in[M[12]];
    const float* wq = (const float*)d_in[M[13]];
    const float* wk = (const float*)d_in[M[14]];
    const float* wv = (const float*)d_in[M[15]];
    const float* wqp = (const float*)d_in[M[16]];
    const float* wkp = (const float*)d_in[M[17]];
    const float* wvp = (const float*)d_in[M[18]];
    const float* wbm = (const float*)d_in[M[19]];
    const float* gamma = (const float*)d_in[M[20]];
    const float* wo = (const float*)d_in[M[21]];
    const float* bo = (const float*)d_in[M[22]];
    const float* ln2_s = (const float*)d_in[M[23]];
    const float* ln2_o = (const float*)d_in[M[24]];
    const float* wg = (const float*)d_in[M[25]];
    const float* wvm = (const float*)d_in[M[26]];
    const float* wom = (const float*)d_in[M[27]];
    const float* ln3_s = (const float*)d_in[M[28]];
    const float* ln3_o = (const float*)d_in[M[29]];
    const float* wpos = (const float*)d_in[M[30]];

    int N = in_sizes[0] / DMODEL;

    float* out_local = (float*)d_out;
    float* out_pos = out_local + (size_t)N * DMODEL;

    char* wsb = (char*)d_ws;
    float* Rw = (float*)wsb;   wsb += (size_t)N * 9 * 4;
    float* lpw = (float*)wsb;  wsb += (size_t)N * 15 * 4;
    bf16* qbh = (bf16*)wsb;    wsb += (size_t)N * 256 * 2;
    bf16* kvb = (bf16*)wsb;    wsb += (size_t)N * 512 * 2;
    bf16* qpl = (bf16*)wsb;    wsb += (size_t)N * 192 * 2;
    bf16* kpl = (bf16*)wsb;    wsb += (size_t)N * 192 * 2;
    bf16* vpl = (bf16*)wsb;    wsb += (size_t)N * 192 * 2;
    bf16* ipab = (bf16*)wsb;   wsb += (size_t)N * 1024 * 2;
    float* qpg = (float*)wsb;  wsb += (size_t)N * 192 * 4;
    bf16* kvpgh = (bf16*)wsb;  wsb += (size_t)N * 384 * 2;
    unsigned short* featb = (unsigned short*)wsb; wsb += (size_t)N * KPAD * 2;
    unsigned short* wtrans = (unsigned short*)wsb; wsb += (size_t)WT_TOTAL * 2;
    unsigned short* wAllT = wtrans + OFF_WALL;
    unsigned short* woT   = wtrans + OFF_WO;
    unsigned short* wgT   = wtrans + OFF_WG;
    unsigned short* wvmT  = wtrans + OFF_WVM;
    unsigned short* womT  = wtrans + OFF_WOM;
    unsigned short* wpT   = wtrans + OFF_WP;
    unsigned short* winT  = wtrans + OFF_WIN;
    unsigned short* wbmT  = wtrans + OFF_WBM;

    dim3 blk(256);
    hipLaunchKernelGGL(kT, dim3(512), blk, 0, stream, wq, wk, wv, wqp, wkp, wvp,
                       wo, wg, wvm, wom, w_pair, w_in, wbm, wtrans);
    hipLaunchKernelGGL(kA1, dim3(N / 8), blk, 0, stream, pos, Rw, lpw, featb);
    hipLaunchKernelGGL(kB, dim3(N / 32), blk, 0, stream, local, featb, ln1_s, ln1_o, wAllT, winT,
                       out_local, qbh, kvb, qpl, kpl, vpl);
    hipLaunchKernelGGL(kP, dim3(N / 4), blk, 0, stream, qpl, kpl, vpl, Rw, pos, qpg, kvpgh);
    hipLaunchKernelGGL(kC, dim3(N), blk, 0, stream, pos, nbr, resi, chain, batch, mask, Rw,
                       w_pair, wpT, b_pair, wbmT, gamma, qbh, kvb, qpg, kvpgh, ipab, N);
    hipLaunchKernelGGL(kDEF, dim3(N / 32), blk, 0, stream, ipab, woT, bo, ln2_s, ln2_o,
                       wgT, wvmT, womT, out_local, ln3_s, ln3_o, wpos, lpw, Rw, pos, umask, out_pos);
}

// Round 11
// 599.593 us; speedup vs baseline: 1.0818x; 1.0818x over previous
//
#include <hip/hip_runtime.h>
#include <hip/hip_bf16.h>
#include <math.h>

#define DMODEL 256
#define KNB 32
#define NHEAD 8
#define FIN 95
#define FPD 95        // dense part of pair features
#define KPAD 104      // padded K for pair/feat MFMA staging
#define FOUT 1024
#define DHID 512
#define BTS 36        // BigT kk-stride (pad 32->36: 8B-aligned frags, no 16-way banks)
#define PRS 72        // pairR row stride (144B: 16B-aligned b128 frags)

typedef __hip_bfloat16 bf16;
typedef __attribute__((ext_vector_type(8))) short short8;
typedef __attribute__((ext_vector_type(4))) float floatx4;

__device__ inline float B2F(bf16 x) { return __bfloat162float(x); }
__device__ inline bf16 F2B(float x) { return __float2bfloat16(x); }
__device__ inline unsigned short f2bs(float x) {
    bf16 h = __float2bfloat16(x);
    return *reinterpret_cast<unsigned short*>(&h);
}
__device__ inline float bs2f(short s) {
    return __uint_as_float(((unsigned)(unsigned short)s) << 16);
}

// fast gelu: tanh(y) = 1 - 2/(1+e^{2y}); e^{2y} via __expf (v_exp)
__device__ inline float gelu_f(float x) {
    float u = 1.5957691216057308f * x * (1.f + 0.044715f * x * x);   // 2*0.79788456*(x+0.044715x^3)
    float t = 1.f - 2.f / (1.f + __expf(u));
    return 0.5f * x * (1.f + t);
}

// ---- weight transpose buffer layout (bf16 elements) ----
#define OFF_WALL 0          // [1344][256]  q|k|v|qp|kp|vp columns
#define OFF_WO   344064     // [256][1024]
#define OFF_WG   606208     // [512][256]
#define OFF_WVM  737280     // [512][256]
#define OFF_WOM  868352     // [256][512]
#define OFF_WP   999424     // [64][KPAD]
#define OFF_WIN  1006080    // [256][KPAD]  w_in transposed
#define OFF_WBM  1032704    // [16][64]     wbm transposed (heads 8..15 zero)
#define WT_TOTAL 1033728

// Kernel T: transpose/convert all weights to bf16 [n][k] (k-contiguous)
__global__ __launch_bounds__(256) void kT(const float* __restrict__ wq, const float* __restrict__ wk,
                                          const float* __restrict__ wv, const float* __restrict__ wqp,
                                          const float* __restrict__ wkp, const float* __restrict__ wvp,
                                          const float* __restrict__ wo, const float* __restrict__ wg,
                                          const float* __restrict__ wvm, const float* __restrict__ wom,
                                          const float* __restrict__ w_pair, const float* __restrict__ w_in,
                                          const float* __restrict__ wbm,
                                          unsigned short* __restrict__ wt) {
    int stride = gridDim.x * 256;
    for (int e = blockIdx.x * 256 + threadIdx.x; e < WT_TOTAL; e += stride) {
        float v;
        if (e < OFF_WO) {
            int n = e >> 8, k = e & 255;
            if (n < 256) v = wq[k * 256 + n];
            else if (n < 512) v = wk[k * 256 + n - 256];
            else if (n < 768) v = wv[k * 256 + n - 512];
            else if (n < 960) v = wqp[k * 192 + n - 768];
            else if (n < 1152) v = wkp[k * 192 + n - 960];
            else v = wvp[k * 192 + n - 1152];
        } else if (e < OFF_WG) {
            int u = e - OFF_WO; int n = u >> 10, k = u & 1023;
            v = wo[k * 256 + n];
        } else if (e < OFF_WVM) {
            int u = e - OFF_WG; int n = u >> 8, k = u & 255;
            v = wg[k * 512 + n];
        } else if (e < OFF_WOM) {
            int u = e - OFF_WVM; int n = u >> 8, k = u & 255;
            v = wvm[k * 512 + n];
        } else if (e < OFF_WP) {
            int u = e - OFF_WOM; int n = u >> 9, k = u & 511;
            v = wom[k * 256 + n];
        } else if (e < OFF_WIN) {
            int u = e - OFF_WP; int n = u / KPAD, k = u % KPAD;
            v = (k < FPD) ? w_pair[k * 64 + n] : 0.f;
        } else if (e < OFF_WBM) {
            int u = e - OFF_WIN; int n = u / KPAD, k = u % KPAD;
            v = (k < FIN) ? w_in[k * 256 + n] : 0.f;
        } else {
            int u = e - OFF_WBM; int n = u >> 6, k = u & 63;
            v = (n < NHEAD) ? wbm[k * 8 + n] : 0.f;
        }
        wt[e] = f2bs(v);
    }
}

// Kernel A1: frames + feat (bf16, 104-padded). 8 residues/block, 32 threads each.
__global__ __launch_bounds__(256) void kA1(const float* __restrict__ pos,
                                           float* __restrict__ Rw,
                                           float* __restrict__ lpw,
                                           unsigned short* __restrict__ featb) {
    int tid = threadIdx.x;
    int res = tid >> 5, lt = tid & 31;
    int ri = blockIdx.x * 8 + res;
    const float* pp = pos + (size_t)ri * 15;
    float nx = pp[0], ny = pp[1], nz = pp[2];
    float cax = pp[3], cay = pp[4], caz = pp[5];
    float cx = pp[6], cy = pp[7], cz = pp[8];
    float e1x = cx - cax, e1y = cy - cay, e1z = cz - caz;
    float inv = rsqrtf(e1x * e1x + e1y * e1y + e1z * e1z + 1e-6f);
    e1x *= inv; e1y *= inv; e1z *= inv;
    float ux = nx - cax, uy = ny - cay, uz = nz - caz;
    float d = ux * e1x + uy * e1y + uz * e1z;
    float wx = ux - d * e1x, wy = uy - d * e1y, wz = uz - d * e1z;
    inv = rsqrtf(wx * wx + wy * wy + wz * wz + 1e-6f);
    float e2x = wx * inv, e2y = wy * inv, e2z = wz * inv;
    float e3x = e1y * e2z - e1z * e2y;
    float e3y = e1z * e2x - e1x * e2z;
    float e3z = e1x * e2y - e1y * e2x;
    float R[9] = {e1x, e2x, e3x, e1y, e2y, e3y, e1z, e2z, e3z};

    __shared__ float lpS[8][15];
    __shared__ float ddS[8][5], dinvS[8][5];

    if (lt < 9) Rw[(size_t)ri * 9 + lt] = R[lt];
    if (lt < 15) {
        int a = lt / 3, ii = lt % 3;
        float px = pp[a * 3 + 0] - cax, py = pp[a * 3 + 1] - cay, pz = pp[a * 3 + 2] - caz;
        float v = R[0 * 3 + ii] * px + R[1 * 3 + ii] * py + R[2 * 3 + ii] * pz;
        lpS[res][lt] = v;
        lpw[(size_t)ri * 15 + lt] = v;
    }
    __syncthreads();
    if (lt < 5) {
        float s = lpS[res][lt * 3] * lpS[res][lt * 3] + lpS[res][lt * 3 + 1] * lpS[res][lt * 3 + 1] +
                  lpS[res][lt * 3 + 2] * lpS[res][lt * 3 + 2];
        ddS[res][lt] = sqrtf(s + 1e-12f);
        dinvS[res][lt] = rsqrtf(s + 1e-6f);
    }
    __syncthreads();
    for (int e = lt; e < KPAD; e += 32) {
        float v;
        if (e < 15) v = lpS[res][e] * dinvS[res][e / 3];
        else if (e < 95) {
            int u = e - 15, a = u >> 4, b = u & 15;
            float z = (ddS[res][a] - (float)b * (10.f / 15.f)) * (1.f / 0.625f);
            v = __expf(-z * z);
        } else v = 0.f;
        featb[(size_t)ri * KPAD + e] = f2bs(v);
    }
}

// Kernel B v3: 32 rows/block, 512 threads (8 waves = 2 mtile x 4 par).
// Same block count (no weight-traffic duplication), 2x waves/CU for latency hiding.
__global__ __launch_bounds__(512) void kB(const float* __restrict__ local,
                                          const unsigned short* __restrict__ featb,
                                          const float* __restrict__ ln1_s,
                                          const float* __restrict__ ln1_o,
                                          const unsigned short* __restrict__ wAllT,
                                          const unsigned short* __restrict__ w_inT,
                                          float* __restrict__ dlocal,
                                          bf16* __restrict__ qbh, bf16* __restrict__ kvb,
                                          bf16* __restrict__ qpl, bf16* __restrict__ kpl,
                                          bf16* __restrict__ vpl) {
    int r0 = blockIdx.x * 32;
    int tid = threadIdx.x;
    __shared__ __align__(16) unsigned short featA[32 * KPAD];
    __shared__ __align__(16) unsigned short xbf[32 * 264];
    __shared__ float statsS[32 * 8];

    {
        const short8* src = reinterpret_cast<const short8*>(featb + (size_t)r0 * KPAD);
        short8* dst = reinterpret_cast<short8*>(featA);
        for (int c = tid; c < 32 * KPAD / 8; c += 512) dst[c] = src[c];
    }
    __syncthreads();

    int lane = tid & 63, w = tid >> 6;
    int mtile = w & 1, par = w >> 1;          // par in 0..3
    int m = lane & 15, quad = lane >> 4;

    short8 fa[3];
#pragma unroll
    for (int ks = 0; ks < 3; ks++)
        fa[ks] = *reinterpret_cast<const short8*>(&featA[(mtile * 16 + m) * KPAD + ks * 32 + quad * 8]);
    float lupv[4][4];
#pragma unroll
    for (int j = 0; j < 4; j++) {
        int nt = par + 4 * j;
        floatx4 c = {0.f, 0.f, 0.f, 0.f};
        const short8* bp = reinterpret_cast<const short8*>(w_inT + (size_t)(nt * 16 + m) * KPAD);
#pragma unroll
        for (int ks = 0; ks < 3; ks++)
            c = __builtin_amdgcn_mfma_f32_16x16x32_bf16(fa[ks], bp[ks * 4 + quad], c, 0, 0, 0);
        int col = nt * 16 + m;
#pragma unroll
        for (int r = 0; r < 4; r++) {
            int row = mtile * 16 + quad * 4 + r;
            float lv = local[(size_t)(r0 + row) * 256 + col] + c[r];
            lupv[j][r] = lv;
            dlocal[(size_t)(r0 + row) * 256 + col] = lv;
        }
    }
    {
        float s[4] = {0.f, 0.f, 0.f, 0.f}, ss[4] = {0.f, 0.f, 0.f, 0.f};
#pragma unroll
        for (int j = 0; j < 4; j++)
#pragma unroll
            for (int r = 0; r < 4; r++) { s[r] += lupv[j][r]; ss[r] += lupv[j][r] * lupv[j][r]; }
#pragma unroll
        for (int mask = 1; mask < 16; mask <<= 1)
#pragma unroll
            for (int r = 0; r < 4; r++) { s[r] += __shfl_xor(s[r], mask); ss[r] += __shfl_xor(ss[r], mask); }
        if (m == 0) {
#pragma unroll
            for (int r = 0; r < 4; r++) {
                int row = mtile * 16 + quad * 4 + r;
                statsS[row * 8 + par * 2 + 0] = s[r];
                statsS[row * 8 + par * 2 + 1] = ss[r];
            }
        }
    }
    __syncthreads();
    {
        float mu[4], rs_[4];
#pragma unroll
        for (int r = 0; r < 4; r++) {
            int row = mtile * 16 + quad * 4 + r;
            float S = statsS[row * 8 + 0] + statsS[row * 8 + 2] + statsS[row * 8 + 4] + statsS[row * 8 + 6];
            float SS = statsS[row * 8 + 1] + statsS[row * 8 + 3] + statsS[row * 8 + 5] + statsS[row * 8 + 7];
            float m_ = S * (1.f / 256.f);
            mu[r] = m_;
            rs_[r] = rsqrtf(SS * (1.f / 256.f) - m_ * m_ + 1e-5f);
        }
#pragma unroll
        for (int j = 0; j < 4; j++) {
            int col = (par + 4 * j) * 16 + m;
            float g = ln1_s[col], o = ln1_o[col];
#pragma unroll
            for (int r = 0; r < 4; r++) {
                int row = mtile * 16 + quad * 4 + r;
                xbf[row * 264 + col] = f2bs((lupv[j][r] - mu[r]) * rs_[r] * g + o);
            }
        }
    }
    __syncthreads();

    short8 afr[8];
#pragma unroll
    for (int ks = 0; ks < 8; ks++)
        afr[ks] = *reinterpret_cast<const short8*>(&xbf[(mtile * 16 + m) * 264 + ks * 32 + quad * 8]);
    for (int nt = par; nt < 84; nt += 4) {
        floatx4 c = {0.f, 0.f, 0.f, 0.f};
        const short8* bp = reinterpret_cast<const short8*>(wAllT + (size_t)(nt * 16 + m) * 256);
#pragma unroll
        for (int ks = 0; ks < 8; ks++)
            c = __builtin_amdgcn_mfma_f32_16x16x32_bf16(afr[ks], bp[ks * 4 + quad], c, 0, 0, 0);
        int colg = nt * 16 + m;
        bf16* O; int c0, ncol;
        if (colg < 256)       { O = qbh; c0 = colg;        ncol = 256; }
        else if (colg < 768)  { O = kvb; c0 = colg - 256;  ncol = 512; }
        else if (colg < 960)  { O = qpl; c0 = colg - 768;  ncol = 192; }
        else if (colg < 1152) { O = kpl; c0 = colg - 960;  ncol = 192; }
        else                  { O = vpl; c0 = colg - 1152; ncol = 192; }
#pragma unroll
        for (int r = 0; r < 4; r++) {
            int rg = r0 + mtile * 16 + quad * 4 + r;
            O[(size_t)rg * ncol + c0] = F2B(c[r]);
        }
    }
}

// Kernel P: rotate local-frame points to global frame.
__global__ __launch_bounds__(256) void kP(const bf16* __restrict__ qpl,
                                          const bf16* __restrict__ kpl,
                                          const bf16* __restrict__ vpl,
                                          const float* __restrict__ Rw,
                                          const float* __restrict__ pos,
                                          float* __restrict__ qpg,
                                          bf16* __restrict__ kvpgh) {
    int r0 = blockIdx.x * 4;
    int tid = threadIdx.x;
    for (int u = tid; u < 4 * 192; u += 256) {
        int r = u / 192, e = u % 192, hp = e / 3, ii = e % 3;
        int ri = r0 + r;
        float R0 = Rw[(size_t)ri * 9 + ii * 3 + 0];
        float R1 = Rw[(size_t)ri * 9 + ii * 3 + 1];
        float R2 = Rw[(size_t)ri * 9 + ii * 3 + 2];
        float tt = pos[(size_t)ri * 15 + 3 + ii];
        size_t base = (size_t)ri * 192 + hp * 3;
        qpg[(size_t)ri * 192 + e] = R0 * B2F(qpl[base]) + R1 * B2F(qpl[base + 1]) + R2 * B2F(qpl[base + 2]) + tt;
        kvpgh[(size_t)ri * 384 + e] = F2B(R0 * B2F(kpl[base]) + R1 * B2F(kpl[base + 1]) + R2 * B2F(kpl[base + 2]));
        kvpgh[(size_t)ri * 384 + 192 + e] = F2B(R0 * B2F(vpl[base]) + R1 * B2F(vpl[base + 1]) + R2 * B2F(vpl[base + 2]));
    }
}

// Kernel C v6 (reverted to round-9 exact: best measured 216.8-218us).
__global__ __launch_bounds__(256, 4) void kC(const float* __restrict__ pos,
                                          const int* __restrict__ nbr,
                                          const int* __restrict__ resi,
                                          const int* __restrict__ chain,
                                          const int* __restrict__ batch,
                                          const int* __restrict__ mask,
                                          const float* __restrict__ Rw,
                                          const float* __restrict__ w_pair,
                                          const unsigned short* __restrict__ wT,
                                          const float* __restrict__ b_pair,
                                          const unsigned short* __restrict__ wbmT,
                                          const float* __restrict__ gamma,
                                          const bf16* __restrict__ qbh,
                                          const bf16* __restrict__ kvb,
                                          const float* __restrict__ qpg,
                                          const bf16* __restrict__ kvpgh,
                                          bf16* __restrict__ ipab,
                                          int N) {
    int i = blockIdx.x;
    int tid = threadIdx.x;
    __shared__ __align__(16) unsigned short BigT[256 * BTS];
    __shared__ __align__(16) unsigned short pairR[32 * PRS];
    __shared__ __align__(16) unsigned short attb[16 * 40];
    __shared__ __align__(16) float qS[256];
    __shared__ __align__(16) float qpS[192];
    __shared__ __align__(16) float pbS[256];     // pb -> logits -> att (f32), all in place
    __shared__ float spS[NHEAD];
    __shared__ float tjS[KNB][3];
    __shared__ float attjS[24];
    __shared__ int idxS[KNB], rpS[KNB], scS[KNB], sbS[KNB], pmS[KNB];
    __shared__ __align__(16) union UShare {
        unsigned short pfA[32 * KPAD];                    // 6656 B, dies after pair MLP
        struct { float ipaS[FOUT]; float optg[192]; } o;  // 4864 B, born at pass-1 extraction
    } uS;

    // ---- top-of-kernel prefetch of the v / vp_rel gathers (v consumed in staging, vp in pass 2)
    int kk_s = tid & 31, seg = tid >> 5;
    int jpre;
    {
        int nb = nbr[(size_t)i * KNB + kk_s];
        jpre = min(max(nb, 0), N - 1);
    }
    short8 pv0, pv1, pv2, pv3, pp0, pp1, pp2;
    {
        const short8* vsrc = reinterpret_cast<const short8*>(kvb + (size_t)jpre * 512 + 256 + seg * 32);
        pv0 = vsrc[0]; pv1 = vsrc[1]; pv2 = vsrc[2]; pv3 = vsrc[3];
        const unsigned short* vpb = reinterpret_cast<const unsigned short*>(kvpgh) + (size_t)jpre * 384 + 192 + seg * 24;
        const short8* vpsrc = reinterpret_cast<const short8*>(vpb);
        pp0 = vpsrc[0]; pp1 = vpsrc[1]; pp2 = vpsrc[2];
    }

    float R[9];
#pragma unroll
    for (int u = 0; u < 9; u++) R[u] = Rw[(size_t)i * 9 + u];
    float t0 = pos[(size_t)i * 15 + 3];
    float t1 = pos[(size_t)i * 15 + 4];
    float t2 = pos[(size_t)i * 15 + 5];

    qS[tid] = B2F(qbh[(size_t)i * 256 + tid]);
    if (tid < 192) qpS[tid] = qpg[(size_t)i * 192 + tid];
    if (tid < NHEAD) spS[tid] = log1pf(__expf(gamma[tid]));
    if (tid < KNB) {
        int nb = nbr[(size_t)i * KNB + tid];
        int j = min(max(nb, 0), N - 1);
        idxS[tid] = j;
        int rp = resi[j] - resi[i];
        rp = min(max(rp, -32), 32) + 32;
        rpS[tid] = rp;
        scS[tid] = (chain[j] == chain[i]) ? 1 : 0;
        sbS[tid] = (batch[j] == batch[i]) ? 1 : 0;
        pmS[tid] = (mask[i] != 0 && mask[j] != 0 && nb >= 0 && batch[j] == batch[i]) ? 1 : 0;
    }
    __syncthreads();
    if (tid < 160) {
        int kk = tid & 31, a = tid >> 5;
        int j = idxS[kk];
        const float* pj = pos + (size_t)j * 15 + a * 3;
        float pj0 = pj[0], pj1 = pj[1], pj2 = pj[2];
        if (a == 1) { tjS[kk][0] = pj0; tjS[kk][1] = pj1; tjS[kk][2] = pj2; }   // t_j = CA of j
        float px = pj0 - t0, py = pj1 - t1, pz = pj2 - t2;
        float r0_ = R[0] * px + R[3] * py + R[6] * pz;
        float r1_ = R[1] * px + R[4] * py + R[7] * pz;
        float r2_ = R[2] * px + R[5] * py + R[8] * pz;
        float s = r0_ * r0_ + r1_ * r1_ + r2_ * r2_;
        float dij = sqrtf(s + 1e-12f);
        float di = 1.f / (dij + 1e-6f);
        uS.pfA[kk * KPAD + a * 3 + 0] = f2bs(r0_ * di);
        uS.pfA[kk * KPAD + a * 3 + 1] = f2bs(r1_ * di);
        uS.pfA[kk * KPAD + a * 3 + 2] = f2bs(r2_ * di);
        for (int b = 0; b < 16; b++) {
            float z = (dij - (float)b * (10.f / 15.f)) * (1.f / 0.625f);
            uS.pfA[kk * KPAD + 15 + a * 16 + b] = f2bs(__expf(-z * z));
        }
    }
    if (tid < KNB) uS.pfA[tid * KPAD + FPD] = 0;
    __syncthreads();

    // ---- pair MLP via MFMA; epilogue writes pairR (row-major)
    {
        int lane = tid & 63;
        int wv = tid >> 6;
        int n0 = wv * 16;
        int mrow = lane & 15;
        int quad = lane >> 4;
        floatx4 c0 = {0.f, 0.f, 0.f, 0.f};
        floatx4 c1 = {0.f, 0.f, 0.f, 0.f};
#pragma unroll
        for (int ks = 0; ks < 3; ks++) {
            int k0 = ks * 32 + quad * 8;
            short8 a0 = *reinterpret_cast<const short8*>(&uS.pfA[mrow * KPAD + k0]);
            short8 a1 = *reinterpret_cast<const short8*>(&uS.pfA[(16 + mrow) * KPAD + k0]);
            short8 bb = *reinterpret_cast<const short8*>(&wT[(n0 + mrow) * KPAD + k0]);
            c0 = __builtin_amdgcn_mfma_f32_16x16x32_bf16(a0, bb, c0, 0, 0, 0);
            c1 = __builtin_amdgcn_mfma_f32_16x16x32_bf16(a1, bb, c1, 0, 0, 0);
        }
        int col = n0 + mrow;
        float bp = b_pair[col];
        float w160 = w_pair[160 * 64 + col];
        float w161 = w_pair[161 * 64 + col];
#pragma unroll
        for (int mt = 0; mt < 2; mt++) {
            floatx4 cc = mt ? c1 : c0;
#pragma unroll
            for (int r = 0; r < 4; r++) {
                int row = mt * 16 + quad * 4 + r;
                float s = cc[r] + bp + w_pair[(95 + rpS[row]) * 64 + col] +
                          (scS[row] ? w160 : 0.f) + (sbS[row] ? w161 : 0.f);
                pairR[row * PRS + col] = f2bs(gelu_f(s));
            }
        }
    }
    __syncthreads();

    // ---- staging phase: prefetch k/kp for logits, write prefetched V to BigT, pb MFMA
    short8 pk0, pk1, pk2, pk3, pq0, pq1, pq2;
    {
        int kk2 = tid >> 3, h2 = tid & 7;
        int j2 = idxS[kk2];
        const short8* ksrc = reinterpret_cast<const short8*>(kvb + (size_t)j2 * 512 + h2 * 32);
        pk0 = ksrc[0]; pk1 = ksrc[1]; pk2 = ksrc[2]; pk3 = ksrc[3];
        const unsigned short* kpb = reinterpret_cast<const unsigned short*>(kvpgh) + (size_t)j2 * 384 + h2 * 24;
        const short8* kpsrc = reinterpret_cast<const short8*>(kpb);
        pq0 = kpsrc[0]; pq1 = kpsrc[1]; pq2 = kpsrc[2];
    }
    {   // V: cols 0..255 (transpose-store the top prefetch)
        int kk = kk_s;
#pragma unroll
        for (int c = 0; c < 8; c++) BigT[(seg * 32 + c) * BTS + kk] = (unsigned short)pv0[c];
#pragma unroll
        for (int c = 0; c < 8; c++) BigT[(seg * 32 + 8 + c) * BTS + kk] = (unsigned short)pv1[c];
#pragma unroll
        for (int c = 0; c < 8; c++) BigT[(seg * 32 + 16 + c) * BTS + kk] = (unsigned short)pv2[c];
#pragma unroll
        for (int c = 0; c < 8; c++) BigT[(seg * 32 + 24 + c) * BTS + kk] = (unsigned short)pv3[c];
    }
    {   // pb = pair @ wbm via MFMA: D[m=kk][n=h], K=64
        int w = tid >> 6;
        if (w < 2) {
            int lane = tid & 63, la = lane & 15, quad = lane >> 4;
            floatx4 c = {0.f, 0.f, 0.f, 0.f};
#pragma unroll
            for (int ks = 0; ks < 2; ks++) {
                short8 a = *reinterpret_cast<const short8*>(&pairR[(w * 16 + la) * PRS + ks * 32 + quad * 8]);
                short8 b = *reinterpret_cast<const short8*>(wbmT + la * 64 + ks * 32 + quad * 8);
                c = __builtin_amdgcn_mfma_f32_16x16x32_bf16(a, b, c, 0, 0, 0);
            }
            if (la < NHEAD) {
#pragma unroll
                for (int r = 0; r < 4; r++)
                    pbS[(w * 16 + quad * 4 + r) * 8 + la] = c[r];
            }
        }
    }
    __syncthreads();

    // ---- logits: qk + d2 from prefetched registers; pb from MFMA; store into pbS in place
    {
        int kk = tid >> 3, h = tid & 7;
        float qk = 0.f;
        const floatx4* qh4 = reinterpret_cast<const floatx4*>(qS + h * 32);
        short8 kvv[4] = {pk0, pk1, pk2, pk3};
#pragma unroll
        for (int e = 0; e < 4; e++) {
            short8 kv = kvv[e];
            floatx4 qa = qh4[2 * e], qb = qh4[2 * e + 1];
            qk += qa[0] * bs2f(kv[0]) + qa[1] * bs2f(kv[1]) + qa[2] * bs2f(kv[2]) + qa[3] * bs2f(kv[3]) +
                  qb[0] * bs2f(kv[4]) + qb[1] * bs2f(kv[5]) + qb[2] * bs2f(kv[6]) + qb[3] * bs2f(kv[7]);
        }
        qk *= 0.17677669529663687f;
        float d2 = 0.f;
        const float* qp = qpS + h * 24;
        float tj[3] = {tjS[kk][0], tjS[kk][1], tjS[kk][2]};
        short8 kpv[3] = {pq0, pq1, pq2};
#pragma unroll
        for (int e8 = 0; e8 < 3; e8++)
#pragma unroll
            for (int c8 = 0; c8 < 8; c8++) {
                int x = e8 * 8 + c8;
                float df = (qp[x] - tj[x % 3]) - bs2f(kpv[e8][c8]);
                d2 += df * df;
            }
        float pb = pbS[kk * 8 + h];
        float lgt = 0.5773502691896258f * (qk + pb - (1.f / 12.f) * spS[h] * d2);
        pbS[kk * 8 + h] = pmS[kk] ? lgt : -1e9f;
    }
    __syncthreads();

    // ---- softmax over kk per head; write att to attb (bf16) AND pbS (f32, for t_j sums)
    if (tid < 64) {
        int h = tid >> 3, sub = tid & 7;
        float m = -INFINITY;
        float lv[4];
#pragma unroll
        for (int q = 0; q < 4; q++) {
            lv[q] = pbS[(sub + 8 * q) * 8 + h];
            m = fmaxf(m, lv[q]);
        }
#pragma unroll
        for (int mk = 1; mk < 8; mk <<= 1) m = fmaxf(m, __shfl_xor(m, mk));
        float s = 0.f, ex[4];
#pragma unroll
        for (int q = 0; q < 4; q++) { ex[q] = __expf(lv[q] - m); s += ex[q]; }
#pragma unroll
        for (int mk = 1; mk < 8; mk <<= 1) s += __shfl_xor(s, mk);
        float invs = 1.f / s;
#pragma unroll
        for (int q = 0; q < 4; q++) {
            int kk = sub + 8 * q;
            float a = pmS[kk] ? ex[q] * invs : 0.f;
            attb[h * 40 + kk] = f2bs(a);
            pbS[kk * 8 + h] = a;
        }
    } else if (tid < 128) {
        int t2 = tid - 64;
        int h2 = 8 + (t2 >> 3);
        int k0 = (t2 & 7) * 4;
#pragma unroll
        for (int q = 0; q < 4; q++) attb[h2 * 40 + k0 + q] = 0;
    }
    __syncthreads();

    int la_ = (tid & 63) & 15, quad_ = (tid & 63) >> 4, w_ = tid >> 6;
    short8 af = *reinterpret_cast<const short8*>(&attb[la_ * 40 + quad_ * 8]);

    // ---- PASS 1: D[16 x 256] = att @ BigT(V); extract o_s diag blocks
#pragma unroll
    for (int n4 = 0; n4 < 4; n4++) {
        int colg = (w_ * 4 + n4) * 16 + la_;
        union { short8 s; unsigned long long u[2]; } bb;
        const unsigned long long* bp = reinterpret_cast<const unsigned long long*>(&BigT[colg * BTS + quad_ * 8]);
        bb.u[0] = bp[0]; bb.u[1] = bp[1];
        floatx4 z = {0.f, 0.f, 0.f, 0.f};
        floatx4 d = __builtin_amdgcn_mfma_f32_16x16x32_bf16(af, bb.s, z, 0, 0, 0);
        int h_req = colg >> 5;
        if (quad_ == (h_req >> 2)) {
#pragma unroll
            for (int r = 0; r < 4; r++)
                if ((h_req & 3) == r) uS.o.ipaS[(h_req << 5) + (colg & 31)] = d[r];
        }
    }
    // att @ t_j (f32): 24 outputs [h][c]
    if (tid < 24) {
        int h = tid / 3, c = tid % 3;
        float s = 0.f;
#pragma unroll
        for (int kk = 0; kk < KNB; kk++) s += pbS[kk * 8 + h] * tjS[kk][c];
        attjS[tid] = s;
    }
    __syncthreads();

    // ---- PASS 2 staging: overwrite BigT cols 0..191 with vp_rel (regs), 192..255 with pair (pairR)
    {
        int kk = kk_s;
#pragma unroll
        for (int c = 0; c < 8; c++) BigT[(seg * 24 + c) * BTS + kk] = (unsigned short)pp0[c];
#pragma unroll
        for (int c = 0; c < 8; c++) BigT[(seg * 24 + 8 + c) * BTS + kk] = (unsigned short)pp1[c];
#pragma unroll
        for (int c = 0; c < 8; c++) BigT[(seg * 24 + 16 + c) * BTS + kk] = (unsigned short)pp2[c];
    }
    // pair transpose, conflict-free mapping: 8 threads/row, 8 cols each (read+write banks spread)
#pragma unroll
    for (int q = 0; q < 8; q++) {
        int row = tid >> 3;                 // 0..31
        int col = (tid & 7) + q * 8;        // 0..63
        BigT[(192 + col) * BTS + row] = pairR[row * PRS + col];
    }
    __syncthreads();

    // ---- PASS 2: D[16 x 256] = att @ BigT(vp|pair); extract optg + o_pr
#pragma unroll
    for (int n4 = 0; n4 < 4; n4++) {
        int colg = (w_ * 4 + n4) * 16 + la_;
        union { short8 s; unsigned long long u[2]; } bb;
        const unsigned long long* bp = reinterpret_cast<const unsigned long long*>(&BigT[colg * BTS + quad_ * 8]);
        bb.u[0] = bp[0]; bb.u[1] = bp[1];
        floatx4 z = {0.f, 0.f, 0.f, 0.f};
        floatx4 d = __builtin_amdgcn_mfma_f32_16x16x32_bf16(af, bb.s, z, 0, 0, 0);
        if (colg < 192) {
            int h_req = colg / 24;
            if (quad_ == (h_req >> 2)) {
#pragma unroll
                for (int r = 0; r < 4; r++)
                    if ((h_req & 3) == r) uS.o.optg[colg] = d[r];
            }
        } else if (quad_ < 2) {
            int c = colg - 192;
#pragma unroll
            for (int r = 0; r < 4; r++)
                uS.o.ipaS[256 + (quad_ * 4 + r) * 64 + c] = d[r];
        }
    }
    __syncthreads();

    // ---- rotate o_pt back to local frame: v = sum(att*vp_rel) + sum(att*t_j) - t_i
    if (tid < 192) {
        int hp = tid / 3, ii = tid % 3;
        int h = hp >> 3;
        float v0 = uS.o.optg[hp * 3 + 0] + attjS[h * 3 + 0] - t0;
        float v1 = uS.o.optg[hp * 3 + 1] + attjS[h * 3 + 1] - t1;
        float v2 = uS.o.optg[hp * 3 + 2] + attjS[h * 3 + 2] - t2;
        uS.o.ipaS[768 + tid] = R[0 + ii] * v0 + R[3 + ii] * v1 + R[6 + ii] * v2;
    }
    __syncthreads();
    if (tid < 64) {
        float a0 = uS.o.ipaS[768 + tid * 3], a1 = uS.o.ipaS[768 + tid * 3 + 1], a2 = uS.o.ipaS[768 + tid * 3 + 2];
        uS.o.ipaS[960 + tid] = sqrtf(a0 * a0 + a1 * a1 + a2 * a2 + 1e-8f);
    }
    __syncthreads();
    for (int u = tid; u < FOUT; u += 256) ipab[(size_t)i * FOUT + u] = F2B(uS.o.ipaS[u]);
}

// Kernel DEF v2: 32 rows/block, 512 threads (8 waves = 2 mtile x 4 par).
// Same block count; 2x waves/CU; halved per-thread accumulator pressure.
__global__ __launch_bounds__(512) void kDEF(const bf16* __restrict__ ipab,
                                            const unsigned short* __restrict__ woT,
                                            const float* __restrict__ bo,
                                            const float* __restrict__ ln2_s,
                                            const float* __restrict__ ln2_o,
                                            const unsigned short* __restrict__ wgT,
                                            const unsigned short* __restrict__ wvmT,
                                            const unsigned short* __restrict__ womT,
                                            float* __restrict__ dlocal,
                                            const float* __restrict__ ln3_s,
                                            const float* __restrict__ ln3_o,
                                            const float* __restrict__ wpos,
                                            const float* __restrict__ lpw,
                                            const float* __restrict__ Rw,
                                            const float* __restrict__ pos,
                                            const int* __restrict__ umask,
                                            float* __restrict__ outp) {
    int r0 = blockIdx.x * 32;
    int tid = threadIdx.x;
    __shared__ __align__(16) unsigned short xbf[32 * 264];
    __shared__ __align__(16) unsigned short hbf[32 * 520];   // reused as f32 x3F[32][259] after GEMM2
    __shared__ float statsS[32 * 8];
    __shared__ float nlS[32][15];
    int lane = tid & 63, w = tid >> 6;
    int mtile = w & 1, par = w >> 1, m = lane & 15, quad = lane >> 4;   // par in 0..3

    // GEMM0: ipa @ wo; each wave: 4 n-tiles, nt = par + 4j
    floatx4 l2[4];
#pragma unroll
    for (int j = 0; j < 4; j++) l2[j] = {0.f, 0.f, 0.f, 0.f};
    const short8* arow = reinterpret_cast<const short8*>(ipab + (size_t)(r0 + mtile * 16 + m) * 1024);
    for (int ks = 0; ks < 32; ks++) {
        short8 a = arow[ks * 4 + quad];
#pragma unroll
        for (int j = 0; j < 4; j++) {
            int nt = par + 4 * j;
            const short8* bp = reinterpret_cast<const short8*>(woT + (size_t)(nt * 16 + m) * 1024);
            l2[j] = __builtin_amdgcn_mfma_f32_16x16x32_bf16(a, bp[ks * 4 + quad], l2[j], 0, 0, 0);
        }
    }
#pragma unroll
    for (int j = 0; j < 4; j++) {
        int colg = (par + 4 * j) * 16 + m;
        float bov = bo[colg];
#pragma unroll
        for (int r = 0; r < 4; r++) {
            int row = mtile * 16 + quad * 4 + r;
            l2[j][r] += dlocal[(size_t)(r0 + row) * 256 + colg] + bov;
        }
    }
    // LN2 stats (4 partials per row)
    {
        float s[4] = {0.f, 0.f, 0.f, 0.f}, ss[4] = {0.f, 0.f, 0.f, 0.f};
#pragma unroll
        for (int j = 0; j < 4; j++)
#pragma unroll
            for (int r = 0; r < 4; r++) { s[r] += l2[j][r]; ss[r] += l2[j][r] * l2[j][r]; }
#pragma unroll
        for (int mask = 1; mask < 16; mask <<= 1)
#pragma unroll
            for (int r = 0; r < 4; r++) { s[r] += __shfl_xor(s[r], mask); ss[r] += __shfl_xor(ss[r], mask); }
        if (m == 0) {
#pragma unroll
            for (int r = 0; r < 4; r++) {
                int row = mtile * 16 + quad * 4 + r;
                statsS[row * 8 + par * 2 + 0] = s[r];
                statsS[row * 8 + par * 2 + 1] = ss[r];
            }
        }
    }
    __syncthreads();
    {
        float mu[4], rs_[4];
#pragma unroll
        for (int r = 0; r < 4; r++) {
            int row = mtile * 16 + quad * 4 + r;
            float S = statsS[row * 8 + 0] + statsS[row * 8 + 2] + statsS[row * 8 + 4] + statsS[row * 8 + 6];
            float SS = statsS[row * 8 + 1] + statsS[row * 8 + 3] + statsS[row * 8 + 5] + statsS[row * 8 + 7];
            float m_ = S * (1.f / 256.f);
            mu[r] = m_;
            rs_[r] = rsqrtf(SS * (1.f / 256.f) - m_ * m_ + 1e-5f);
        }
#pragma unroll
        for (int j = 0; j < 4; j++) {
            int colg = (par + 4 * j) * 16 + m;
            float g = ln2_s[colg], o = ln2_o[colg];
#pragma unroll
            for (int r = 0; r < 4; r++) {
                int row = mtile * 16 + quad * 4 + r;
                xbf[row * 264 + colg] = f2bs((l2[j][r] - mu[r]) * rs_[r] * g + o);
            }
        }
    }
    __syncthreads();
    // GEMM1: x @ [wg|wvm] -> h = gelu(ag)*av  (32 n-tiles, 8 per wave)
    short8 afr[8];
#pragma unroll
    for (int ks = 0; ks < 8; ks++)
        afr[ks] = *reinterpret_cast<const short8*>(&xbf[(mtile * 16 + m) * 264 + ks * 32 + quad * 8]);
    for (int nt = par; nt < 32; nt += 4) {
        floatx4 cg = {0.f, 0.f, 0.f, 0.f};
        floatx4 cv = {0.f, 0.f, 0.f, 0.f};
        const short8* bg = reinterpret_cast<const short8*>(wgT + (size_t)(nt * 16 + m) * 256);
        const short8* bv = reinterpret_cast<const short8*>(wvmT + (size_t)(nt * 16 + m) * 256);
#pragma unroll
        for (int ks = 0; ks < 8; ks++) {
            cg = __builtin_amdgcn_mfma_f32_16x16x32_bf16(afr[ks], bg[ks * 4 + quad], cg, 0, 0, 0);
            cv = __builtin_amdgcn_mfma_f32_16x16x32_bf16(afr[ks], bv[ks * 4 + quad], cv, 0, 0, 0);
        }
#pragma unroll
        for (int r = 0; r < 4; r++) {
            int row = mtile * 16 + quad * 4 + r;
            hbf[row * 520 + nt * 16 + m] = f2bs(gelu_f(cg[r]) * cv[r]);
        }
    }
    __syncthreads();
    // GEMM2: h @ wom; final = l2 + acc  (16 n-tiles, 4 per wave)
    floatx4 acc[4];
#pragma unroll
    for (int j = 0; j < 4; j++) acc[j] = {0.f, 0.f, 0.f, 0.f};
    for (int ks = 0; ks < 16; ks++) {
        short8 a = *reinterpret_cast<const short8*>(&hbf[(mtile * 16 + m) * 520 + ks * 32 + quad * 8]);
#pragma unroll
        for (int j = 0; j < 4; j++) {
            int nt = par + 4 * j;
            const short8* bp = reinterpret_cast<const short8*>(womT + (size_t)(nt * 16 + m) * 512);
            acc[j] = __builtin_amdgcn_mfma_f32_16x16x32_bf16(a, bp[ks * 4 + quad], acc[j], 0, 0, 0);
        }
    }
    // final values: write out_local, keep in regs for LN3
    float fin[4][4];
#pragma unroll
    for (int j = 0; j < 4; j++) {
        int colg = (par + 4 * j) * 16 + m;
#pragma unroll
        for (int r = 0; r < 4; r++) {
            int row = mtile * 16 + quad * 4 + r;
            float fv = l2[j][r] + acc[j][r];
            fin[j][r] = fv;
            dlocal[(size_t)(r0 + row) * 256 + colg] = fv;
        }
    }
    // ---- LN3 stats
    {
        float s[4] = {0.f, 0.f, 0.f, 0.f}, ss[4] = {0.f, 0.f, 0.f, 0.f};
#pragma unroll
        for (int j = 0; j < 4; j++)
#pragma unroll
            for (int r = 0; r < 4; r++) { s[r] += fin[j][r]; ss[r] += fin[j][r] * fin[j][r]; }
#pragma unroll
        for (int mask = 1; mask < 16; mask <<= 1)
#pragma unroll
            for (int r = 0; r < 4; r++) { s[r] += __shfl_xor(s[r], mask); ss[r] += __shfl_xor(ss[r], mask); }
        if (m == 0) {
#pragma unroll
            for (int r = 0; r < 4; r++) {
                int row = mtile * 16 + quad * 4 + r;
                statsS[row * 8 + par * 2 + 0] = s[r];
                statsS[row * 8 + par * 2 + 1] = ss[r];
            }
        }
    }
    __syncthreads();   // also fences hbf reads (GEMM2) before x3F overwrite
    float* x3F = reinterpret_cast<float*>(hbf);   // [32][259] f32 = 33152 B <= 33280 B
    {
        float mu[4], rs_[4];
#pragma unroll
        for (int r = 0; r < 4; r++) {
            int row = mtile * 16 + quad * 4 + r;
            float S = statsS[row * 8 + 0] + statsS[row * 8 + 2] + statsS[row * 8 + 4] + statsS[row * 8 + 6];
            float SS = statsS[row * 8 + 1] + statsS[row * 8 + 3] + statsS[row * 8 + 5] + statsS[row * 8 + 7];
            float m_ = S * (1.f / 256.f);
            mu[r] = m_;
            rs_[r] = rsqrtf(SS * (1.f / 256.f) - m_ * m_ + 1e-5f);
        }
#pragma unroll
        for (int j = 0; j < 4; j++) {
            int colg = (par + 4 * j) * 16 + m;
            float g = ln3_s[colg], o = ln3_o[colg];
#pragma unroll
            for (int r = 0; r < 4; r++) {
                int row = mtile * 16 + quad * 4 + r;
                x3F[row * 259 + colg] = (fin[j][r] - mu[r]) * rs_[r] * g + o;
            }
        }
    }
    __syncthreads();
    // ---- nl = lpw + x3 @ wpos  (480 outputs: row 0..31, e 0..14)
    for (int o = tid; o < 480; o += 512) {
        int row = o & 31, e = o >> 5;
        const float* xr = x3F + row * 259;
        float sum = 0.f;
        for (int f = 0; f < 256; f++) sum += xr[f] * wpos[f * 15 + e];
        nlS[row][e] = lpw[(size_t)(r0 + row) * 15 + e] + sum;
    }
    __syncthreads();
    // ---- frame transform + update_mask
    for (int o = tid; o < 480; o += 512) {
        int row = o & 31, e = o >> 5;
        int rj = r0 + row;
        int a2 = e / 3, ii = e % 3;
        float R0 = Rw[(size_t)rj * 9 + ii * 3 + 0];
        float R1 = Rw[(size_t)rj * 9 + ii * 3 + 1];
        float R2 = Rw[(size_t)rj * 9 + ii * 3 + 2];
        float tt = pos[(size_t)rj * 15 + 3 + ii];
        float np = R0 * nlS[row][a2 * 3 + 0] + R1 * nlS[row][a2 * 3 + 1] + R2 * nlS[row][a2 * 3 + 2] + tt;
        float old = pos[(size_t)rj * 15 + e];
        outp[(size_t)rj * 15 + e] = (umask[rj] != 0) ? np : old;
    }
}

extern "C" void kernel_launch(void* const* d_in, const int* in_sizes, int n_in,
                              void* d_out, int out_size, void* d_ws, size_t ws_size,
                              hipStream_t stream) {
    static const int map_dict[31] = {0, 1, 2, 3, 4, 5, 6, 7, 8, 9, 10, 11, 12, 13, 14, 15,
                                     16, 17, 18, 19, 20, 21, 22, 23, 24, 25, 26, 27, 28, 29, 30};
    static const int map_sig[31] = {0, 1, 25, 26, 27, 28, 29, 30, 2, 3, 4, 5, 6, 7, 8, 9,
                                    10, 11, 12, 13, 14, 15, 16, 17, 18, 19, 20, 21, 22, 23, 24};
    const int* M = (in_sizes[2] == FIN * DMODEL) ? map_sig : map_dict;

    const float* local = (const float*)d_in[M[0]];
    const float* pos = (const float*)d_in[M[1]];
    const int* nbr = (const int*)d_in[M[2]];
    const int* resi = (const int*)d_in[M[3]];
    const int* chain = (const int*)d_in[M[4]];
    const int* batch = (const int*)d_in[M[5]];
    const int* umask = (const int*)d_in[M[6]];
    const int* mask = (const int*)d_in[M[7]];
    const float* w_in = (const float*)d_in[M[8]];
    const float* w_pair = (const float*)d_in[M[9]];
    const float* b_pair = (const float*)d_in[M[10]];
    const float* ln1_s = (const float*)d_in[M[11]];
    const float* ln1_o = (const float*)d_in[M[12]];
    const float* wq = (const float*)d_in[M[13]];
    const float* wk = (const float*)d_in[M[14]];
    const float* wv = (const float*)d_in[M[15]];
    const float* wqp = (const float*)d_in[M[16]];
    const float* wkp = (const float*)d_in[M[17]];
    const float* wvp = (const float*)d_in[M[18]];
    const float* wbm = (const float*)d_in[M[19]];
    const float* gamma = (const float*)d_in[M[20]];
    const float* wo = (const float*)d_in[M[21]];
    const float* bo = (const float*)d_in[M[22]];
    const float* ln2_s = (const float*)d_in[M[23]];
    const float* ln2_o = (const float*)d_in[M[24]];
    const float* wg = (const float*)d_in[M[25]];
    const float* wvm = (const float*)d_in[M[26]];
    const float* wom = (const float*)d_in[M[27]];
    const float* ln3_s = (const float*)d_in[M[28]];
    const float* ln3_o = (const float*)d_in[M[29]];
    const float* wpos = (const float*)d_in[M[30]];

    int N = in_sizes[0] / DMODEL;

    float* out_local = (float*)d_out;
    float* out_pos = out_local + (size_t)N * DMODEL;

    char* wsb = (char*)d_ws;
    float* Rw = (float*)wsb;   wsb += (size_t)N * 9 * 4;
    float* lpw = (float*)wsb;  wsb += (size_t)N * 15 * 4;
    bf16* qbh = (bf16*)wsb;    wsb += (size_t)N * 256 * 2;
    bf16* kvb = (bf16*)wsb;    wsb += (size_t)N * 512 * 2;
    bf16* qpl = (bf16*)wsb;    wsb += (size_t)N * 192 * 2;
    bf16* kpl = (bf16*)wsb;    wsb += (size_t)N * 192 * 2;
    bf16* vpl = (bf16*)wsb;    wsb += (size_t)N * 192 * 2;
    bf16* ipab = (bf16*)wsb;   wsb += (size_t)N * 1024 * 2;
    float* qpg = (float*)wsb;  wsb += (size_t)N * 192 * 4;
    bf16* kvpgh = (bf16*)wsb;  wsb += (size_t)N * 384 * 2;
    unsigned short* featb = (unsigned short*)wsb; wsb += (size_t)N * KPAD * 2;
    unsigned short* wtrans = (unsigned short*)wsb; wsb += (size_t)WT_TOTAL * 2;
    unsigned short* wAllT = wtrans + OFF_WALL;
    unsigned short* woT   = wtrans + OFF_WO;
    unsigned short* wgT   = wtrans + OFF_WG;
    unsigned short* wvmT  = wtrans + OFF_WVM;
    unsigned short* womT  = wtrans + OFF_WOM;
    unsigned short* wpT   = wtrans + OFF_WP;
    unsigned short* winT  = wtrans + OFF_WIN;
    unsigned short* wbmT  = wtrans + OFF_WBM;

    dim3 blk(256);
    dim3 blk512(512);
    hipLaunchKernelGGL(kT, dim3(512), blk, 0, stream, wq, wk, wv, wqp, wkp, wvp,
                       wo, wg, wvm, wom, w_pair, w_in, wbm, wtrans);
    hipLaunchKernelGGL(kA1, dim3(N / 8), blk, 0, stream, pos, Rw, lpw, featb);
    hipLaunchKernelGGL(kB, dim3(N / 32), blk512, 0, stream, local, featb, ln1_s, ln1_o, wAllT, winT,
                       out_local, qbh, kvb, qpl, kpl, vpl);
    hipLaunchKernelGGL(kP, dim3(N / 4), blk, 0, stream, qpl, kpl, vpl, Rw, pos, qpg, kvpgh);
    hipLaunchKernelGGL(kC, dim3(N), blk, 0, stream, pos, nbr, resi, chain, batch, mask, Rw,
                       w_pair, wpT, b_pair, wbmT, gamma, qbh, kvb, qpg, kvpgh, ipab, N);
    hipLaunchKernelGGL(kDEF, dim3(N / 32), blk512, 0, stream, ipab, woT, bo, ln2_s, ln2_o,
                       wgT, wvmT, womT, out_local, ln3_s, ln3_o, wpos, lpw, Rw, pos, umask, out_pos);
}

// Round 12
// 594.675 us; speedup vs baseline: 1.0907x; 1.0083x over previous
//
#include <hip/hip_runtime.h>
#include <hip/hip_bf16.h>
#include <math.h>

#define DMODEL 256
#define KNB 32
#define NHEAD 8
#define FIN 95
#define FPD 95        // dense part of pair features
#define KPAD 104      // padded K for pair/feat MFMA staging
#define FOUT 1024
#define DHID 512
#define BTS 36        // BigT kk-stride (pad 32->36: 8B-aligned frags, no 16-way banks)
#define PRS 72        // pairR row stride (144B: 16B-aligned b128 frags)

typedef __hip_bfloat16 bf16;
typedef __attribute__((ext_vector_type(8))) short short8;
typedef __attribute__((ext_vector_type(4))) float floatx4;

__device__ inline float B2F(bf16 x) { return __bfloat162float(x); }
__device__ inline bf16 F2B(float x) { return __float2bfloat16(x); }
__device__ inline unsigned short f2bs(float x) {
    bf16 h = __float2bfloat16(x);
    return *reinterpret_cast<unsigned short*>(&h);
}
__device__ inline float bs2f(short s) {
    return __uint_as_float(((unsigned)(unsigned short)s) << 16);
}

// fast gelu: tanh(y) = 1 - 2/(1+e^{2y}); e^{2y} via __expf (v_exp)
__device__ inline float gelu_f(float x) {
    float u = 1.5957691216057308f * x * (1.f + 0.044715f * x * x);   // 2*0.79788456*(x+0.044715x^3)
    float t = 1.f - 2.f / (1.f + __expf(u));
    return 0.5f * x * (1.f + t);
}

// ---- weight transpose buffer layout (bf16 elements) ----
#define OFF_WALL 0          // [1344][256]  q|k|v|qp|kp|vp columns
#define OFF_WO   344064     // [256][1024]
#define OFF_WG   606208     // [512][256]
#define OFF_WVM  737280     // [512][256]
#define OFF_WOM  868352     // [256][512]
#define OFF_WP   999424     // [64][KPAD]
#define OFF_WIN  1006080    // [256][KPAD]  w_in transposed
#define OFF_WBM  1032704    // [16][64]     wbm transposed (heads 8..15 zero)
#define WT_TOTAL 1033728

// Kernel T: transpose/convert all weights to bf16 [n][k] (k-contiguous)
__global__ __launch_bounds__(256) void kT(const float* __restrict__ wq, const float* __restrict__ wk,
                                          const float* __restrict__ wv, const float* __restrict__ wqp,
                                          const float* __restrict__ wkp, const float* __restrict__ wvp,
                                          const float* __restrict__ wo, const float* __restrict__ wg,
                                          const float* __restrict__ wvm, const float* __restrict__ wom,
                                          const float* __restrict__ w_pair, const float* __restrict__ w_in,
                                          const float* __restrict__ wbm,
                                          unsigned short* __restrict__ wt) {
    int stride = gridDim.x * 256;
    for (int e = blockIdx.x * 256 + threadIdx.x; e < WT_TOTAL; e += stride) {
        float v;
        if (e < OFF_WO) {
            int n = e >> 8, k = e & 255;
            if (n < 256) v = wq[k * 256 + n];
            else if (n < 512) v = wk[k * 256 + n - 256];
            else if (n < 768) v = wv[k * 256 + n - 512];
            else if (n < 960) v = wqp[k * 192 + n - 768];
            else if (n < 1152) v = wkp[k * 192 + n - 960];
            else v = wvp[k * 192 + n - 1152];
        } else if (e < OFF_WG) {
            int u = e - OFF_WO; int n = u >> 10, k = u & 1023;
            v = wo[k * 256 + n];
        } else if (e < OFF_WVM) {
            int u = e - OFF_WG; int n = u >> 8, k = u & 255;
            v = wg[k * 512 + n];
        } else if (e < OFF_WOM) {
            int u = e - OFF_WVM; int n = u >> 8, k = u & 255;
            v = wvm[k * 512 + n];
        } else if (e < OFF_WP) {
            int u = e - OFF_WOM; int n = u >> 9, k = u & 511;
            v = wom[k * 256 + n];
        } else if (e < OFF_WIN) {
            int u = e - OFF_WP; int n = u / KPAD, k = u % KPAD;
            v = (k < FPD) ? w_pair[k * 64 + n] : 0.f;
        } else if (e < OFF_WBM) {
            int u = e - OFF_WIN; int n = u / KPAD, k = u % KPAD;
            v = (k < FIN) ? w_in[k * 256 + n] : 0.f;
        } else {
            int u = e - OFF_WBM; int n = u >> 6, k = u & 63;
            v = (n < NHEAD) ? wbm[k * 8 + n] : 0.f;
        }
        wt[e] = f2bs(v);
    }
}

// Kernel B v4: frames+feat (ex-kA1) computed in-block into featA LDS (no featb round-trip),
// then lup GEMM + LN1 + projections. 32 rows/block, 512 threads (8 waves).
__global__ __launch_bounds__(512) void kB(const float* __restrict__ local,
                                          const float* __restrict__ pos,
                                          const float* __restrict__ ln1_s,
                                          const float* __restrict__ ln1_o,
                                          const unsigned short* __restrict__ wAllT,
                                          const unsigned short* __restrict__ w_inT,
                                          float* __restrict__ Rw,
                                          float* __restrict__ lpw,
                                          float* __restrict__ dlocal,
                                          bf16* __restrict__ qbh, bf16* __restrict__ kvb,
                                          bf16* __restrict__ qpl, bf16* __restrict__ kpl,
                                          bf16* __restrict__ vpl) {
    int r0 = blockIdx.x * 32;
    int tid = threadIdx.x;
    __shared__ __align__(16) unsigned short featA[32 * KPAD];
    __shared__ __align__(16) unsigned short xbf[32 * 264];
    __shared__ float statsS[32 * 8];
    __shared__ float lpS[32][15];
    __shared__ float ddS[32][5], dinvS[32][5];

    // ---- phase A: frames + feat (ex-kA1), 16 threads per residue
    {
        int res = tid >> 4, lt = tid & 15;
        int ri = r0 + res;
        const float* pp = pos + (size_t)ri * 15;
        float nx = pp[0], ny = pp[1], nz = pp[2];
        float cax = pp[3], cay = pp[4], caz = pp[5];
        float cx = pp[6], cy = pp[7], cz = pp[8];
        float e1x = cx - cax, e1y = cy - cay, e1z = cz - caz;
        float inv = rsqrtf(e1x * e1x + e1y * e1y + e1z * e1z + 1e-6f);
        e1x *= inv; e1y *= inv; e1z *= inv;
        float ux = nx - cax, uy = ny - cay, uz = nz - caz;
        float d = ux * e1x + uy * e1y + uz * e1z;
        float wx = ux - d * e1x, wy = uy - d * e1y, wz = uz - d * e1z;
        inv = rsqrtf(wx * wx + wy * wy + wz * wz + 1e-6f);
        float e2x = wx * inv, e2y = wy * inv, e2z = wz * inv;
        float e3x = e1y * e2z - e1z * e2y;
        float e3y = e1z * e2x - e1x * e2z;
        float e3z = e1x * e2y - e1y * e2x;
        float R[9] = {e1x, e2x, e3x, e1y, e2y, e3y, e1z, e2z, e3z};

        if (lt < 9) Rw[(size_t)ri * 9 + lt] = R[lt];
        if (lt < 15) {
            int a = lt / 3, ii = lt % 3;
            float px = pp[a * 3 + 0] - cax, py = pp[a * 3 + 1] - cay, pz = pp[a * 3 + 2] - caz;
            float v = R[0 * 3 + ii] * px + R[1 * 3 + ii] * py + R[2 * 3 + ii] * pz;
            lpS[res][lt] = v;
            lpw[(size_t)ri * 15 + lt] = v;
        }
        __syncthreads();
        if (lt < 5) {
            float s = lpS[res][lt * 3] * lpS[res][lt * 3] + lpS[res][lt * 3 + 1] * lpS[res][lt * 3 + 1] +
                      lpS[res][lt * 3 + 2] * lpS[res][lt * 3 + 2];
            ddS[res][lt] = sqrtf(s + 1e-12f);
            dinvS[res][lt] = rsqrtf(s + 1e-6f);
        }
        __syncthreads();
        for (int e = lt; e < KPAD; e += 16) {
            float v;
            if (e < 15) v = lpS[res][e] * dinvS[res][e / 3];
            else if (e < 95) {
                int u = e - 15, a = u >> 4, b = u & 15;
                float z = (ddS[res][a] - (float)b * (10.f / 15.f)) * (1.f / 0.625f);
                v = __expf(-z * z);
            } else v = 0.f;
            featA[res * KPAD + e] = f2bs(v);
        }
    }
    __syncthreads();

    int lane = tid & 63, w = tid >> 6;
    int mtile = w & 1, par = w >> 1;          // par in 0..3
    int m = lane & 15, quad = lane >> 4;

    short8 fa[3];
#pragma unroll
    for (int ks = 0; ks < 3; ks++)
        fa[ks] = *reinterpret_cast<const short8*>(&featA[(mtile * 16 + m) * KPAD + ks * 32 + quad * 8]);
    float lupv[4][4];
#pragma unroll
    for (int j = 0; j < 4; j++) {
        int nt = par + 4 * j;
        floatx4 c = {0.f, 0.f, 0.f, 0.f};
        const short8* bp = reinterpret_cast<const short8*>(w_inT + (size_t)(nt * 16 + m) * KPAD);
#pragma unroll
        for (int ks = 0; ks < 3; ks++)
            c = __builtin_amdgcn_mfma_f32_16x16x32_bf16(fa[ks], bp[ks * 4 + quad], c, 0, 0, 0);
        int col = nt * 16 + m;
#pragma unroll
        for (int r = 0; r < 4; r++) {
            int row = mtile * 16 + quad * 4 + r;
            float lv = local[(size_t)(r0 + row) * 256 + col] + c[r];
            lupv[j][r] = lv;
            dlocal[(size_t)(r0 + row) * 256 + col] = lv;
        }
    }
    {
        float s[4] = {0.f, 0.f, 0.f, 0.f}, ss[4] = {0.f, 0.f, 0.f, 0.f};
#pragma unroll
        for (int j = 0; j < 4; j++)
#pragma unroll
            for (int r = 0; r < 4; r++) { s[r] += lupv[j][r]; ss[r] += lupv[j][r] * lupv[j][r]; }
#pragma unroll
        for (int mask = 1; mask < 16; mask <<= 1)
#pragma unroll
            for (int r = 0; r < 4; r++) { s[r] += __shfl_xor(s[r], mask); ss[r] += __shfl_xor(ss[r], mask); }
        if (m == 0) {
#pragma unroll
            for (int r = 0; r < 4; r++) {
                int row = mtile * 16 + quad * 4 + r;
                statsS[row * 8 + par * 2 + 0] = s[r];
                statsS[row * 8 + par * 2 + 1] = ss[r];
            }
        }
    }
    __syncthreads();
    {
        float mu[4], rs_[4];
#pragma unroll
        for (int r = 0; r < 4; r++) {
            int row = mtile * 16 + quad * 4 + r;
            float S = statsS[row * 8 + 0] + statsS[row * 8 + 2] + statsS[row * 8 + 4] + statsS[row * 8 + 6];
            float SS = statsS[row * 8 + 1] + statsS[row * 8 + 3] + statsS[row * 8 + 5] + statsS[row * 8 + 7];
            float m_ = S * (1.f / 256.f);
            mu[r] = m_;
            rs_[r] = rsqrtf(SS * (1.f / 256.f) - m_ * m_ + 1e-5f);
        }
#pragma unroll
        for (int j = 0; j < 4; j++) {
            int col = (par + 4 * j) * 16 + m;
            float g = ln1_s[col], o = ln1_o[col];
#pragma unroll
            for (int r = 0; r < 4; r++) {
                int row = mtile * 16 + quad * 4 + r;
                xbf[row * 264 + col] = f2bs((lupv[j][r] - mu[r]) * rs_[r] * g + o);
            }
        }
    }
    __syncthreads();

    short8 afr[8];
#pragma unroll
    for (int ks = 0; ks < 8; ks++)
        afr[ks] = *reinterpret_cast<const short8*>(&xbf[(mtile * 16 + m) * 264 + ks * 32 + quad * 8]);
    for (int nt = par; nt < 84; nt += 4) {
        floatx4 c = {0.f, 0.f, 0.f, 0.f};
        const short8* bp = reinterpret_cast<const short8*>(wAllT + (size_t)(nt * 16 + m) * 256);
#pragma unroll
        for (int ks = 0; ks < 8; ks++)
            c = __builtin_amdgcn_mfma_f32_16x16x32_bf16(afr[ks], bp[ks * 4 + quad], c, 0, 0, 0);
        int colg = nt * 16 + m;
        bf16* O; int c0, ncol;
        if (colg < 256)       { O = qbh; c0 = colg;        ncol = 256; }
        else if (colg < 768)  { O = kvb; c0 = colg - 256;  ncol = 512; }
        else if (colg < 960)  { O = qpl; c0 = colg - 768;  ncol = 192; }
        else if (colg < 1152) { O = kpl; c0 = colg - 960;  ncol = 192; }
        else                  { O = vpl; c0 = colg - 1152; ncol = 192; }
#pragma unroll
        for (int r = 0; r < 4; r++) {
            int rg = r0 + mtile * 16 + quad * 4 + r;
            O[(size_t)rg * ncol + c0] = F2B(c[r]);
        }
    }
}

// Kernel P: rotate local-frame points to global frame.
__global__ __launch_bounds__(256) void kP(const bf16* __restrict__ qpl,
                                          const bf16* __restrict__ kpl,
                                          const bf16* __restrict__ vpl,
                                          const float* __restrict__ Rw,
                                          const float* __restrict__ pos,
                                          float* __restrict__ qpg,
                                          bf16* __restrict__ kvpgh) {
    int r0 = blockIdx.x * 4;
    int tid = threadIdx.x;
    for (int u = tid; u < 4 * 192; u += 256) {
        int r = u / 192, e = u % 192, hp = e / 3, ii = e % 3;
        int ri = r0 + r;
        float R0 = Rw[(size_t)ri * 9 + ii * 3 + 0];
        float R1 = Rw[(size_t)ri * 9 + ii * 3 + 1];
        float R2 = Rw[(size_t)ri * 9 + ii * 3 + 2];
        float tt = pos[(size_t)ri * 15 + 3 + ii];
        size_t base = (size_t)ri * 192 + hp * 3;
        qpg[(size_t)ri * 192 + e] = R0 * B2F(qpl[base]) + R1 * B2F(qpl[base + 1]) + R2 * B2F(qpl[base + 2]) + tt;
        kvpgh[(size_t)ri * 384 + e] = F2B(R0 * B2F(kpl[base]) + R1 * B2F(kpl[base + 1]) + R2 * B2F(kpl[base + 2]));
        kvpgh[(size_t)ri * 384 + 192 + e] = F2B(R0 * B2F(vpl[base]) + R1 * B2F(vpl[base + 1]) + R2 * B2F(vpl[base + 2]));
    }
}

// Kernel C v6 (unchanged; best measured 216.8-230us clock-dependent).
__global__ __launch_bounds__(256, 4) void kC(const float* __restrict__ pos,
                                          const int* __restrict__ nbr,
                                          const int* __restrict__ resi,
                                          const int* __restrict__ chain,
                                          const int* __restrict__ batch,
                                          const int* __restrict__ mask,
                                          const float* __restrict__ Rw,
                                          const float* __restrict__ w_pair,
                                          const unsigned short* __restrict__ wT,
                                          const float* __restrict__ b_pair,
                                          const unsigned short* __restrict__ wbmT,
                                          const float* __restrict__ gamma,
                                          const bf16* __restrict__ qbh,
                                          const bf16* __restrict__ kvb,
                                          const float* __restrict__ qpg,
                                          const bf16* __restrict__ kvpgh,
                                          bf16* __restrict__ ipab,
                                          int N) {
    int i = blockIdx.x;
    int tid = threadIdx.x;
    __shared__ __align__(16) unsigned short BigT[256 * BTS];
    __shared__ __align__(16) unsigned short pairR[32 * PRS];
    __shared__ __align__(16) unsigned short attb[16 * 40];
    __shared__ __align__(16) float qS[256];
    __shared__ __align__(16) float qpS[192];
    __shared__ __align__(16) float pbS[256];     // pb -> logits -> att (f32), all in place
    __shared__ float spS[NHEAD];
    __shared__ float tjS[KNB][3];
    __shared__ float attjS[24];
    __shared__ int idxS[KNB], rpS[KNB], scS[KNB], sbS[KNB], pmS[KNB];
    __shared__ __align__(16) union UShare {
        unsigned short pfA[32 * KPAD];                    // 6656 B, dies after pair MLP
        struct { float ipaS[FOUT]; float optg[192]; } o;  // 4864 B, born at pass-1 extraction
    } uS;

    // ---- top-of-kernel prefetch of the v / vp_rel gathers (v consumed in staging, vp in pass 2)
    int kk_s = tid & 31, seg = tid >> 5;
    int jpre;
    {
        int nb = nbr[(size_t)i * KNB + kk_s];
        jpre = min(max(nb, 0), N - 1);
    }
    short8 pv0, pv1, pv2, pv3, pp0, pp1, pp2;
    {
        const short8* vsrc = reinterpret_cast<const short8*>(kvb + (size_t)jpre * 512 + 256 + seg * 32);
        pv0 = vsrc[0]; pv1 = vsrc[1]; pv2 = vsrc[2]; pv3 = vsrc[3];
        const unsigned short* vpb = reinterpret_cast<const unsigned short*>(kvpgh) + (size_t)jpre * 384 + 192 + seg * 24;
        const short8* vpsrc = reinterpret_cast<const short8*>(vpb);
        pp0 = vpsrc[0]; pp1 = vpsrc[1]; pp2 = vpsrc[2];
    }

    float R[9];
#pragma unroll
    for (int u = 0; u < 9; u++) R[u] = Rw[(size_t)i * 9 + u];
    float t0 = pos[(size_t)i * 15 + 3];
    float t1 = pos[(size_t)i * 15 + 4];
    float t2 = pos[(size_t)i * 15 + 5];

    qS[tid] = B2F(qbh[(size_t)i * 256 + tid]);
    if (tid < 192) qpS[tid] = qpg[(size_t)i * 192 + tid];
    if (tid < NHEAD) spS[tid] = log1pf(__expf(gamma[tid]));
    if (tid < KNB) {
        int nb = nbr[(size_t)i * KNB + tid];
        int j = min(max(nb, 0), N - 1);
        idxS[tid] = j;
        int rp = resi[j] - resi[i];
        rp = min(max(rp, -32), 32) + 32;
        rpS[tid] = rp;
        scS[tid] = (chain[j] == chain[i]) ? 1 : 0;
        sbS[tid] = (batch[j] == batch[i]) ? 1 : 0;
        pmS[tid] = (mask[i] != 0 && mask[j] != 0 && nb >= 0 && batch[j] == batch[i]) ? 1 : 0;
    }
    __syncthreads();
    if (tid < 160) {
        int kk = tid & 31, a = tid >> 5;
        int j = idxS[kk];
        const float* pj = pos + (size_t)j * 15 + a * 3;
        float pj0 = pj[0], pj1 = pj[1], pj2 = pj[2];
        if (a == 1) { tjS[kk][0] = pj0; tjS[kk][1] = pj1; tjS[kk][2] = pj2; }   // t_j = CA of j
        float px = pj0 - t0, py = pj1 - t1, pz = pj2 - t2;
        float r0_ = R[0] * px + R[3] * py + R[6] * pz;
        float r1_ = R[1] * px + R[4] * py + R[7] * pz;
        float r2_ = R[2] * px + R[5] * py + R[8] * pz;
        float s = r0_ * r0_ + r1_ * r1_ + r2_ * r2_;
        float dij = sqrtf(s + 1e-12f);
        float di = 1.f / (dij + 1e-6f);
        uS.pfA[kk * KPAD + a * 3 + 0] = f2bs(r0_ * di);
        uS.pfA[kk * KPAD + a * 3 + 1] = f2bs(r1_ * di);
        uS.pfA[kk * KPAD + a * 3 + 2] = f2bs(r2_ * di);
        for (int b = 0; b < 16; b++) {
            float z = (dij - (float)b * (10.f / 15.f)) * (1.f / 0.625f);
            uS.pfA[kk * KPAD + 15 + a * 16 + b] = f2bs(__expf(-z * z));
        }
    }
    if (tid < KNB) uS.pfA[tid * KPAD + FPD] = 0;
    __syncthreads();

    // ---- pair MLP via MFMA; epilogue writes pairR (row-major)
    {
        int lane = tid & 63;
        int wv = tid >> 6;
        int n0 = wv * 16;
        int mrow = lane & 15;
        int quad = lane >> 4;
        floatx4 c0 = {0.f, 0.f, 0.f, 0.f};
        floatx4 c1 = {0.f, 0.f, 0.f, 0.f};
#pragma unroll
        for (int ks = 0; ks < 3; ks++) {
            int k0 = ks * 32 + quad * 8;
            short8 a0 = *reinterpret_cast<const short8*>(&uS.pfA[mrow * KPAD + k0]);
            short8 a1 = *reinterpret_cast<const short8*>(&uS.pfA[(16 + mrow) * KPAD + k0]);
            short8 bb = *reinterpret_cast<const short8*>(&wT[(n0 + mrow) * KPAD + k0]);
            c0 = __builtin_amdgcn_mfma_f32_16x16x32_bf16(a0, bb, c0, 0, 0, 0);
            c1 = __builtin_amdgcn_mfma_f32_16x16x32_bf16(a1, bb, c1, 0, 0, 0);
        }
        int col = n0 + mrow;
        float bp = b_pair[col];
        float w160 = w_pair[160 * 64 + col];
        float w161 = w_pair[161 * 64 + col];
#pragma unroll
        for (int mt = 0; mt < 2; mt++) {
            floatx4 cc = mt ? c1 : c0;
#pragma unroll
            for (int r = 0; r < 4; r++) {
                int row = mt * 16 + quad * 4 + r;
                float s = cc[r] + bp + w_pair[(95 + rpS[row]) * 64 + col] +
                          (scS[row] ? w160 : 0.f) + (sbS[row] ? w161 : 0.f);
                pairR[row * PRS + col] = f2bs(gelu_f(s));
            }
        }
    }
    __syncthreads();

    // ---- staging phase: prefetch k/kp for logits, write prefetched V to BigT, pb MFMA
    short8 pk0, pk1, pk2, pk3, pq0, pq1, pq2;
    {
        int kk2 = tid >> 3, h2 = tid & 7;
        int j2 = idxS[kk2];
        const short8* ksrc = reinterpret_cast<const short8*>(kvb + (size_t)j2 * 512 + h2 * 32);
        pk0 = ksrc[0]; pk1 = ksrc[1]; pk2 = ksrc[2]; pk3 = ksrc[3];
        const unsigned short* kpb = reinterpret_cast<const unsigned short*>(kvpgh) + (size_t)j2 * 384 + h2 * 24;
        const short8* kpsrc = reinterpret_cast<const short8*>(kpb);
        pq0 = kpsrc[0]; pq1 = kpsrc[1]; pq2 = kpsrc[2];
    }
    {   // V: cols 0..255 (transpose-store the top prefetch)
        int kk = kk_s;
#pragma unroll
        for (int c = 0; c < 8; c++) BigT[(seg * 32 + c) * BTS + kk] = (unsigned short)pv0[c];
#pragma unroll
        for (int c = 0; c < 8; c++) BigT[(seg * 32 + 8 + c) * BTS + kk] = (unsigned short)pv1[c];
#pragma unroll
        for (int c = 0; c < 8; c++) BigT[(seg * 32 + 16 + c) * BTS + kk] = (unsigned short)pv2[c];
#pragma unroll
        for (int c = 0; c < 8; c++) BigT[(seg * 32 + 24 + c) * BTS + kk] = (unsigned short)pv3[c];
    }
    {   // pb = pair @ wbm via MFMA: D[m=kk][n=h], K=64
        int w = tid >> 6;
        if (w < 2) {
            int lane = tid & 63, la = lane & 15, quad = lane >> 4;
            floatx4 c = {0.f, 0.f, 0.f, 0.f};
#pragma unroll
            for (int ks = 0; ks < 2; ks++) {
                short8 a = *reinterpret_cast<const short8*>(&pairR[(w * 16 + la) * PRS + ks * 32 + quad * 8]);
                short8 b = *reinterpret_cast<const short8*>(wbmT + la * 64 + ks * 32 + quad * 8);
                c = __builtin_amdgcn_mfma_f32_16x16x32_bf16(a, b, c, 0, 0, 0);
            }
            if (la < NHEAD) {
#pragma unroll
                for (int r = 0; r < 4; r++)
                    pbS[(w * 16 + quad * 4 + r) * 8 + la] = c[r];
            }
        }
    }
    __syncthreads();

    // ---- logits: qk + d2 from prefetched registers; pb from MFMA; store into pbS in place
    {
        int kk = tid >> 3, h = tid & 7;
        float qk = 0.f;
        const floatx4* qh4 = reinterpret_cast<const floatx4*>(qS + h * 32);
        short8 kvv[4] = {pk0, pk1, pk2, pk3};
#pragma unroll
        for (int e = 0; e < 4; e++) {
            short8 kv = kvv[e];
            floatx4 qa = qh4[2 * e], qb = qh4[2 * e + 1];
            qk += qa[0] * bs2f(kv[0]) + qa[1] * bs2f(kv[1]) + qa[2] * bs2f(kv[2]) + qa[3] * bs2f(kv[3]) +
                  qb[0] * bs2f(kv[4]) + qb[1] * bs2f(kv[5]) + qb[2] * bs2f(kv[6]) + qb[3] * bs2f(kv[7]);
        }
        qk *= 0.17677669529663687f;
        float d2 = 0.f;
        const float* qp = qpS + h * 24;
        float tj[3] = {tjS[kk][0], tjS[kk][1], tjS[kk][2]};
        short8 kpv[3] = {pq0, pq1, pq2};
#pragma unroll
        for (int e8 = 0; e8 < 3; e8++)
#pragma unroll
            for (int c8 = 0; c8 < 8; c8++) {
                int x = e8 * 8 + c8;
                float df = (qp[x] - tj[x % 3]) - bs2f(kpv[e8][c8]);
                d2 += df * df;
            }
        float pb = pbS[kk * 8 + h];
        float lgt = 0.5773502691896258f * (qk + pb - (1.f / 12.f) * spS[h] * d2);
        pbS[kk * 8 + h] = pmS[kk] ? lgt : -1e9f;
    }
    __syncthreads();

    // ---- softmax over kk per head; write att to attb (bf16) AND pbS (f32, for t_j sums)
    if (tid < 64) {
        int h = tid >> 3, sub = tid & 7;
        float m = -INFINITY;
        float lv[4];
#pragma unroll
        for (int q = 0; q < 4; q++) {
            lv[q] = pbS[(sub + 8 * q) * 8 + h];
            m = fmaxf(m, lv[q]);
        }
#pragma unroll
        for (int mk = 1; mk < 8; mk <<= 1) m = fmaxf(m, __shfl_xor(m, mk));
        float s = 0.f, ex[4];
#pragma unroll
        for (int q = 0; q < 4; q++) { ex[q] = __expf(lv[q] - m); s += ex[q]; }
#pragma unroll
        for (int mk = 1; mk < 8; mk <<= 1) s += __shfl_xor(s, mk);
        float invs = 1.f / s;
#pragma unroll
        for (int q = 0; q < 4; q++) {
            int kk = sub + 8 * q;
            float a = pmS[kk] ? ex[q] * invs : 0.f;
            attb[h * 40 + kk] = f2bs(a);
            pbS[kk * 8 + h] = a;
        }
    } else if (tid < 128) {
        int t2 = tid - 64;
        int h2 = 8 + (t2 >> 3);
        int k0 = (t2 & 7) * 4;
#pragma unroll
        for (int q = 0; q < 4; q++) attb[h2 * 40 + k0 + q] = 0;
    }
    __syncthreads();

    int la_ = (tid & 63) & 15, quad_ = (tid & 63) >> 4, w_ = tid >> 6;
    short8 af = *reinterpret_cast<const short8*>(&attb[la_ * 40 + quad_ * 8]);

    // ---- PASS 1: D[16 x 256] = att @ BigT(V); extract o_s diag blocks
#pragma unroll
    for (int n4 = 0; n4 < 4; n4++) {
        int colg = (w_ * 4 + n4) * 16 + la_;
        union { short8 s; unsigned long long u[2]; } bb;
        const unsigned long long* bp = reinterpret_cast<const unsigned long long*>(&BigT[colg * BTS + quad_ * 8]);
        bb.u[0] = bp[0]; bb.u[1] = bp[1];
        floatx4 z = {0.f, 0.f, 0.f, 0.f};
        floatx4 d = __builtin_amdgcn_mfma_f32_16x16x32_bf16(af, bb.s, z, 0, 0, 0);
        int h_req = colg >> 5;
        if (quad_ == (h_req >> 2)) {
#pragma unroll
            for (int r = 0; r < 4; r++)
                if ((h_req & 3) == r) uS.o.ipaS[(h_req << 5) + (colg & 31)] = d[r];
        }
    }
    // att @ t_j (f32): 24 outputs [h][c]
    if (tid < 24) {
        int h = tid / 3, c = tid % 3;
        float s = 0.f;
#pragma unroll
        for (int kk = 0; kk < KNB; kk++) s += pbS[kk * 8 + h] * tjS[kk][c];
        attjS[tid] = s;
    }
    __syncthreads();

    // ---- PASS 2 staging: overwrite BigT cols 0..191 with vp_rel (regs), 192..255 with pair (pairR)
    {
        int kk = kk_s;
#pragma unroll
        for (int c = 0; c < 8; c++) BigT[(seg * 24 + c) * BTS + kk] = (unsigned short)pp0[c];
#pragma unroll
        for (int c = 0; c < 8; c++) BigT[(seg * 24 + 8 + c) * BTS + kk] = (unsigned short)pp1[c];
#pragma unroll
        for (int c = 0; c < 8; c++) BigT[(seg * 24 + 16 + c) * BTS + kk] = (unsigned short)pp2[c];
    }
    // pair transpose, conflict-free mapping: 8 threads/row, 8 cols each (read+write banks spread)
#pragma unroll
    for (int q = 0; q < 8; q++) {
        int row = tid >> 3;                 // 0..31
        int col = (tid & 7) + q * 8;        // 0..63
        BigT[(192 + col) * BTS + row] = pairR[row * PRS + col];
    }
    __syncthreads();

    // ---- PASS 2: D[16 x 256] = att @ BigT(vp|pair); extract optg + o_pr
#pragma unroll
    for (int n4 = 0; n4 < 4; n4++) {
        int colg = (w_ * 4 + n4) * 16 + la_;
        union { short8 s; unsigned long long u[2]; } bb;
        const unsigned long long* bp = reinterpret_cast<const unsigned long long*>(&BigT[colg * BTS + quad_ * 8]);
        bb.u[0] = bp[0]; bb.u[1] = bp[1];
        floatx4 z = {0.f, 0.f, 0.f, 0.f};
        floatx4 d = __builtin_amdgcn_mfma_f32_16x16x32_bf16(af, bb.s, z, 0, 0, 0);
        if (colg < 192) {
            int h_req = colg / 24;
            if (quad_ == (h_req >> 2)) {
#pragma unroll
                for (int r = 0; r < 4; r++)
                    if ((h_req & 3) == r) uS.o.optg[colg] = d[r];
            }
        } else if (quad_ < 2) {
            int c = colg - 192;
#pragma unroll
            for (int r = 0; r < 4; r++)
                uS.o.ipaS[256 + (quad_ * 4 + r) * 64 + c] = d[r];
        }
    }
    __syncthreads();

    // ---- rotate o_pt back to local frame: v = sum(att*vp_rel) + sum(att*t_j) - t_i
    if (tid < 192) {
        int hp = tid / 3, ii = tid % 3;
        int h = hp >> 3;
        float v0 = uS.o.optg[hp * 3 + 0] + attjS[h * 3 + 0] - t0;
        float v1 = uS.o.optg[hp * 3 + 1] + attjS[h * 3 + 1] - t1;
        float v2 = uS.o.optg[hp * 3 + 2] + attjS[h * 3 + 2] - t2;
        uS.o.ipaS[768 + tid] = R[0 + ii] * v0 + R[3 + ii] * v1 + R[6 + ii] * v2;
    }
    __syncthreads();
    if (tid < 64) {
        float a0 = uS.o.ipaS[768 + tid * 3], a1 = uS.o.ipaS[768 + tid * 3 + 1], a2 = uS.o.ipaS[768 + tid * 3 + 2];
        uS.o.ipaS[960 + tid] = sqrtf(a0 * a0 + a1 * a1 + a2 * a2 + 1e-8f);
    }
    __syncthreads();
    for (int u = tid; u < FOUT; u += 256) ipab[(size_t)i * FOUT + u] = F2B(uS.o.ipaS[u]);
}

// Kernel DEF v2 (unchanged from round 11): 32 rows/block, 512 threads.
__global__ __launch_bounds__(512) void kDEF(const bf16* __restrict__ ipab,
                                            const unsigned short* __restrict__ woT,
                                            const float* __restrict__ bo,
                                            const float* __restrict__ ln2_s,
                                            const float* __restrict__ ln2_o,
                                            const unsigned short* __restrict__ wgT,
                                            const unsigned short* __restrict__ wvmT,
                                            const unsigned short* __restrict__ womT,
                                            float* __restrict__ dlocal,
                                            const float* __restrict__ ln3_s,
                                            const float* __restrict__ ln3_o,
                                            const float* __restrict__ wpos,
                                            const float* __restrict__ lpw,
                                            const float* __restrict__ Rw,
                                            const float* __restrict__ pos,
                                            const int* __restrict__ umask,
                                            float* __restrict__ outp) {
    int r0 = blockIdx.x * 32;
    int tid = threadIdx.x;
    __shared__ __align__(16) unsigned short xbf[32 * 264];
    __shared__ __align__(16) unsigned short hbf[32 * 520];   // reused as f32 x3F[32][259] after GEMM2
    __shared__ float statsS[32 * 8];
    __shared__ float nlS[32][15];
    int lane = tid & 63, w = tid >> 6;
    int mtile = w & 1, par = w >> 1, m = lane & 15, quad = lane >> 4;   // par in 0..3

    // GEMM0: ipa @ wo; each wave: 4 n-tiles, nt = par + 4j
    floatx4 l2[4];
#pragma unroll
    for (int j = 0; j < 4; j++) l2[j] = {0.f, 0.f, 0.f, 0.f};
    const short8* arow = reinterpret_cast<const short8*>(ipab + (size_t)(r0 + mtile * 16 + m) * 1024);
    for (int ks = 0; ks < 32; ks++) {
        short8 a = arow[ks * 4 + quad];
#pragma unroll
        for (int j = 0; j < 4; j++) {
            int nt = par + 4 * j;
            const short8* bp = reinterpret_cast<const short8*>(woT + (size_t)(nt * 16 + m) * 1024);
            l2[j] = __builtin_amdgcn_mfma_f32_16x16x32_bf16(a, bp[ks * 4 + quad], l2[j], 0, 0, 0);
        }
    }
#pragma unroll
    for (int j = 0; j < 4; j++) {
        int colg = (par + 4 * j) * 16 + m;
        float bov = bo[colg];
#pragma unroll
        for (int r = 0; r < 4; r++) {
            int row = mtile * 16 + quad * 4 + r;
            l2[j][r] += dlocal[(size_t)(r0 + row) * 256 + colg] + bov;
        }
    }
    // LN2 stats (4 partials per row)
    {
        float s[4] = {0.f, 0.f, 0.f, 0.f}, ss[4] = {0.f, 0.f, 0.f, 0.f};
#pragma unroll
        for (int j = 0; j < 4; j++)
#pragma unroll
            for (int r = 0; r < 4; r++) { s[r] += l2[j][r]; ss[r] += l2[j][r] * l2[j][r]; }
#pragma unroll
        for (int mask = 1; mask < 16; mask <<= 1)
#pragma unroll
            for (int r = 0; r < 4; r++) { s[r] += __shfl_xor(s[r], mask); ss[r] += __shfl_xor(ss[r], mask); }
        if (m == 0) {
#pragma unroll
            for (int r = 0; r < 4; r++) {
                int row = mtile * 16 + quad * 4 + r;
                statsS[row * 8 + par * 2 + 0] = s[r];
                statsS[row * 8 + par * 2 + 1] = ss[r];
            }
        }
    }
    __syncthreads();
    {
        float mu[4], rs_[4];
#pragma unroll
        for (int r = 0; r < 4; r++) {
            int row = mtile * 16 + quad * 4 + r;
            float S = statsS[row * 8 + 0] + statsS[row * 8 + 2] + statsS[row * 8 + 4] + statsS[row * 8 + 6];
            float SS = statsS[row * 8 + 1] + statsS[row * 8 + 3] + statsS[row * 8 + 5] + statsS[row * 8 + 7];
            float m_ = S * (1.f / 256.f);
            mu[r] = m_;
            rs_[r] = rsqrtf(SS * (1.f / 256.f) - m_ * m_ + 1e-5f);
        }
#pragma unroll
        for (int j = 0; j < 4; j++) {
            int colg = (par + 4 * j) * 16 + m;
            float g = ln2_s[colg], o = ln2_o[colg];
#pragma unroll
            for (int r = 0; r < 4; r++) {
                int row = mtile * 16 + quad * 4 + r;
                xbf[row * 264 + colg] = f2bs((l2[j][r] - mu[r]) * rs_[r] * g + o);
            }
        }
    }
    __syncthreads();
    // GEMM1: x @ [wg|wvm] -> h = gelu(ag)*av  (32 n-tiles, 8 per wave)
    short8 afr[8];
#pragma unroll
    for (int ks = 0; ks < 8; ks++)
        afr[ks] = *reinterpret_cast<const short8*>(&xbf[(mtile * 16 + m) * 264 + ks * 32 + quad * 8]);
    for (int nt = par; nt < 32; nt += 4) {
        floatx4 cg = {0.f, 0.f, 0.f, 0.f};
        floatx4 cv = {0.f, 0.f, 0.f, 0.f};
        const short8* bg = reinterpret_cast<const short8*>(wgT + (size_t)(nt * 16 + m) * 256);
        const short8* bv = reinterpret_cast<const short8*>(wvmT + (size_t)(nt * 16 + m) * 256);
#pragma unroll
        for (int ks = 0; ks < 8; ks++) {
            cg = __builtin_amdgcn_mfma_f32_16x16x32_bf16(afr[ks], bg[ks * 4 + quad], cg, 0, 0, 0);
            cv = __builtin_amdgcn_mfma_f32_16x16x32_bf16(afr[ks], bv[ks * 4 + quad], cv, 0, 0, 0);
        }
#pragma unroll
        for (int r = 0; r < 4; r++) {
            int row = mtile * 16 + quad * 4 + r;
            hbf[row * 520 + nt * 16 + m] = f2bs(gelu_f(cg[r]) * cv[r]);
        }
    }
    __syncthreads();
    // GEMM2: h @ wom; final = l2 + acc  (16 n-tiles, 4 per wave)
    floatx4 acc[4];
#pragma unroll
    for (int j = 0; j < 4; j++) acc[j] = {0.f, 0.f, 0.f, 0.f};
    for (int ks = 0; ks < 16; ks++) {
        short8 a = *reinterpret_cast<const short8*>(&hbf[(mtile * 16 + m) * 520 + ks * 32 + quad * 8]);
#pragma unroll
        for (int j = 0; j < 4; j++) {
            int nt = par + 4 * j;
            const short8* bp = reinterpret_cast<const short8*>(womT + (size_t)(nt * 16 + m) * 512);
            acc[j] = __builtin_amdgcn_mfma_f32_16x16x32_bf16(a, bp[ks * 4 + quad], acc[j], 0, 0, 0);
        }
    }
    // final values: write out_local, keep in regs for LN3
    float fin[4][4];
#pragma unroll
    for (int j = 0; j < 4; j++) {
        int colg = (par + 4 * j) * 16 + m;
#pragma unroll
        for (int r = 0; r < 4; r++) {
            int row = mtile * 16 + quad * 4 + r;
            float fv = l2[j][r] + acc[j][r];
            fin[j][r] = fv;
            dlocal[(size_t)(r0 + row) * 256 + colg] = fv;
        }
    }
    // ---- LN3 stats
    {
        float s[4] = {0.f, 0.f, 0.f, 0.f}, ss[4] = {0.f, 0.f, 0.f, 0.f};
#pragma unroll
        for (int j = 0; j < 4; j++)
#pragma unroll
            for (int r = 0; r < 4; r++) { s[r] += fin[j][r]; ss[r] += fin[j][r] * fin[j][r]; }
#pragma unroll
        for (int mask = 1; mask < 16; mask <<= 1)
#pragma unroll
            for (int r = 0; r < 4; r++) { s[r] += __shfl_xor(s[r], mask); ss[r] += __shfl_xor(ss[r], mask); }
        if (m == 0) {
#pragma unroll
            for (int r = 0; r < 4; r++) {
                int row = mtile * 16 + quad * 4 + r;
                statsS[row * 8 + par * 2 + 0] = s[r];
                statsS[row * 8 + par * 2 + 1] = ss[r];
            }
        }
    }
    __syncthreads();   // also fences hbf reads (GEMM2) before x3F overwrite
    float* x3F = reinterpret_cast<float*>(hbf);   // [32][259] f32 = 33152 B <= 33280 B
    {
        float mu[4], rs_[4];
#pragma unroll
        for (int r = 0; r < 4; r++) {
            int row = mtile * 16 + quad * 4 + r;
            float S = statsS[row * 8 + 0] + statsS[row * 8 + 2] + statsS[row * 8 + 4] + statsS[row * 8 + 6];
            float SS = statsS[row * 8 + 1] + statsS[row * 8 + 3] + statsS[row * 8 + 5] + statsS[row * 8 + 7];
            float m_ = S * (1.f / 256.f);
            mu[r] = m_;
            rs_[r] = rsqrtf(SS * (1.f / 256.f) - m_ * m_ + 1e-5f);
        }
#pragma unroll
        for (int j = 0; j < 4; j++) {
            int colg = (par + 4 * j) * 16 + m;
            float g = ln3_s[colg], o = ln3_o[colg];
#pragma unroll
            for (int r = 0; r < 4; r++) {
                int row = mtile * 16 + quad * 4 + r;
                x3F[row * 259 + colg] = (fin[j][r] - mu[r]) * rs_[r] * g + o;
            }
        }
    }
    __syncthreads();
    // ---- nl = lpw + x3 @ wpos  (480 outputs: row 0..31, e 0..14)
    for (int o = tid; o < 480; o += 512) {
        int row = o & 31, e = o >> 5;
        const float* xr = x3F + row * 259;
        float sum = 0.f;
        for (int f = 0; f < 256; f++) sum += xr[f] * wpos[f * 15 + e];
        nlS[row][e] = lpw[(size_t)(r0 + row) * 15 + e] + sum;
    }
    __syncthreads();
    // ---- frame transform + update_mask
    for (int o = tid; o < 480; o += 512) {
        int row = o & 31, e = o >> 5;
        int rj = r0 + row;
        int a2 = e / 3, ii = e % 3;
        float R0 = Rw[(size_t)rj * 9 + ii * 3 + 0];
        float R1 = Rw[(size_t)rj * 9 + ii * 3 + 1];
        float R2 = Rw[(size_t)rj * 9 + ii * 3 + 2];
        float tt = pos[(size_t)rj * 15 + 3 + ii];
        float np = R0 * nlS[row][a2 * 3 + 0] + R1 * nlS[row][a2 * 3 + 1] + R2 * nlS[row][a2 * 3 + 2] + tt;
        float old = pos[(size_t)rj * 15 + e];
        outp[(size_t)rj * 15 + e] = (umask[rj] != 0) ? np : old;
    }
}

extern "C" void kernel_launch(void* const* d_in, const int* in_sizes, int n_in,
                              void* d_out, int out_size, void* d_ws, size_t ws_size,
                              hipStream_t stream) {
    static const int map_dict[31] = {0, 1, 2, 3, 4, 5, 6, 7, 8, 9, 10, 11, 12, 13, 14, 15,
                                     16, 17, 18, 19, 20, 21, 22, 23, 24, 25, 26, 27, 28, 29, 30};
    static const int map_sig[31] = {0, 1, 25, 26, 27, 28, 29, 30, 2, 3, 4, 5, 6, 7, 8, 9,
                                    10, 11, 12, 13, 14, 15, 16, 17, 18, 19, 20, 21, 22, 23, 24};
    const int* M = (in_sizes[2] == FIN * DMODEL) ? map_sig : map_dict;

    const float* local = (const float*)d_in[M[0]];
    const float* pos = (const float*)d_in[M[1]];
    const int* nbr = (const int*)d_in[M[2]];
    const int* resi = (const int*)d_in[M[3]];
    const int* chain = (const int*)d_in[M[4]];
    const int* batch = (const int*)d_in[M[5]];
    const int* umask = (const int*)d_in[M[6]];
    const int* mask = (const int*)d_in[M[7]];
    const float* w_in = (const float*)d_in[M[8]];
    const float* w_pair = (const float*)d_in[M[9]];
    const float* b_pair = (const float*)d_in[M[10]];
    const float* ln1_s = (const float*)d_in[M[11]];
    const float* ln1_o = (const float*)d_in[M[12]];
    const float* wq = (const float*)d_in[M[13]];
    const float* wk = (const float*)d_in[M[14]];
    const float* wv = (const float*)d_in[M[15]];
    const float* wqp = (const float*)d_in[M[16]];
    const float* wkp = (const float*)d_in[M[17]];
    const float* wvp = (const float*)d_in[M[18]];
    const float* wbm = (const float*)d_in[M[19]];
    const float* gamma = (const float*)d_in[M[20]];
    const float* wo = (const float*)d_in[M[21]];
    const float* bo = (const float*)d_in[M[22]];
    const float* ln2_s = (const float*)d_in[M[23]];
    const float* ln2_o = (const float*)d_in[M[24]];
    const float* wg = (const float*)d_in[M[25]];
    const float* wvm = (const float*)d_in[M[26]];
    const float* wom = (const float*)d_in[M[27]];
    const float* ln3_s = (const float*)d_in[M[28]];
    const float* ln3_o = (const float*)d_in[M[29]];
    const float* wpos = (const float*)d_in[M[30]];

    int N = in_sizes[0] / DMODEL;

    float* out_local = (float*)d_out;
    float* out_pos = out_local + (size_t)N * DMODEL;

    char* wsb = (char*)d_ws;
    float* Rw = (float*)wsb;   wsb += (size_t)N * 9 * 4;
    float* lpw = (float*)wsb;  wsb += (size_t)N * 15 * 4;
    bf16* qbh = (bf16*)wsb;    wsb += (size_t)N * 256 * 2;
    bf16* kvb = (bf16*)wsb;    wsb += (size_t)N * 512 * 2;
    bf16* qpl = (bf16*)wsb;    wsb += (size_t)N * 192 * 2;
    bf16* kpl = (bf16*)wsb;    wsb += (size_t)N * 192 * 2;
    bf16* vpl = (bf16*)wsb;    wsb += (size_t)N * 192 * 2;
    bf16* ipab = (bf16*)wsb;   wsb += (size_t)N * 1024 * 2;
    float* qpg = (float*)wsb;  wsb += (size_t)N * 192 * 4;
    bf16* kvpgh = (bf16*)wsb;  wsb += (size_t)N * 384 * 2;
    unsigned short* wtrans = (unsigned short*)wsb; wsb += (size_t)WT_TOTAL * 2;
    unsigned short* wAllT = wtrans + OFF_WALL;
    unsigned short* woT   = wtrans + OFF_WO;
    unsigned short* wgT   = wtrans + OFF_WG;
    unsigned short* wvmT  = wtrans + OFF_WVM;
    unsigned short* womT  = wtrans + OFF_WOM;
    unsigned short* wpT   = wtrans + OFF_WP;
    unsigned short* winT  = wtrans + OFF_WIN;
    unsigned short* wbmT  = wtrans + OFF_WBM;

    dim3 blk(256);
    dim3 blk512(512);
    hipLaunchKernelGGL(kT, dim3(512), blk, 0, stream, wq, wk, wv, wqp, wkp, wvp,
                       wo, wg, wvm, wom, w_pair, w_in, wbm, wtrans);
    hipLaunchKernelGGL(kB, dim3(N / 32), blk512, 0, stream, local, pos, ln1_s, ln1_o, wAllT, winT,
                       Rw, lpw, out_local, qbh, kvb, qpl, kpl, vpl);
    hipLaunchKernelGGL(kP, dim3(N / 4), blk, 0, stream, qpl, kpl, vpl, Rw, pos, qpg, kvpgh);
    hipLaunchKernelGGL(kC, dim3(N), blk, 0, stream, pos, nbr, resi, chain, batch, mask, Rw,
                       w_pair, wpT, b_pair, wbmT, gamma, qbh, kvb, qpg, kvpgh, ipab, N);
    hipLaunchKernelGGL(kDEF, dim3(N / 32), blk512, 0, stream, ipab, woT, bo, ln2_s, ln2_o,
                       wgT, wvmT, womT, out_local, ln3_s, ln3_o, wpos, lpw, Rw, pos, umask, out_pos);
}

// Round 13
// 587.645 us; speedup vs baseline: 1.1037x; 1.0120x over previous
//
#include <hip/hip_runtime.h>
#include <hip/hip_bf16.h>
#include <math.h>

#define DMODEL 256
#define KNB 32
#define NHEAD 8
#define FIN 95
#define FPD 95        // dense part of pair features
#define KPAD 104      // padded K for pair/feat MFMA staging
#define FOUT 1024
#define DHID 512
#define BTS 36        // BigT kk-stride (pad 32->36: 8B-aligned frags, no 16-way banks)
#define PRS 72        // pairR row stride (144B: 16B-aligned b128 frags)

typedef __hip_bfloat16 bf16;
typedef __attribute__((ext_vector_type(8))) short short8;
typedef __attribute__((ext_vector_type(4))) float floatx4;

__device__ inline float B2F(bf16 x) { return __bfloat162float(x); }
__device__ inline bf16 F2B(float x) { return __float2bfloat16(x); }
__device__ inline unsigned short f2bs(float x) {
    bf16 h = __float2bfloat16(x);
    return *reinterpret_cast<unsigned short*>(&h);
}
__device__ inline float bs2f(short s) {
    return __uint_as_float(((unsigned)(unsigned short)s) << 16);
}

// fast gelu: tanh(y) = 1 - 2/(1+e^{2y}); e^{2y} via __expf (v_exp)
__device__ inline float gelu_f(float x) {
    float u = 1.5957691216057308f * x * (1.f + 0.044715f * x * x);   // 2*0.79788456*(x+0.044715x^3)
    float t = 1.f - 2.f / (1.f + __expf(u));
    return 0.5f * x * (1.f + t);
}

// ---- weight transpose buffer layout (bf16 elements) ----
#define OFF_WALL 0          // [1344][256]  q|k|v|qp|kp|vp columns
#define OFF_WO   344064     // [256][1024]
#define OFF_WG   606208     // [512][256]
#define OFF_WVM  737280     // [512][256]
#define OFF_WOM  868352     // [256][512]
#define OFF_WP   999424     // [64][KPAD]
#define OFF_WIN  1006080    // [256][KPAD]  w_in transposed
#define OFF_WBM  1032704    // [16][64]     wbm transposed (heads 8..15 zero)
#define WT_TOTAL 1033728

// Kernel T: transpose/convert all weights to bf16 [n][k] (k-contiguous)
__global__ __launch_bounds__(256) void kT(const float* __restrict__ wq, const float* __restrict__ wk,
                                          const float* __restrict__ wv, const float* __restrict__ wqp,
                                          const float* __restrict__ wkp, const float* __restrict__ wvp,
                                          const float* __restrict__ wo, const float* __restrict__ wg,
                                          const float* __restrict__ wvm, const float* __restrict__ wom,
                                          const float* __restrict__ w_pair, const float* __restrict__ w_in,
                                          const float* __restrict__ wbm,
                                          unsigned short* __restrict__ wt) {
    int stride = gridDim.x * 256;
    for (int e = blockIdx.x * 256 + threadIdx.x; e < WT_TOTAL; e += stride) {
        float v;
        if (e < OFF_WO) {
            int n = e >> 8, k = e & 255;
            if (n < 256) v = wq[k * 256 + n];
            else if (n < 512) v = wk[k * 256 + n - 256];
            else if (n < 768) v = wv[k * 256 + n - 512];
            else if (n < 960) v = wqp[k * 192 + n - 768];
            else if (n < 1152) v = wkp[k * 192 + n - 960];
            else v = wvp[k * 192 + n - 1152];
        } else if (e < OFF_WG) {
            int u = e - OFF_WO; int n = u >> 10, k = u & 1023;
            v = wo[k * 256 + n];
        } else if (e < OFF_WVM) {
            int u = e - OFF_WG; int n = u >> 8, k = u & 255;
            v = wg[k * 512 + n];
        } else if (e < OFF_WOM) {
            int u = e - OFF_WVM; int n = u >> 8, k = u & 255;
            v = wvm[k * 512 + n];
        } else if (e < OFF_WP) {
            int u = e - OFF_WOM; int n = u >> 9, k = u & 511;
            v = wom[k * 256 + n];
        } else if (e < OFF_WIN) {
            int u = e - OFF_WP; int n = u / KPAD, k = u % KPAD;
            v = (k < FPD) ? w_pair[k * 64 + n] : 0.f;
        } else if (e < OFF_WBM) {
            int u = e - OFF_WIN; int n = u / KPAD, k = u % KPAD;
            v = (k < FIN) ? w_in[k * 256 + n] : 0.f;
        } else {
            int u = e - OFF_WBM; int n = u >> 6, k = u & 63;
            v = (n < NHEAD) ? wbm[k * 8 + n] : 0.f;
        }
        wt[e] = f2bs(v);
    }
}

// Kernel B v5: frames+feat in-block (ex-kA1) + lup GEMM + LN1 + projections + in-block
// point rotation (ex-kP): point-projection columns staged in LDS (union with dead
// featA/xbf), rotated with R from LDS, written directly as qpg (f32) / kvpgh (bf16 rel).
// 32 rows/block, 512 threads (8 waves).
__global__ __launch_bounds__(512) void kB(const float* __restrict__ local,
                                          const float* __restrict__ pos,
                                          const float* __restrict__ ln1_s,
                                          const float* __restrict__ ln1_o,
                                          const unsigned short* __restrict__ wAllT,
                                          const unsigned short* __restrict__ w_inT,
                                          float* __restrict__ Rw,
                                          float* __restrict__ lpw,
                                          float* __restrict__ dlocal,
                                          bf16* __restrict__ qbh, bf16* __restrict__ kvb,
                                          float* __restrict__ qpg,
                                          bf16* __restrict__ kvpgh) {
    int r0 = blockIdx.x * 32;
    int tid = threadIdx.x;
    // featA+xbf die once fa/afr are in registers; ptsS born in the projection epilogue.
    __shared__ __align__(16) union BU {
        struct { unsigned short featA[32 * KPAD]; unsigned short xbf[32 * 264]; } s;  // 23552 B
        unsigned short ptsS[32 * 576];                                                 // 36864 B
    } bu;
    __shared__ float statsS[32 * 8];
    __shared__ float lpS[32][15];
    __shared__ float ddS[32][5], dinvS[32][5];
    __shared__ float RS[32][9];

    // ---- phase A: frames + feat (ex-kA1), 16 threads per residue
    {
        int res = tid >> 4, lt = tid & 15;
        int ri = r0 + res;
        const float* pp = pos + (size_t)ri * 15;
        float nx = pp[0], ny = pp[1], nz = pp[2];
        float cax = pp[3], cay = pp[4], caz = pp[5];
        float cx = pp[6], cy = pp[7], cz = pp[8];
        float e1x = cx - cax, e1y = cy - cay, e1z = cz - caz;
        float inv = rsqrtf(e1x * e1x + e1y * e1y + e1z * e1z + 1e-6f);
        e1x *= inv; e1y *= inv; e1z *= inv;
        float ux = nx - cax, uy = ny - cay, uz = nz - caz;
        float d = ux * e1x + uy * e1y + uz * e1z;
        float wx = ux - d * e1x, wy = uy - d * e1y, wz = uz - d * e1z;
        inv = rsqrtf(wx * wx + wy * wy + wz * wz + 1e-6f);
        float e2x = wx * inv, e2y = wy * inv, e2z = wz * inv;
        float e3x = e1y * e2z - e1z * e2y;
        float e3y = e1z * e2x - e1x * e2z;
        float e3z = e1x * e2y - e1y * e2x;
        float R[9] = {e1x, e2x, e3x, e1y, e2y, e3y, e1z, e2z, e3z};

        if (lt < 9) { Rw[(size_t)ri * 9 + lt] = R[lt]; RS[res][lt] = R[lt]; }
        if (lt < 15) {
            int a = lt / 3, ii = lt % 3;
            float px = pp[a * 3 + 0] - cax, py = pp[a * 3 + 1] - cay, pz = pp[a * 3 + 2] - caz;
            float v = R[0 * 3 + ii] * px + R[1 * 3 + ii] * py + R[2 * 3 + ii] * pz;
            lpS[res][lt] = v;
            lpw[(size_t)ri * 15 + lt] = v;
        }
        __syncthreads();
        if (lt < 5) {
            float s = lpS[res][lt * 3] * lpS[res][lt * 3] + lpS[res][lt * 3 + 1] * lpS[res][lt * 3 + 1] +
                      lpS[res][lt * 3 + 2] * lpS[res][lt * 3 + 2];
            ddS[res][lt] = sqrtf(s + 1e-12f);
            dinvS[res][lt] = rsqrtf(s + 1e-6f);
        }
        __syncthreads();
        for (int e = lt; e < KPAD; e += 16) {
            float v;
            if (e < 15) v = lpS[res][e] * dinvS[res][e / 3];
            else if (e < 95) {
                int u = e - 15, a = u >> 4, b = u & 15;
                float z = (ddS[res][a] - (float)b * (10.f / 15.f)) * (1.f / 0.625f);
                v = __expf(-z * z);
            } else v = 0.f;
            bu.s.featA[res * KPAD + e] = f2bs(v);
        }
    }
    __syncthreads();

    int lane = tid & 63, w = tid >> 6;
    int mtile = w & 1, par = w >> 1;          // par in 0..3
    int m = lane & 15, quad = lane >> 4;

    short8 fa[3];
#pragma unroll
    for (int ks = 0; ks < 3; ks++)
        fa[ks] = *reinterpret_cast<const short8*>(&bu.s.featA[(mtile * 16 + m) * KPAD + ks * 32 + quad * 8]);
    float lupv[4][4];
#pragma unroll
    for (int j = 0; j < 4; j++) {
        int nt = par + 4 * j;
        floatx4 c = {0.f, 0.f, 0.f, 0.f};
        const short8* bp = reinterpret_cast<const short8*>(w_inT + (size_t)(nt * 16 + m) * KPAD);
#pragma unroll
        for (int ks = 0; ks < 3; ks++)
            c = __builtin_amdgcn_mfma_f32_16x16x32_bf16(fa[ks], bp[ks * 4 + quad], c, 0, 0, 0);
        int col = nt * 16 + m;
#pragma unroll
        for (int r = 0; r < 4; r++) {
            int row = mtile * 16 + quad * 4 + r;
            float lv = local[(size_t)(r0 + row) * 256 + col] + c[r];
            lupv[j][r] = lv;
            dlocal[(size_t)(r0 + row) * 256 + col] = lv;
        }
    }
    {
        float s[4] = {0.f, 0.f, 0.f, 0.f}, ss[4] = {0.f, 0.f, 0.f, 0.f};
#pragma unroll
        for (int j = 0; j < 4; j++)
#pragma unroll
            for (int r = 0; r < 4; r++) { s[r] += lupv[j][r]; ss[r] += lupv[j][r] * lupv[j][r]; }
#pragma unroll
        for (int mask = 1; mask < 16; mask <<= 1)
#pragma unroll
            for (int r = 0; r < 4; r++) { s[r] += __shfl_xor(s[r], mask); ss[r] += __shfl_xor(ss[r], mask); }
        if (m == 0) {
#pragma unroll
            for (int r = 0; r < 4; r++) {
                int row = mtile * 16 + quad * 4 + r;
                statsS[row * 8 + par * 2 + 0] = s[r];
                statsS[row * 8 + par * 2 + 1] = ss[r];
            }
        }
    }
    __syncthreads();
    {
        float mu[4], rs_[4];
#pragma unroll
        for (int r = 0; r < 4; r++) {
            int row = mtile * 16 + quad * 4 + r;
            float S = statsS[row * 8 + 0] + statsS[row * 8 + 2] + statsS[row * 8 + 4] + statsS[row * 8 + 6];
            float SS = statsS[row * 8 + 1] + statsS[row * 8 + 3] + statsS[row * 8 + 5] + statsS[row * 8 + 7];
            float m_ = S * (1.f / 256.f);
            mu[r] = m_;
            rs_[r] = rsqrtf(SS * (1.f / 256.f) - m_ * m_ + 1e-5f);
        }
#pragma unroll
        for (int j = 0; j < 4; j++) {
            int col = (par + 4 * j) * 16 + m;
            float g = ln1_s[col], o = ln1_o[col];
#pragma unroll
            for (int r = 0; r < 4; r++) {
                int row = mtile * 16 + quad * 4 + r;
                bu.s.xbf[row * 264 + col] = f2bs((lupv[j][r] - mu[r]) * rs_[r] * g + o);
            }
        }
    }
    __syncthreads();

    short8 afr[8];
#pragma unroll
    for (int ks = 0; ks < 8; ks++)
        afr[ks] = *reinterpret_cast<const short8*>(&bu.s.xbf[(mtile * 16 + m) * 264 + ks * 32 + quad * 8]);
    __syncthreads();   // xbf fully consumed into afr before ptsS (union) is written

    for (int nt = par; nt < 84; nt += 4) {
        floatx4 c = {0.f, 0.f, 0.f, 0.f};
        const short8* bp = reinterpret_cast<const short8*>(wAllT + (size_t)(nt * 16 + m) * 256);
#pragma unroll
        for (int ks = 0; ks < 8; ks++)
            c = __builtin_amdgcn_mfma_f32_16x16x32_bf16(afr[ks], bp[ks * 4 + quad], c, 0, 0, 0);
        int colg = nt * 16 + m;
        if (colg < 256) {
#pragma unroll
            for (int r = 0; r < 4; r++) {
                int rg = r0 + mtile * 16 + quad * 4 + r;
                qbh[(size_t)rg * 256 + colg] = F2B(c[r]);
            }
        } else if (colg < 768) {
            int c0 = colg - 256;
#pragma unroll
            for (int r = 0; r < 4; r++) {
                int rg = r0 + mtile * 16 + quad * 4 + r;
                kvb[(size_t)rg * 512 + c0] = F2B(c[r]);
            }
        } else {
            int c0 = colg - 768;   // 0..575: qp | kp | vp local coords
#pragma unroll
            for (int r = 0; r < 4; r++) {
                int row = mtile * 16 + quad * 4 + r;
                bu.ptsS[row * 576 + c0] = f2bs(c[r]);
            }
        }
    }
    __syncthreads();

    // ---- in-block point rotation (ex-kP): qpg = R*qp + t (f32); kvpgh = R*kp|R*vp (bf16 rel)
    for (int u = tid; u < 32 * 192; u += 512) {
        int r = u / 192, e = u % 192;
        int hp = e / 3, ii = e % 3;
        int ri = r0 + r;
        float R0 = RS[r][ii * 3 + 0];
        float R1 = RS[r][ii * 3 + 1];
        float R2 = RS[r][ii * 3 + 2];
        float tt = pos[(size_t)ri * 15 + 3 + ii];
        int base = hp * 3;
        const unsigned short* pr = &bu.ptsS[r * 576];
        qpg[(size_t)ri * 192 + e] = R0 * bs2f(pr[base]) + R1 * bs2f(pr[base + 1]) + R2 * bs2f(pr[base + 2]) + tt;
        kvpgh[(size_t)ri * 384 + e] =
            F2B(R0 * bs2f(pr[192 + base]) + R1 * bs2f(pr[192 + base + 1]) + R2 * bs2f(pr[192 + base + 2]));
        kvpgh[(size_t)ri * 384 + 192 + e] =
            F2B(R0 * bs2f(pr[384 + base]) + R1 * bs2f(pr[384 + base + 1]) + R2 * bs2f(pr[384 + base + 2]));
    }
}

// Kernel C v6 (unchanged; best measured 216.8-218us at fast clock).
__global__ __launch_bounds__(256, 4) void kC(const float* __restrict__ pos,
                                          const int* __restrict__ nbr,
                                          const int* __restrict__ resi,
                                          const int* __restrict__ chain,
                                          const int* __restrict__ batch,
                                          const int* __restrict__ mask,
                                          const float* __restrict__ Rw,
                                          const float* __restrict__ w_pair,
                                          const unsigned short* __restrict__ wT,
                                          const float* __restrict__ b_pair,
                                          const unsigned short* __restrict__ wbmT,
                                          const float* __restrict__ gamma,
                                          const bf16* __restrict__ qbh,
                                          const bf16* __restrict__ kvb,
                                          const float* __restrict__ qpg,
                                          const bf16* __restrict__ kvpgh,
                                          bf16* __restrict__ ipab,
                                          int N) {
    int i = blockIdx.x;
    int tid = threadIdx.x;
    __shared__ __align__(16) unsigned short BigT[256 * BTS];
    __shared__ __align__(16) unsigned short pairR[32 * PRS];
    __shared__ __align__(16) unsigned short attb[16 * 40];
    __shared__ __align__(16) float qS[256];
    __shared__ __align__(16) float qpS[192];
    __shared__ __align__(16) float pbS[256];     // pb -> logits -> att (f32), all in place
    __shared__ float spS[NHEAD];
    __shared__ float tjS[KNB][3];
    __shared__ float attjS[24];
    __shared__ int idxS[KNB], rpS[KNB], scS[KNB], sbS[KNB], pmS[KNB];
    __shared__ __align__(16) union UShare {
        unsigned short pfA[32 * KPAD];                    // 6656 B, dies after pair MLP
        struct { float ipaS[FOUT]; float optg[192]; } o;  // 4864 B, born at pass-1 extraction
    } uS;

    // ---- top-of-kernel prefetch of the v / vp_rel gathers (v consumed in staging, vp in pass 2)
    int kk_s = tid & 31, seg = tid >> 5;
    int jpre;
    {
        int nb = nbr[(size_t)i * KNB + kk_s];
        jpre = min(max(nb, 0), N - 1);
    }
    short8 pv0, pv1, pv2, pv3, pp0, pp1, pp2;
    {
        const short8* vsrc = reinterpret_cast<const short8*>(kvb + (size_t)jpre * 512 + 256 + seg * 32);
        pv0 = vsrc[0]; pv1 = vsrc[1]; pv2 = vsrc[2]; pv3 = vsrc[3];
        const unsigned short* vpb = reinterpret_cast<const unsigned short*>(kvpgh) + (size_t)jpre * 384 + 192 + seg * 24;
        const short8* vpsrc = reinterpret_cast<const short8*>(vpb);
        pp0 = vpsrc[0]; pp1 = vpsrc[1]; pp2 = vpsrc[2];
    }

    float R[9];
#pragma unroll
    for (int u = 0; u < 9; u++) R[u] = Rw[(size_t)i * 9 + u];
    float t0 = pos[(size_t)i * 15 + 3];
    float t1 = pos[(size_t)i * 15 + 4];
    float t2 = pos[(size_t)i * 15 + 5];

    qS[tid] = B2F(qbh[(size_t)i * 256 + tid]);
    if (tid < 192) qpS[tid] = qpg[(size_t)i * 192 + tid];
    if (tid < NHEAD) spS[tid] = log1pf(__expf(gamma[tid]));
    if (tid < KNB) {
        int nb = nbr[(size_t)i * KNB + tid];
        int j = min(max(nb, 0), N - 1);
        idxS[tid] = j;
        int rp = resi[j] - resi[i];
        rp = min(max(rp, -32), 32) + 32;
        rpS[tid] = rp;
        scS[tid] = (chain[j] == chain[i]) ? 1 : 0;
        sbS[tid] = (batch[j] == batch[i]) ? 1 : 0;
        pmS[tid] = (mask[i] != 0 && mask[j] != 0 && nb >= 0 && batch[j] == batch[i]) ? 1 : 0;
    }
    __syncthreads();
    if (tid < 160) {
        int kk = tid & 31, a = tid >> 5;
        int j = idxS[kk];
        const float* pj = pos + (size_t)j * 15 + a * 3;
        float pj0 = pj[0], pj1 = pj[1], pj2 = pj[2];
        if (a == 1) { tjS[kk][0] = pj0; tjS[kk][1] = pj1; tjS[kk][2] = pj2; }   // t_j = CA of j
        float px = pj0 - t0, py = pj1 - t1, pz = pj2 - t2;
        float r0_ = R[0] * px + R[3] * py + R[6] * pz;
        float r1_ = R[1] * px + R[4] * py + R[7] * pz;
        float r2_ = R[2] * px + R[5] * py + R[8] * pz;
        float s = r0_ * r0_ + r1_ * r1_ + r2_ * r2_;
        float dij = sqrtf(s + 1e-12f);
        float di = 1.f / (dij + 1e-6f);
        uS.pfA[kk * KPAD + a * 3 + 0] = f2bs(r0_ * di);
        uS.pfA[kk * KPAD + a * 3 + 1] = f2bs(r1_ * di);
        uS.pfA[kk * KPAD + a * 3 + 2] = f2bs(r2_ * di);
        for (int b = 0; b < 16; b++) {
            float z = (dij - (float)b * (10.f / 15.f)) * (1.f / 0.625f);
            uS.pfA[kk * KPAD + 15 + a * 16 + b] = f2bs(__expf(-z * z));
        }
    }
    if (tid < KNB) uS.pfA[tid * KPAD + FPD] = 0;
    __syncthreads();

    // ---- pair MLP via MFMA; epilogue writes pairR (row-major)
    {
        int lane = tid & 63;
        int wv = tid >> 6;
        int n0 = wv * 16;
        int mrow = lane & 15;
        int quad = lane >> 4;
        floatx4 c0 = {0.f, 0.f, 0.f, 0.f};
        floatx4 c1 = {0.f, 0.f, 0.f, 0.f};
#pragma unroll
        for (int ks = 0; ks < 3; ks++) {
            int k0 = ks * 32 + quad * 8;
            short8 a0 = *reinterpret_cast<const short8*>(&uS.pfA[mrow * KPAD + k0]);
            short8 a1 = *reinterpret_cast<const short8*>(&uS.pfA[(16 + mrow) * KPAD + k0]);
            short8 bb = *reinterpret_cast<const short8*>(&wT[(n0 + mrow) * KPAD + k0]);
            c0 = __builtin_amdgcn_mfma_f32_16x16x32_bf16(a0, bb, c0, 0, 0, 0);
            c1 = __builtin_amdgcn_mfma_f32_16x16x32_bf16(a1, bb, c1, 0, 0, 0);
        }
        int col = n0 + mrow;
        float bp = b_pair[col];
        float w160 = w_pair[160 * 64 + col];
        float w161 = w_pair[161 * 64 + col];
#pragma unroll
        for (int mt = 0; mt < 2; mt++) {
            floatx4 cc = mt ? c1 : c0;
#pragma unroll
            for (int r = 0; r < 4; r++) {
                int row = mt * 16 + quad * 4 + r;
                float s = cc[r] + bp + w_pair[(95 + rpS[row]) * 64 + col] +
                          (scS[row] ? w160 : 0.f) + (sbS[row] ? w161 : 0.f);
                pairR[row * PRS + col] = f2bs(gelu_f(s));
            }
        }
    }
    __syncthreads();

    // ---- staging phase: prefetch k/kp for logits, write prefetched V to BigT, pb MFMA
    short8 pk0, pk1, pk2, pk3, pq0, pq1, pq2;
    {
        int kk2 = tid >> 3, h2 = tid & 7;
        int j2 = idxS[kk2];
        const short8* ksrc = reinterpret_cast<const short8*>(kvb + (size_t)j2 * 512 + h2 * 32);
        pk0 = ksrc[0]; pk1 = ksrc[1]; pk2 = ksrc[2]; pk3 = ksrc[3];
        const unsigned short* kpb = reinterpret_cast<const unsigned short*>(kvpgh) + (size_t)j2 * 384 + h2 * 24;
        const short8* kpsrc = reinterpret_cast<const short8*>(kpb);
        pq0 = kpsrc[0]; pq1 = kpsrc[1]; pq2 = kpsrc[2];
    }
    {   // V: cols 0..255 (transpose-store the top prefetch)
        int kk = kk_s;
#pragma unroll
        for (int c = 0; c < 8; c++) BigT[(seg * 32 + c) * BTS + kk] = (unsigned short)pv0[c];
#pragma unroll
        for (int c = 0; c < 8; c++) BigT[(seg * 32 + 8 + c) * BTS + kk] = (unsigned short)pv1[c];
#pragma unroll
        for (int c = 0; c < 8; c++) BigT[(seg * 32 + 16 + c) * BTS + kk] = (unsigned short)pv2[c];
#pragma unroll
        for (int c = 0; c < 8; c++) BigT[(seg * 32 + 24 + c) * BTS + kk] = (unsigned short)pv3[c];
    }
    {   // pb = pair @ wbm via MFMA: D[m=kk][n=h], K=64
        int w = tid >> 6;
        if (w < 2) {
            int lane = tid & 63, la = lane & 15, quad = lane >> 4;
            floatx4 c = {0.f, 0.f, 0.f, 0.f};
#pragma unroll
            for (int ks = 0; ks < 2; ks++) {
                short8 a = *reinterpret_cast<const short8*>(&pairR[(w * 16 + la) * PRS + ks * 32 + quad * 8]);
                short8 b = *reinterpret_cast<const short8*>(wbmT + la * 64 + ks * 32 + quad * 8);
                c = __builtin_amdgcn_mfma_f32_16x16x32_bf16(a, b, c, 0, 0, 0);
            }
            if (la < NHEAD) {
#pragma unroll
                for (int r = 0; r < 4; r++)
                    pbS[(w * 16 + quad * 4 + r) * 8 + la] = c[r];
            }
        }
    }
    __syncthreads();

    // ---- logits: qk + d2 from prefetched registers; pb from MFMA; store into pbS in place
    {
        int kk = tid >> 3, h = tid & 7;
        float qk = 0.f;
        const floatx4* qh4 = reinterpret_cast<const floatx4*>(qS + h * 32);
        short8 kvv[4] = {pk0, pk1, pk2, pk3};
#pragma unroll
        for (int e = 0; e < 4; e++) {
            short8 kv = kvv[e];
            floatx4 qa = qh4[2 * e], qb = qh4[2 * e + 1];
            qk += qa[0] * bs2f(kv[0]) + qa[1] * bs2f(kv[1]) + qa[2] * bs2f(kv[2]) + qa[3] * bs2f(kv[3]) +
                  qb[0] * bs2f(kv[4]) + qb[1] * bs2f(kv[5]) + qb[2] * bs2f(kv[6]) + qb[3] * bs2f(kv[7]);
        }
        qk *= 0.17677669529663687f;
        float d2 = 0.f;
        const float* qp = qpS + h * 24;
        float tj[3] = {tjS[kk][0], tjS[kk][1], tjS[kk][2]};
        short8 kpv[3] = {pq0, pq1, pq2};
#pragma unroll
        for (int e8 = 0; e8 < 3; e8++)
#pragma unroll
            for (int c8 = 0; c8 < 8; c8++) {
                int x = e8 * 8 + c8;
                float df = (qp[x] - tj[x % 3]) - bs2f(kpv[e8][c8]);
                d2 += df * df;
            }
        float pb = pbS[kk * 8 + h];
        float lgt = 0.5773502691896258f * (qk + pb - (1.f / 12.f) * spS[h] * d2);
        pbS[kk * 8 + h] = pmS[kk] ? lgt : -1e9f;
    }
    __syncthreads();

    // ---- softmax over kk per head; write att to attb (bf16) AND pbS (f32, for t_j sums)
    if (tid < 64) {
        int h = tid >> 3, sub = tid & 7;
        float m = -INFINITY;
        float lv[4];
#pragma unroll
        for (int q = 0; q < 4; q++) {
            lv[q] = pbS[(sub + 8 * q) * 8 + h];
            m = fmaxf(m, lv[q]);
        }
#pragma unroll
        for (int mk = 1; mk < 8; mk <<= 1) m = fmaxf(m, __shfl_xor(m, mk));
        float s = 0.f, ex[4];
#pragma unroll
        for (int q = 0; q < 4; q++) { ex[q] = __expf(lv[q] - m); s += ex[q]; }
#pragma unroll
        for (int mk = 1; mk < 8; mk <<= 1) s += __shfl_xor(s, mk);
        float invs = 1.f / s;
#pragma unroll
        for (int q = 0; q < 4; q++) {
            int kk = sub + 8 * q;
            float a = pmS[kk] ? ex[q] * invs : 0.f;
            attb[h * 40 + kk] = f2bs(a);
            pbS[kk * 8 + h] = a;
        }
    } else if (tid < 128) {
        int t2 = tid - 64;
        int h2 = 8 + (t2 >> 3);
        int k0 = (t2 & 7) * 4;
#pragma unroll
        for (int q = 0; q < 4; q++) attb[h2 * 40 + k0 + q] = 0;
    }
    __syncthreads();

    int la_ = (tid & 63) & 15, quad_ = (tid & 63) >> 4, w_ = tid >> 6;
    short8 af = *reinterpret_cast<const short8*>(&attb[la_ * 40 + quad_ * 8]);

    // ---- PASS 1: D[16 x 256] = att @ BigT(V); extract o_s diag blocks
#pragma unroll
    for (int n4 = 0; n4 < 4; n4++) {
        int colg = (w_ * 4 + n4) * 16 + la_;
        union { short8 s; unsigned long long u[2]; } bb;
        const unsigned long long* bp = reinterpret_cast<const unsigned long long*>(&BigT[colg * BTS + quad_ * 8]);
        bb.u[0] = bp[0]; bb.u[1] = bp[1];
        floatx4 z = {0.f, 0.f, 0.f, 0.f};
        floatx4 d = __builtin_amdgcn_mfma_f32_16x16x32_bf16(af, bb.s, z, 0, 0, 0);
        int h_req = colg >> 5;
        if (quad_ == (h_req >> 2)) {
#pragma unroll
            for (int r = 0; r < 4; r++)
                if ((h_req & 3) == r) uS.o.ipaS[(h_req << 5) + (colg & 31)] = d[r];
        }
    }
    // att @ t_j (f32): 24 outputs [h][c]
    if (tid < 24) {
        int h = tid / 3, c = tid % 3;
        float s = 0.f;
#pragma unroll
        for (int kk = 0; kk < KNB; kk++) s += pbS[kk * 8 + h] * tjS[kk][c];
        attjS[tid] = s;
    }
    __syncthreads();

    // ---- PASS 2 staging: overwrite BigT cols 0..191 with vp_rel (regs), 192..255 with pair (pairR)
    {
        int kk = kk_s;
#pragma unroll
        for (int c = 0; c < 8; c++) BigT[(seg * 24 + c) * BTS + kk] = (unsigned short)pp0[c];
#pragma unroll
        for (int c = 0; c < 8; c++) BigT[(seg * 24 + 8 + c) * BTS + kk] = (unsigned short)pp1[c];
#pragma unroll
        for (int c = 0; c < 8; c++) BigT[(seg * 24 + 16 + c) * BTS + kk] = (unsigned short)pp2[c];
    }
    // pair transpose, conflict-free mapping: 8 threads/row, 8 cols each (read+write banks spread)
#pragma unroll
    for (int q = 0; q < 8; q++) {
        int row = tid >> 3;                 // 0..31
        int col = (tid & 7) + q * 8;        // 0..63
        BigT[(192 + col) * BTS + row] = pairR[row * PRS + col];
    }
    __syncthreads();

    // ---- PASS 2: D[16 x 256] = att @ BigT(vp|pair); extract optg + o_pr
#pragma unroll
    for (int n4 = 0; n4 < 4; n4++) {
        int colg = (w_ * 4 + n4) * 16 + la_;
        union { short8 s; unsigned long long u[2]; } bb;
        const unsigned long long* bp = reinterpret_cast<const unsigned long long*>(&BigT[colg * BTS + quad_ * 8]);
        bb.u[0] = bp[0]; bb.u[1] = bp[1];
        floatx4 z = {0.f, 0.f, 0.f, 0.f};
        floatx4 d = __builtin_amdgcn_mfma_f32_16x16x32_bf16(af, bb.s, z, 0, 0, 0);
        if (colg < 192) {
            int h_req = colg / 24;
            if (quad_ == (h_req >> 2)) {
#pragma unroll
                for (int r = 0; r < 4; r++)
                    if ((h_req & 3) == r) uS.o.optg[colg] = d[r];
            }
        } else if (quad_ < 2) {
            int c = colg - 192;
#pragma unroll
            for (int r = 0; r < 4; r++)
                uS.o.ipaS[256 + (quad_ * 4 + r) * 64 + c] = d[r];
        }
    }
    __syncthreads();

    // ---- rotate o_pt back to local frame: v = sum(att*vp_rel) + sum(att*t_j) - t_i
    if (tid < 192) {
        int hp = tid / 3, ii = tid % 3;
        int h = hp >> 3;
        float v0 = uS.o.optg[hp * 3 + 0] + attjS[h * 3 + 0] - t0;
        float v1 = uS.o.optg[hp * 3 + 1] + attjS[h * 3 + 1] - t1;
        float v2 = uS.o.optg[hp * 3 + 2] + attjS[h * 3 + 2] - t2;
        uS.o.ipaS[768 + tid] = R[0 + ii] * v0 + R[3 + ii] * v1 + R[6 + ii] * v2;
    }
    __syncthreads();
    if (tid < 64) {
        float a0 = uS.o.ipaS[768 + tid * 3], a1 = uS.o.ipaS[768 + tid * 3 + 1], a2 = uS.o.ipaS[768 + tid * 3 + 2];
        uS.o.ipaS[960 + tid] = sqrtf(a0 * a0 + a1 * a1 + a2 * a2 + 1e-8f);
    }
    __syncthreads();
    for (int u = tid; u < FOUT; u += 256) ipab[(size_t)i * FOUT + u] = F2B(uS.o.ipaS[u]);
}

// Kernel DEF v2 (unchanged): 32 rows/block, 512 threads.
__global__ __launch_bounds__(512) void kDEF(const bf16* __restrict__ ipab,
                                            const unsigned short* __restrict__ woT,
                                            const float* __restrict__ bo,
                                            const float* __restrict__ ln2_s,
                                            const float* __restrict__ ln2_o,
                                            const unsigned short* __restrict__ wgT,
                                            const unsigned short* __restrict__ wvmT,
                                            const unsigned short* __restrict__ womT,
                                            float* __restrict__ dlocal,
                                            const float* __restrict__ ln3_s,
                                            const float* __restrict__ ln3_o,
                                            const float* __restrict__ wpos,
                                            const float* __restrict__ lpw,
                                            const float* __restrict__ Rw,
                                            const float* __restrict__ pos,
                                            const int* __restrict__ umask,
                                            float* __restrict__ outp) {
    int r0 = blockIdx.x * 32;
    int tid = threadIdx.x;
    __shared__ __align__(16) unsigned short xbf[32 * 264];
    __shared__ __align__(16) unsigned short hbf[32 * 520];   // reused as f32 x3F[32][259] after GEMM2
    __shared__ float statsS[32 * 8];
    __shared__ float nlS[32][15];
    int lane = tid & 63, w = tid >> 6;
    int mtile = w & 1, par = w >> 1, m = lane & 15, quad = lane >> 4;   // par in 0..3

    // GEMM0: ipa @ wo; each wave: 4 n-tiles, nt = par + 4j
    floatx4 l2[4];
#pragma unroll
    for (int j = 0; j < 4; j++) l2[j] = {0.f, 0.f, 0.f, 0.f};
    const short8* arow = reinterpret_cast<const short8*>(ipab + (size_t)(r0 + mtile * 16 + m) * 1024);
    for (int ks = 0; ks < 32; ks++) {
        short8 a = arow[ks * 4 + quad];
#pragma unroll
        for (int j = 0; j < 4; j++) {
            int nt = par + 4 * j;
            const short8* bp = reinterpret_cast<const short8*>(woT + (size_t)(nt * 16 + m) * 1024);
            l2[j] = __builtin_amdgcn_mfma_f32_16x16x32_bf16(a, bp[ks * 4 + quad], l2[j], 0, 0, 0);
        }
    }
#pragma unroll
    for (int j = 0; j < 4; j++) {
        int colg = (par + 4 * j) * 16 + m;
        float bov = bo[colg];
#pragma unroll
        for (int r = 0; r < 4; r++) {
            int row = mtile * 16 + quad * 4 + r;
            l2[j][r] += dlocal[(size_t)(r0 + row) * 256 + colg] + bov;
        }
    }
    // LN2 stats (4 partials per row)
    {
        float s[4] = {0.f, 0.f, 0.f, 0.f}, ss[4] = {0.f, 0.f, 0.f, 0.f};
#pragma unroll
        for (int j = 0; j < 4; j++)
#pragma unroll
            for (int r = 0; r < 4; r++) { s[r] += l2[j][r]; ss[r] += l2[j][r] * l2[j][r]; }
#pragma unroll
        for (int mask = 1; mask < 16; mask <<= 1)
#pragma unroll
            for (int r = 0; r < 4; r++) { s[r] += __shfl_xor(s[r], mask); ss[r] += __shfl_xor(ss[r], mask); }
        if (m == 0) {
#pragma unroll
            for (int r = 0; r < 4; r++) {
                int row = mtile * 16 + quad * 4 + r;
                statsS[row * 8 + par * 2 + 0] = s[r];
                statsS[row * 8 + par * 2 + 1] = ss[r];
            }
        }
    }
    __syncthreads();
    {
        float mu[4], rs_[4];
#pragma unroll
        for (int r = 0; r < 4; r++) {
            int row = mtile * 16 + quad * 4 + r;
            float S = statsS[row * 8 + 0] + statsS[row * 8 + 2] + statsS[row * 8 + 4] + statsS[row * 8 + 6];
            float SS = statsS[row * 8 + 1] + statsS[row * 8 + 3] + statsS[row * 8 + 5] + statsS[row * 8 + 7];
            float m_ = S * (1.f / 256.f);
            mu[r] = m_;
            rs_[r] = rsqrtf(SS * (1.f / 256.f) - m_ * m_ + 1e-5f);
        }
#pragma unroll
        for (int j = 0; j < 4; j++) {
            int colg = (par + 4 * j) * 16 + m;
            float g = ln2_s[colg], o = ln2_o[colg];
#pragma unroll
            for (int r = 0; r < 4; r++) {
                int row = mtile * 16 + quad * 4 + r;
                xbf[row * 264 + colg] = f2bs((l2[j][r] - mu[r]) * rs_[r] * g + o);
            }
        }
    }
    __syncthreads();
    // GEMM1: x @ [wg|wvm] -> h = gelu(ag)*av  (32 n-tiles, 8 per wave)
    short8 afr[8];
#pragma unroll
    for (int ks = 0; ks < 8; ks++)
        afr[ks] = *reinterpret_cast<const short8*>(&xbf[(mtile * 16 + m) * 264 + ks * 32 + quad * 8]);
    for (int nt = par; nt < 32; nt += 4) {
        floatx4 cg = {0.f, 0.f, 0.f, 0.f};
        floatx4 cv = {0.f, 0.f, 0.f, 0.f};
        const short8* bg = reinterpret_cast<const short8*>(wgT + (size_t)(nt * 16 + m) * 256);
        const short8* bv = reinterpret_cast<const short8*>(wvmT + (size_t)(nt * 16 + m) * 256);
#pragma unroll
        for (int ks = 0; ks < 8; ks++) {
            cg = __builtin_amdgcn_mfma_f32_16x16x32_bf16(afr[ks], bg[ks * 4 + quad], cg, 0, 0, 0);
            cv = __builtin_amdgcn_mfma_f32_16x16x32_bf16(afr[ks], bv[ks * 4 + quad], cv, 0, 0, 0);
        }
#pragma unroll
        for (int r = 0; r < 4; r++) {
            int row = mtile * 16 + quad * 4 + r;
            hbf[row * 520 + nt * 16 + m] = f2bs(gelu_f(cg[r]) * cv[r]);
        }
    }
    __syncthreads();
    // GEMM2: h @ wom; final = l2 + acc  (16 n-tiles, 4 per wave)
    floatx4 acc[4];
#pragma unroll
    for (int j = 0; j < 4; j++) acc[j] = {0.f, 0.f, 0.f, 0.f};
    for (int ks = 0; ks < 16; ks++) {
        short8 a = *reinterpret_cast<const short8*>(&hbf[(mtile * 16 + m) * 520 + ks * 32 + quad * 8]);
#pragma unroll
        for (int j = 0; j < 4; j++) {
            int nt = par + 4 * j;
            const short8* bp = reinterpret_cast<const short8*>(womT + (size_t)(nt * 16 + m) * 512);
            acc[j] = __builtin_amdgcn_mfma_f32_16x16x32_bf16(a, bp[ks * 4 + quad], acc[j], 0, 0, 0);
        }
    }
    // final values: write out_local, keep in regs for LN3
    float fin[4][4];
#pragma unroll
    for (int j = 0; j < 4; j++) {
        int colg = (par + 4 * j) * 16 + m;
#pragma unroll
        for (int r = 0; r < 4; r++) {
            int row = mtile * 16 + quad * 4 + r;
            float fv = l2[j][r] + acc[j][r];
            fin[j][r] = fv;
            dlocal[(size_t)(r0 + row) * 256 + colg] = fv;
        }
    }
    // ---- LN3 stats
    {
        float s[4] = {0.f, 0.f, 0.f, 0.f}, ss[4] = {0.f, 0.f, 0.f, 0.f};
#pragma unroll
        for (int j = 0; j < 4; j++)
#pragma unroll
            for (int r = 0; r < 4; r++) { s[r] += fin[j][r]; ss[r] += fin[j][r] * fin[j][r]; }
#pragma unroll
        for (int mask = 1; mask < 16; mask <<= 1)
#pragma unroll
            for (int r = 0; r < 4; r++) { s[r] += __shfl_xor(s[r], mask); ss[r] += __shfl_xor(ss[r], mask); }
        if (m == 0) {
#pragma unroll
            for (int r = 0; r < 4; r++) {
                int row = mtile * 16 + quad * 4 + r;
                statsS[row * 8 + par * 2 + 0] = s[r];
                statsS[row * 8 + par * 2 + 1] = ss[r];
            }
        }
    }
    __syncthreads();   // also fences hbf reads (GEMM2) before x3F overwrite
    float* x3F = reinterpret_cast<float*>(hbf);   // [32][259] f32 = 33152 B <= 33280 B
    {
        float mu[4], rs_[4];
#pragma unroll
        for (int r = 0; r < 4; r++) {
            int row = mtile * 16 + quad * 4 + r;
            float S = statsS[row * 8 + 0] + statsS[row * 8 + 2] + statsS[row * 8 + 4] + statsS[row * 8 + 6];
            float SS = statsS[row * 8 + 1] + statsS[row * 8 + 3] + statsS[row * 8 + 5] + statsS[row * 8 + 7];
            float m_ = S * (1.f / 256.f);
            mu[r] = m_;
            rs_[r] = rsqrtf(SS * (1.f / 256.f) - m_ * m_ + 1e-5f);
        }
#pragma unroll
        for (int j = 0; j < 4; j++) {
            int colg = (par + 4 * j) * 16 + m;
            float g = ln3_s[colg], o = ln3_o[colg];
#pragma unroll
            for (int r = 0; r < 4; r++) {
                int row = mtile * 16 + quad * 4 + r;
                x3F[row * 259 + colg] = (fin[j][r] - mu[r]) * rs_[r] * g + o;
            }
        }
    }
    __syncthreads();
    // ---- nl = lpw + x3 @ wpos  (480 outputs: row 0..31, e 0..14)
    for (int o = tid; o < 480; o += 512) {
        int row = o & 31, e = o >> 5;
        const float* xr = x3F + row * 259;
        float sum = 0.f;
        for (int f = 0; f < 256; f++) sum += xr[f] * wpos[f * 15 + e];
        nlS[row][e] = lpw[(size_t)(r0 + row) * 15 + e] + sum;
    }
    __syncthreads();
    // ---- frame transform + update_mask
    for (int o = tid; o < 480; o += 512) {
        int row = o & 31, e = o >> 5;
        int rj = r0 + row;
        int a2 = e / 3, ii = e % 3;
        float R0 = Rw[(size_t)rj * 9 + ii * 3 + 0];
        float R1 = Rw[(size_t)rj * 9 + ii * 3 + 1];
        float R2 = Rw[(size_t)rj * 9 + ii * 3 + 2];
        float tt = pos[(size_t)rj * 15 + 3 + ii];
        float np = R0 * nlS[row][a2 * 3 + 0] + R1 * nlS[row][a2 * 3 + 1] + R2 * nlS[row][a2 * 3 + 2] + tt;
        float old = pos[(size_t)rj * 15 + e];
        outp[(size_t)rj * 15 + e] = (umask[rj] != 0) ? np : old;
    }
}

extern "C" void kernel_launch(void* const* d_in, const int* in_sizes, int n_in,
                              void* d_out, int out_size, void* d_ws, size_t ws_size,
                              hipStream_t stream) {
    static const int map_dict[31] = {0, 1, 2, 3, 4, 5, 6, 7, 8, 9, 10, 11, 12, 13, 14, 15,
                                     16, 17, 18, 19, 20, 21, 22, 23, 24, 25, 26, 27, 28, 29, 30};
    static const int map_sig[31] = {0, 1, 25, 26, 27, 28, 29, 30, 2, 3, 4, 5, 6, 7, 8, 9,
                                    10, 11, 12, 13, 14, 15, 16, 17, 18, 19, 20, 21, 22, 23, 24};
    const int* M = (in_sizes[2] == FIN * DMODEL) ? map_sig : map_dict;

    const float* local = (const float*)d_in[M[0]];
    const float* pos = (const float*)d_in[M[1]];
    const int* nbr = (const int*)d_in[M[2]];
    const int* resi = (const int*)d_in[M[3]];
    const int* chain = (const int*)d_in[M[4]];
    const int* batch = (const int*)d_in[M[5]];
    const int* umask = (const int*)d_in[M[6]];
    const int* mask = (const int*)d_in[M[7]];
    const float* w_in = (const float*)d_in[M[8]];
    const float* w_pair = (const float*)d_in[M[9]];
    const float* b_pair = (const float*)d_in[M[10]];
    const float* ln1_s = (const float*)d_in[M[11]];
    const float* ln1_o = (const float*)d_in[M[12]];
    const float* wq = (const float*)d_in[M[13]];
    const float* wk = (const float*)d_in[M[14]];
    const float* wv = (const float*)d_in[M[15]];
    const float* wqp = (const float*)d_in[M[16]];
    const float* wkp = (const float*)d_in[M[17]];
    const float* wvp = (const float*)d_in[M[18]];
    const float* wbm = (const float*)d_in[M[19]];
    const float* gamma = (const float*)d_in[M[20]];
    const float* wo = (const float*)d_in[M[21]];
    const float* bo = (const float*)d_in[M[22]];
    const float* ln2_s = (const float*)d_in[M[23]];
    const float* ln2_o = (const float*)d_in[M[24]];
    const float* wg = (const float*)d_in[M[25]];
    const float* wvm = (const float*)d_in[M[26]];
    const float* wom = (const float*)d_in[M[27]];
    const float* ln3_s = (const float*)d_in[M[28]];
    const float* ln3_o = (const float*)d_in[M[29]];
    const float* wpos = (const float*)d_in[M[30]];

    int N = in_sizes[0] / DMODEL;

    float* out_local = (float*)d_out;
    float* out_pos = out_local + (size_t)N * DMODEL;

    char* wsb = (char*)d_ws;
    float* Rw = (float*)wsb;   wsb += (size_t)N * 9 * 4;
    float* lpw = (float*)wsb;  wsb += (size_t)N * 15 * 4;
    bf16* qbh = (bf16*)wsb;    wsb += (size_t)N * 256 * 2;
    bf16* kvb = (bf16*)wsb;    wsb += (size_t)N * 512 * 2;
    bf16* ipab = (bf16*)wsb;   wsb += (size_t)N * 1024 * 2;
    float* qpg = (float*)wsb;  wsb += (size_t)N * 192 * 4;
    bf16* kvpgh = (bf16*)wsb;  wsb += (size_t)N * 384 * 2;
    unsigned short* wtrans = (unsigned short*)wsb; wsb += (size_t)WT_TOTAL * 2;
    unsigned short* wAllT = wtrans + OFF_WALL;
    unsigned short* woT   = wtrans + OFF_WO;
    unsigned short* wgT   = wtrans + OFF_WG;
    unsigned short* wvmT  = wtrans + OFF_WVM;
    unsigned short* womT  = wtrans + OFF_WOM;
    unsigned short* wpT   = wtrans + OFF_WP;
    unsigned short* winT  = wtrans + OFF_WIN;
    unsigned short* wbmT  = wtrans + OFF_WBM;

    dim3 blk(256);
    dim3 blk512(512);
    hipLaunchKernelGGL(kT, dim3(512), blk, 0, stream, wq, wk, wv, wqp, wkp, wvp,
                       wo, wg, wvm, wom, w_pair, w_in, wbm, wtrans);
    hipLaunchKernelGGL(kB, dim3(N / 32), blk512, 0, stream, local, pos, ln1_s, ln1_o, wAllT, winT,
                       Rw, lpw, out_local, qbh, kvb, qpg, kvpgh);
    hipLaunchKernelGGL(kC, dim3(N), blk, 0, stream, pos, nbr, resi, chain, batch, mask, Rw,
                       w_pair, wpT, b_pair, wbmT, gamma, qbh, kvb, qpg, kvpgh, ipab, N);
    hipLaunchKernelGGL(kDEF, dim3(N / 32), blk512, 0, stream, ipab, woT, bo, ln2_s, ln2_o,
                       wgT, wvmT, womT, out_local, ln3_s, ln3_o, wpos, lpw, Rw, pos, umask, out_pos);
}

// Round 14
// 585.417 us; speedup vs baseline: 1.1079x; 1.0038x over previous
//
#include <hip/hip_runtime.h>
#include <hip/hip_bf16.h>
#include <math.h>

#define DMODEL 256
#define KNB 32
#define NHEAD 8
#define FIN 95
#define FPD 95        // dense part of pair features
#define KPAD 104      // padded K for pair/feat MFMA staging
#define FOUT 1024
#define DHID 512
#define BTS 36        // BigT kk-stride (pad 32->36: 8B-aligned frags, no 16-way banks)
#define PRS 72        // pairR row stride (144B: 16B-aligned b128 frags)

typedef __hip_bfloat16 bf16;
typedef __attribute__((ext_vector_type(8))) short short8;
typedef __attribute__((ext_vector_type(4))) float floatx4;

__device__ inline float B2F(bf16 x) { return __bfloat162float(x); }
__device__ inline bf16 F2B(float x) { return __float2bfloat16(x); }
__device__ inline unsigned short f2bs(float x) {
    bf16 h = __float2bfloat16(x);
    return *reinterpret_cast<unsigned short*>(&h);
}
__device__ inline float bs2f(short s) {
    return __uint_as_float(((unsigned)(unsigned short)s) << 16);
}

// fast gelu: tanh(y) = 1 - 2/(1+e^{2y}); e^{2y} via __expf (v_exp)
__device__ inline float gelu_f(float x) {
    float u = 1.5957691216057308f * x * (1.f + 0.044715f * x * x);   // 2*0.79788456*(x+0.044715x^3)
    float t = 1.f - 2.f / (1.f + __expf(u));
    return 0.5f * x * (1.f + t);
}

// ---- weight transpose buffer layout (bf16 elements) ----
#define OFF_WALL 0          // [1344][256]  q|k|v|qp|kp|vp columns
#define OFF_WO   344064     // [256][1024]
#define OFF_WG   606208     // [512][256]
#define OFF_WVM  737280     // [512][256]
#define OFF_WOM  868352     // [256][512]
#define OFF_WP   999424     // [64][KPAD]
#define OFF_WIN  1006080    // [256][KPAD]  w_in transposed
#define OFF_WBM  1032704    // [16][64]     wbm transposed (heads 8..15 zero)
#define WT_TOTAL 1033728

// Kernel T: transpose/convert all weights to bf16 [n][k] (k-contiguous)
__global__ __launch_bounds__(256) void kT(const float* __restrict__ wq, const float* __restrict__ wk,
                                          const float* __restrict__ wv, const float* __restrict__ wqp,
                                          const float* __restrict__ wkp, const float* __restrict__ wvp,
                                          const float* __restrict__ wo, const float* __restrict__ wg,
                                          const float* __restrict__ wvm, const float* __restrict__ wom,
                                          const float* __restrict__ w_pair, const float* __restrict__ w_in,
                                          const float* __restrict__ wbm,
                                          unsigned short* __restrict__ wt) {
    int stride = gridDim.x * 256;
    for (int e = blockIdx.x * 256 + threadIdx.x; e < WT_TOTAL; e += stride) {
        float v;
        if (e < OFF_WO) {
            int n = e >> 8, k = e & 255;
            if (n < 256) v = wq[k * 256 + n];
            else if (n < 512) v = wk[k * 256 + n - 256];
            else if (n < 768) v = wv[k * 256 + n - 512];
            else if (n < 960) v = wqp[k * 192 + n - 768];
            else if (n < 1152) v = wkp[k * 192 + n - 960];
            else v = wvp[k * 192 + n - 1152];
        } else if (e < OFF_WG) {
            int u = e - OFF_WO; int n = u >> 10, k = u & 1023;
            v = wo[k * 256 + n];
        } else if (e < OFF_WVM) {
            int u = e - OFF_WG; int n = u >> 8, k = u & 255;
            v = wg[k * 512 + n];
        } else if (e < OFF_WOM) {
            int u = e - OFF_WVM; int n = u >> 8, k = u & 255;
            v = wvm[k * 512 + n];
        } else if (e < OFF_WP) {
            int u = e - OFF_WOM; int n = u >> 9, k = u & 511;
            v = wom[k * 256 + n];
        } else if (e < OFF_WIN) {
            int u = e - OFF_WP; int n = u / KPAD, k = u % KPAD;
            v = (k < FPD) ? w_pair[k * 64 + n] : 0.f;
        } else if (e < OFF_WBM) {
            int u = e - OFF_WIN; int n = u / KPAD, k = u % KPAD;
            v = (k < FIN) ? w_in[k * 256 + n] : 0.f;
        } else {
            int u = e - OFF_WBM; int n = u >> 6, k = u & 63;
            v = (n < NHEAD) ? wbm[k * 8 + n] : 0.f;
        }
        wt[e] = f2bs(v);
    }
}

// Kernel B v5 (unchanged from round 13): frames+feat in-block + lup GEMM + LN1 +
// projections + in-block point rotation. 32 rows/block, 512 threads.
__global__ __launch_bounds__(512) void kB(const float* __restrict__ local,
                                          const float* __restrict__ pos,
                                          const float* __restrict__ ln1_s,
                                          const float* __restrict__ ln1_o,
                                          const unsigned short* __restrict__ wAllT,
                                          const unsigned short* __restrict__ w_inT,
                                          float* __restrict__ Rw,
                                          float* __restrict__ lpw,
                                          float* __restrict__ dlocal,
                                          bf16* __restrict__ qbh, bf16* __restrict__ kvb,
                                          float* __restrict__ qpg,
                                          bf16* __restrict__ kvpgh) {
    int r0 = blockIdx.x * 32;
    int tid = threadIdx.x;
    __shared__ __align__(16) union BU {
        struct { unsigned short featA[32 * KPAD]; unsigned short xbf[32 * 264]; } s;  // 23552 B
        unsigned short ptsS[32 * 576];                                                 // 36864 B
    } bu;
    __shared__ float statsS[32 * 8];
    __shared__ float lpS[32][15];
    __shared__ float ddS[32][5], dinvS[32][5];
    __shared__ float RS[32][9];

    // ---- phase A: frames + feat (ex-kA1), 16 threads per residue
    {
        int res = tid >> 4, lt = tid & 15;
        int ri = r0 + res;
        const float* pp = pos + (size_t)ri * 15;
        float nx = pp[0], ny = pp[1], nz = pp[2];
        float cax = pp[3], cay = pp[4], caz = pp[5];
        float cx = pp[6], cy = pp[7], cz = pp[8];
        float e1x = cx - cax, e1y = cy - cay, e1z = cz - caz;
        float inv = rsqrtf(e1x * e1x + e1y * e1y + e1z * e1z + 1e-6f);
        e1x *= inv; e1y *= inv; e1z *= inv;
        float ux = nx - cax, uy = ny - cay, uz = nz - caz;
        float d = ux * e1x + uy * e1y + uz * e1z;
        float wx = ux - d * e1x, wy = uy - d * e1y, wz = uz - d * e1z;
        inv = rsqrtf(wx * wx + wy * wy + wz * wz + 1e-6f);
        float e2x = wx * inv, e2y = wy * inv, e2z = wz * inv;
        float e3x = e1y * e2z - e1z * e2y;
        float e3y = e1z * e2x - e1x * e2z;
        float e3z = e1x * e2y - e1y * e2x;
        float R[9] = {e1x, e2x, e3x, e1y, e2y, e3y, e1z, e2z, e3z};

        if (lt < 9) { Rw[(size_t)ri * 9 + lt] = R[lt]; RS[res][lt] = R[lt]; }
        if (lt < 15) {
            int a = lt / 3, ii = lt % 3;
            float px = pp[a * 3 + 0] - cax, py = pp[a * 3 + 1] - cay, pz = pp[a * 3 + 2] - caz;
            float v = R[0 * 3 + ii] * px + R[1 * 3 + ii] * py + R[2 * 3 + ii] * pz;
            lpS[res][lt] = v;
            lpw[(size_t)ri * 15 + lt] = v;
        }
        __syncthreads();
        if (lt < 5) {
            float s = lpS[res][lt * 3] * lpS[res][lt * 3] + lpS[res][lt * 3 + 1] * lpS[res][lt * 3 + 1] +
                      lpS[res][lt * 3 + 2] * lpS[res][lt * 3 + 2];
            ddS[res][lt] = sqrtf(s + 1e-12f);
            dinvS[res][lt] = rsqrtf(s + 1e-6f);
        }
        __syncthreads();
        for (int e = lt; e < KPAD; e += 16) {
            float v;
            if (e < 15) v = lpS[res][e] * dinvS[res][e / 3];
            else if (e < 95) {
                int u = e - 15, a = u >> 4, b = u & 15;
                float z = (ddS[res][a] - (float)b * (10.f / 15.f)) * (1.f / 0.625f);
                v = __expf(-z * z);
            } else v = 0.f;
            bu.s.featA[res * KPAD + e] = f2bs(v);
        }
    }
    __syncthreads();

    int lane = tid & 63, w = tid >> 6;
    int mtile = w & 1, par = w >> 1;          // par in 0..3
    int m = lane & 15, quad = lane >> 4;

    short8 fa[3];
#pragma unroll
    for (int ks = 0; ks < 3; ks++)
        fa[ks] = *reinterpret_cast<const short8*>(&bu.s.featA[(mtile * 16 + m) * KPAD + ks * 32 + quad * 8]);
    float lupv[4][4];
#pragma unroll
    for (int j = 0; j < 4; j++) {
        int nt = par + 4 * j;
        floatx4 c = {0.f, 0.f, 0.f, 0.f};
        const short8* bp = reinterpret_cast<const short8*>(w_inT + (size_t)(nt * 16 + m) * KPAD);
#pragma unroll
        for (int ks = 0; ks < 3; ks++)
            c = __builtin_amdgcn_mfma_f32_16x16x32_bf16(fa[ks], bp[ks * 4 + quad], c, 0, 0, 0);
        int col = nt * 16 + m;
#pragma unroll
        for (int r = 0; r < 4; r++) {
            int row = mtile * 16 + quad * 4 + r;
            float lv = local[(size_t)(r0 + row) * 256 + col] + c[r];
            lupv[j][r] = lv;
            dlocal[(size_t)(r0 + row) * 256 + col] = lv;
        }
    }
    {
        float s[4] = {0.f, 0.f, 0.f, 0.f}, ss[4] = {0.f, 0.f, 0.f, 0.f};
#pragma unroll
        for (int j = 0; j < 4; j++)
#pragma unroll
            for (int r = 0; r < 4; r++) { s[r] += lupv[j][r]; ss[r] += lupv[j][r] * lupv[j][r]; }
#pragma unroll
        for (int mask = 1; mask < 16; mask <<= 1)
#pragma unroll
            for (int r = 0; r < 4; r++) { s[r] += __shfl_xor(s[r], mask); ss[r] += __shfl_xor(ss[r], mask); }
        if (m == 0) {
#pragma unroll
            for (int r = 0; r < 4; r++) {
                int row = mtile * 16 + quad * 4 + r;
                statsS[row * 8 + par * 2 + 0] = s[r];
                statsS[row * 8 + par * 2 + 1] = ss[r];
            }
        }
    }
    __syncthreads();
    {
        float mu[4], rs_[4];
#pragma unroll
        for (int r = 0; r < 4; r++) {
            int row = mtile * 16 + quad * 4 + r;
            float S = statsS[row * 8 + 0] + statsS[row * 8 + 2] + statsS[row * 8 + 4] + statsS[row * 8 + 6];
            float SS = statsS[row * 8 + 1] + statsS[row * 8 + 3] + statsS[row * 8 + 5] + statsS[row * 8 + 7];
            float m_ = S * (1.f / 256.f);
            mu[r] = m_;
            rs_[r] = rsqrtf(SS * (1.f / 256.f) - m_ * m_ + 1e-5f);
        }
#pragma unroll
        for (int j = 0; j < 4; j++) {
            int col = (par + 4 * j) * 16 + m;
            float g = ln1_s[col], o = ln1_o[col];
#pragma unroll
            for (int r = 0; r < 4; r++) {
                int row = mtile * 16 + quad * 4 + r;
                bu.s.xbf[row * 264 + col] = f2bs((lupv[j][r] - mu[r]) * rs_[r] * g + o);
            }
        }
    }
    __syncthreads();

    short8 afr[8];
#pragma unroll
    for (int ks = 0; ks < 8; ks++)
        afr[ks] = *reinterpret_cast<const short8*>(&bu.s.xbf[(mtile * 16 + m) * 264 + ks * 32 + quad * 8]);
    __syncthreads();   // xbf fully consumed into afr before ptsS (union) is written

    for (int nt = par; nt < 84; nt += 4) {
        floatx4 c = {0.f, 0.f, 0.f, 0.f};
        const short8* bp = reinterpret_cast<const short8*>(wAllT + (size_t)(nt * 16 + m) * 256);
#pragma unroll
        for (int ks = 0; ks < 8; ks++)
            c = __builtin_amdgcn_mfma_f32_16x16x32_bf16(afr[ks], bp[ks * 4 + quad], c, 0, 0, 0);
        int colg = nt * 16 + m;
        if (colg < 256) {
#pragma unroll
            for (int r = 0; r < 4; r++) {
                int rg = r0 + mtile * 16 + quad * 4 + r;
                qbh[(size_t)rg * 256 + colg] = F2B(c[r]);
            }
        } else if (colg < 768) {
            int c0 = colg - 256;
#pragma unroll
            for (int r = 0; r < 4; r++) {
                int rg = r0 + mtile * 16 + quad * 4 + r;
                kvb[(size_t)rg * 512 + c0] = F2B(c[r]);
            }
        } else {
            int c0 = colg - 768;   // 0..575: qp | kp | vp local coords
#pragma unroll
            for (int r = 0; r < 4; r++) {
                int row = mtile * 16 + quad * 4 + r;
                bu.ptsS[row * 576 + c0] = f2bs(c[r]);
            }
        }
    }
    __syncthreads();

    // ---- in-block point rotation (ex-kP): qpg = R*qp + t (f32); kvpgh = R*kp|R*vp (bf16 rel)
    for (int u = tid; u < 32 * 192; u += 512) {
        int r = u / 192, e = u % 192;
        int hp = e / 3, ii = e % 3;
        int ri = r0 + r;
        float R0 = RS[r][ii * 3 + 0];
        float R1 = RS[r][ii * 3 + 1];
        float R2 = RS[r][ii * 3 + 2];
        float tt = pos[(size_t)ri * 15 + 3 + ii];
        int base = hp * 3;
        const unsigned short* pr = &bu.ptsS[r * 576];
        qpg[(size_t)ri * 192 + e] = R0 * bs2f(pr[base]) + R1 * bs2f(pr[base + 1]) + R2 * bs2f(pr[base + 2]) + tt;
        kvpgh[(size_t)ri * 384 + e] =
            F2B(R0 * bs2f(pr[192 + base]) + R1 * bs2f(pr[192 + base + 1]) + R2 * bs2f(pr[192 + base + 2]));
        kvpgh[(size_t)ri * 384 + 192 + e] =
            F2B(R0 * bs2f(pr[384 + base]) + R1 * bs2f(pr[384 + base + 1]) + R2 * bs2f(pr[384 + base + 2]));
    }
}

// Kernel C v8: v6 structure + LDS diet (pfA unioned with BigT, bf16 qS, packed meta)
// -> 32.6KB LDS -> 5 blocks/CU. launch_bounds kept at (256,4) so VGPR stays ~60
// (r6's regression was the (256,5) VGPR squeeze, not the diet).
__global__ __launch_bounds__(256, 4) void kC(const float* __restrict__ pos,
                                          const int* __restrict__ nbr,
                                          const int* __restrict__ resi,
                                          const int* __restrict__ chain,
                                          const int* __restrict__ batch,
                                          const int* __restrict__ mask,
                                          const float* __restrict__ Rw,
                                          const float* __restrict__ w_pair,
                                          const unsigned short* __restrict__ wT,
                                          const float* __restrict__ b_pair,
                                          const unsigned short* __restrict__ wbmT,
                                          const float* __restrict__ gamma,
                                          const bf16* __restrict__ qbh,
                                          const bf16* __restrict__ kvb,
                                          const float* __restrict__ qpg,
                                          const bf16* __restrict__ kvpgh,
                                          bf16* __restrict__ ipab,
                                          int N) {
    int i = blockIdx.x;
    int tid = threadIdx.x;
    __shared__ __align__(16) union BigU {
        unsigned short pfA[32 * KPAD];      // 6656 B, dies at pair-MLP barrier
        unsigned short BigT[256 * BTS];     // 18432 B, born at staging phase
    } bigU;
    __shared__ __align__(16) unsigned short pairR[32 * PRS];   // 4608 B
    __shared__ __align__(16) unsigned short attb[16 * 40];     // 1280 B
    __shared__ __align__(16) unsigned short qS[256];           // 512 B (bf16)
    __shared__ __align__(16) float qpS[192];                   // 768 B
    __shared__ __align__(16) float pbS[256];                   // 1024 B
    __shared__ float spS[NHEAD];
    __shared__ float tjS[KNB][3];
    __shared__ float attjS[24];
    __shared__ int idxS[KNB];
    __shared__ int metaS[KNB];   // rp | sc<<7 | sb<<8 | pm<<9
    __shared__ __align__(16) struct OutS { float ipaS[FOUT]; float optg[192]; } oS;  // 4864 B

    // ---- top-of-kernel prefetch of the v / vp_rel gathers (v consumed in staging, vp in pass 2)
    int kk_s = tid & 31, seg = tid >> 5;
    int jpre;
    {
        int nb = nbr[(size_t)i * KNB + kk_s];
        jpre = min(max(nb, 0), N - 1);
    }
    short8 pv0, pv1, pv2, pv3, pp0, pp1, pp2;
    {
        const short8* vsrc = reinterpret_cast<const short8*>(kvb + (size_t)jpre * 512 + 256 + seg * 32);
        pv0 = vsrc[0]; pv1 = vsrc[1]; pv2 = vsrc[2]; pv3 = vsrc[3];
        const unsigned short* vpb = reinterpret_cast<const unsigned short*>(kvpgh) + (size_t)jpre * 384 + 192 + seg * 24;
        const short8* vpsrc = reinterpret_cast<const short8*>(vpb);
        pp0 = vpsrc[0]; pp1 = vpsrc[1]; pp2 = vpsrc[2];
    }

    float R[9];
#pragma unroll
    for (int u = 0; u < 9; u++) R[u] = Rw[(size_t)i * 9 + u];
    float t0 = pos[(size_t)i * 15 + 3];
    float t1 = pos[(size_t)i * 15 + 4];
    float t2 = pos[(size_t)i * 15 + 5];

    qS[tid] = reinterpret_cast<const unsigned short*>(qbh)[(size_t)i * 256 + tid];
    if (tid < 192) qpS[tid] = qpg[(size_t)i * 192 + tid];
    if (tid < NHEAD) spS[tid] = log1pf(__expf(gamma[tid]));
    if (tid < KNB) {
        int nb = nbr[(size_t)i * KNB + tid];
        int j = min(max(nb, 0), N - 1);
        idxS[tid] = j;
        int rp = resi[j] - resi[i];
        rp = min(max(rp, -32), 32) + 32;
        int sc = (chain[j] == chain[i]) ? 1 : 0;
        int sb = (batch[j] == batch[i]) ? 1 : 0;
        int pm = (mask[i] != 0 && mask[j] != 0 && nb >= 0 && sb) ? 1 : 0;
        metaS[tid] = rp | (sc << 7) | (sb << 8) | (pm << 9);
    }
    __syncthreads();
    if (tid < 160) {
        int kk = tid & 31, a = tid >> 5;
        int j = idxS[kk];
        const float* pj = pos + (size_t)j * 15 + a * 3;
        float pj0 = pj[0], pj1 = pj[1], pj2 = pj[2];
        if (a == 1) { tjS[kk][0] = pj0; tjS[kk][1] = pj1; tjS[kk][2] = pj2; }   // t_j = CA of j
        float px = pj0 - t0, py = pj1 - t1, pz = pj2 - t2;
        float r0_ = R[0] * px + R[3] * py + R[6] * pz;
        float r1_ = R[1] * px + R[4] * py + R[7] * pz;
        float r2_ = R[2] * px + R[5] * py + R[8] * pz;
        float s = r0_ * r0_ + r1_ * r1_ + r2_ * r2_;
        float dij = sqrtf(s + 1e-12f);
        float di = 1.f / (dij + 1e-6f);
        bigU.pfA[kk * KPAD + a * 3 + 0] = f2bs(r0_ * di);
        bigU.pfA[kk * KPAD + a * 3 + 1] = f2bs(r1_ * di);
        bigU.pfA[kk * KPAD + a * 3 + 2] = f2bs(r2_ * di);
        for (int b = 0; b < 16; b++) {
            float z = (dij - (float)b * (10.f / 15.f)) * (1.f / 0.625f);
            bigU.pfA[kk * KPAD + 15 + a * 16 + b] = f2bs(__expf(-z * z));
        }
    }
    if (tid < KNB) bigU.pfA[tid * KPAD + FPD] = 0;
    __syncthreads();

    // ---- pair MLP via MFMA; epilogue writes pairR (row-major)
    {
        int lane = tid & 63;
        int wv = tid >> 6;
        int n0 = wv * 16;
        int mrow = lane & 15;
        int quad = lane >> 4;
        floatx4 c0 = {0.f, 0.f, 0.f, 0.f};
        floatx4 c1 = {0.f, 0.f, 0.f, 0.f};
#pragma unroll
        for (int ks = 0; ks < 3; ks++) {
            int k0 = ks * 32 + quad * 8;
            short8 a0 = *reinterpret_cast<const short8*>(&bigU.pfA[mrow * KPAD + k0]);
            short8 a1 = *reinterpret_cast<const short8*>(&bigU.pfA[(16 + mrow) * KPAD + k0]);
            short8 bb = *reinterpret_cast<const short8*>(&wT[(n0 + mrow) * KPAD + k0]);
            c0 = __builtin_amdgcn_mfma_f32_16x16x32_bf16(a0, bb, c0, 0, 0, 0);
            c1 = __builtin_amdgcn_mfma_f32_16x16x32_bf16(a1, bb, c1, 0, 0, 0);
        }
        int col = n0 + mrow;
        float bp = b_pair[col];
        float w160 = w_pair[160 * 64 + col];
        float w161 = w_pair[161 * 64 + col];
#pragma unroll
        for (int mt = 0; mt < 2; mt++) {
            floatx4 cc = mt ? c1 : c0;
#pragma unroll
            for (int r = 0; r < 4; r++) {
                int row = mt * 16 + quad * 4 + r;
                int mv = metaS[row];
                float s = cc[r] + bp + w_pair[(95 + (mv & 127)) * 64 + col] +
                          ((mv & 0x80) ? w160 : 0.f) + ((mv & 0x100) ? w161 : 0.f);
                pairR[row * PRS + col] = f2bs(gelu_f(s));
            }
        }
    }
    __syncthreads();

    // ---- staging phase: prefetch k/kp for logits, write prefetched V to BigT, pb MFMA
    short8 pk0, pk1, pk2, pk3, pq0, pq1, pq2;
    {
        int kk2 = tid >> 3, h2 = tid & 7;
        int j2 = idxS[kk2];
        const short8* ksrc = reinterpret_cast<const short8*>(kvb + (size_t)j2 * 512 + h2 * 32);
        pk0 = ksrc[0]; pk1 = ksrc[1]; pk2 = ksrc[2]; pk3 = ksrc[3];
        const unsigned short* kpb = reinterpret_cast<const unsigned short*>(kvpgh) + (size_t)j2 * 384 + h2 * 24;
        const short8* kpsrc = reinterpret_cast<const short8*>(kpb);
        pq0 = kpsrc[0]; pq1 = kpsrc[1]; pq2 = kpsrc[2];
    }
    {   // V: cols 0..255 (transpose-store the top prefetch)
        int kk = kk_s;
#pragma unroll
        for (int c = 0; c < 8; c++) bigU.BigT[(seg * 32 + c) * BTS + kk] = (unsigned short)pv0[c];
#pragma unroll
        for (int c = 0; c < 8; c++) bigU.BigT[(seg * 32 + 8 + c) * BTS + kk] = (unsigned short)pv1[c];
#pragma unroll
        for (int c = 0; c < 8; c++) bigU.BigT[(seg * 32 + 16 + c) * BTS + kk] = (unsigned short)pv2[c];
#pragma unroll
        for (int c = 0; c < 8; c++) bigU.BigT[(seg * 32 + 24 + c) * BTS + kk] = (unsigned short)pv3[c];
    }
    {   // pb = pair @ wbm via MFMA: D[m=kk][n=h], K=64
        int w = tid >> 6;
        if (w < 2) {
            int lane = tid & 63, la = lane & 15, quad = lane >> 4;
            floatx4 c = {0.f, 0.f, 0.f, 0.f};
#pragma unroll
            for (int ks = 0; ks < 2; ks++) {
                short8 a = *reinterpret_cast<const short8*>(&pairR[(w * 16 + la) * PRS + ks * 32 + quad * 8]);
                short8 b = *reinterpret_cast<const short8*>(wbmT + la * 64 + ks * 32 + quad * 8);
                c = __builtin_amdgcn_mfma_f32_16x16x32_bf16(a, b, c, 0, 0, 0);
            }
            if (la < NHEAD) {
#pragma unroll
                for (int r = 0; r < 4; r++)
                    pbS[(w * 16 + quad * 4 + r) * 8 + la] = c[r];
            }
        }
    }
    __syncthreads();

    // ---- logits: qk + d2 from prefetched registers; pb from MFMA; store into pbS in place
    {
        int kk = tid >> 3, h = tid & 7;
        float qk = 0.f;
        const short8* q8 = reinterpret_cast<const short8*>(&qS[h * 32]);
        short8 kvv[4] = {pk0, pk1, pk2, pk3};
#pragma unroll
        for (int e = 0; e < 4; e++) {
            short8 kv = kvv[e];
            short8 qv = q8[e];
            qk += bs2f(qv[0]) * bs2f(kv[0]) + bs2f(qv[1]) * bs2f(kv[1]) +
                  bs2f(qv[2]) * bs2f(kv[2]) + bs2f(qv[3]) * bs2f(kv[3]) +
                  bs2f(qv[4]) * bs2f(kv[4]) + bs2f(qv[5]) * bs2f(kv[5]) +
                  bs2f(qv[6]) * bs2f(kv[6]) + bs2f(qv[7]) * bs2f(kv[7]);
        }
        qk *= 0.17677669529663687f;
        float d2 = 0.f;
        const float* qp = qpS + h * 24;
        float tj[3] = {tjS[kk][0], tjS[kk][1], tjS[kk][2]};
        short8 kpv[3] = {pq0, pq1, pq2};
#pragma unroll
        for (int e8 = 0; e8 < 3; e8++)
#pragma unroll
            for (int c8 = 0; c8 < 8; c8++) {
                int x = e8 * 8 + c8;
                float df = (qp[x] - tj[x % 3]) - bs2f(kpv[e8][c8]);
                d2 += df * df;
            }
        float pb = pbS[kk * 8 + h];
        float lgt = 0.5773502691896258f * (qk + pb - (1.f / 12.f) * spS[h] * d2);
        pbS[kk * 8 + h] = ((metaS[kk] >> 9) & 1) ? lgt : -1e9f;
    }
    __syncthreads();

    // ---- softmax over kk per head; write att to attb (bf16) AND pbS (f32, for t_j sums)
    if (tid < 64) {
        int h = tid >> 3, sub = tid & 7;
        float m = -INFINITY;
        float lv[4];
#pragma unroll
        for (int q = 0; q < 4; q++) {
            lv[q] = pbS[(sub + 8 * q) * 8 + h];
            m = fmaxf(m, lv[q]);
        }
#pragma unroll
        for (int mk = 1; mk < 8; mk <<= 1) m = fmaxf(m, __shfl_xor(m, mk));
        float s = 0.f, ex[4];
#pragma unroll
        for (int q = 0; q < 4; q++) { ex[q] = __expf(lv[q] - m); s += ex[q]; }
#pragma unroll
        for (int mk = 1; mk < 8; mk <<= 1) s += __shfl_xor(s, mk);
        float invs = 1.f / s;
#pragma unroll
        for (int q = 0; q < 4; q++) {
            int kk = sub + 8 * q;
            float a = ((metaS[kk] >> 9) & 1) ? ex[q] * invs : 0.f;
            attb[h * 40 + kk] = f2bs(a);
            pbS[kk * 8 + h] = a;
        }
    } else if (tid < 128) {
        int t2 = tid - 64;
        int h2 = 8 + (t2 >> 3);
        int k0 = (t2 & 7) * 4;
#pragma unroll
        for (int q = 0; q < 4; q++) attb[h2 * 40 + k0 + q] = 0;
    }
    __syncthreads();

    int la_ = (tid & 63) & 15, quad_ = (tid & 63) >> 4, w_ = tid >> 6;
    short8 af = *reinterpret_cast<const short8*>(&attb[la_ * 40 + quad_ * 8]);

    // ---- PASS 1: D[16 x 256] = att @ BigT(V); extract o_s diag blocks
#pragma unroll
    for (int n4 = 0; n4 < 4; n4++) {
        int colg = (w_ * 4 + n4) * 16 + la_;
        union { short8 s; unsigned long long u[2]; } bb;
        const unsigned long long* bp = reinterpret_cast<const unsigned long long*>(&bigU.BigT[colg * BTS + quad_ * 8]);
        bb.u[0] = bp[0]; bb.u[1] = bp[1];
        floatx4 z = {0.f, 0.f, 0.f, 0.f};
        floatx4 d = __builtin_amdgcn_mfma_f32_16x16x32_bf16(af, bb.s, z, 0, 0, 0);
        int h_req = colg >> 5;
        if (quad_ == (h_req >> 2)) {
#pragma unroll
            for (int r = 0; r < 4; r++)
                if ((h_req & 3) == r) oS.ipaS[(h_req << 5) + (colg & 31)] = d[r];
        }
    }
    // att @ t_j (f32): 24 outputs [h][c]
    if (tid < 24) {
        int h = tid / 3, c = tid % 3;
        float s = 0.f;
#pragma unroll
        for (int kk = 0; kk < KNB; kk++) s += pbS[kk * 8 + h] * tjS[kk][c];
        attjS[tid] = s;
    }
    __syncthreads();

    // ---- PASS 2 staging: overwrite BigT cols 0..191 with vp_rel (regs), 192..255 with pair (pairR)
    {
        int kk = kk_s;
#pragma unroll
        for (int c = 0; c < 8; c++) bigU.BigT[(seg * 24 + c) * BTS + kk] = (unsigned short)pp0[c];
#pragma unroll
        for (int c = 0; c < 8; c++) bigU.BigT[(seg * 24 + 8 + c) * BTS + kk] = (unsigned short)pp1[c];
#pragma unroll
        for (int c = 0; c < 8; c++) bigU.BigT[(seg * 24 + 16 + c) * BTS + kk] = (unsigned short)pp2[c];
    }
    // pair transpose, conflict-free mapping: 8 threads/row, 8 cols each (read+write banks spread)
#pragma unroll
    for (int q = 0; q < 8; q++) {
        int row = tid >> 3;                 // 0..31
        int col = (tid & 7) + q * 8;        // 0..63
        bigU.BigT[(192 + col) * BTS + row] = pairR[row * PRS + col];
    }
    __syncthreads();

    // ---- PASS 2: D[16 x 256] = att @ BigT(vp|pair); extract optg + o_pr
#pragma unroll
    for (int n4 = 0; n4 < 4; n4++) {
        int colg = (w_ * 4 + n4) * 16 + la_;
        union { short8 s; unsigned long long u[2]; } bb;
        const unsigned long long* bp = reinterpret_cast<const unsigned long long*>(&bigU.BigT[colg * BTS + quad_ * 8]);
        bb.u[0] = bp[0]; bb.u[1] = bp[1];
        floatx4 z = {0.f, 0.f, 0.f, 0.f};
        floatx4 d = __builtin_amdgcn_mfma_f32_16x16x32_bf16(af, bb.s, z, 0, 0, 0);
        if (colg < 192) {
            int h_req = colg / 24;
            if (quad_ == (h_req >> 2)) {
#pragma unroll
                for (int r = 0; r < 4; r++)
                    if ((h_req & 3) == r) oS.optg[colg] = d[r];
            }
        } else if (quad_ < 2) {
            int c = colg - 192;
#pragma unroll
            for (int r = 0; r < 4; r++)
                oS.ipaS[256 + (quad_ * 4 + r) * 64 + c] = d[r];
        }
    }
    __syncthreads();

    // ---- rotate o_pt back to local frame: v = sum(att*vp_rel) + sum(att*t_j) - t_i
    if (tid < 192) {
        int hp = tid / 3, ii = tid % 3;
        int h = hp >> 3;
        float v0 = oS.optg[hp * 3 + 0] + attjS[h * 3 + 0] - t0;
        float v1 = oS.optg[hp * 3 + 1] + attjS[h * 3 + 1] - t1;
        float v2 = oS.optg[hp * 3 + 2] + attjS[h * 3 + 2] - t2;
        oS.ipaS[768 + tid] = R[0 + ii] * v0 + R[3 + ii] * v1 + R[6 + ii] * v2;
    }
    __syncthreads();
    if (tid < 64) {
        float a0 = oS.ipaS[768 + tid * 3], a1 = oS.ipaS[768 + tid * 3 + 1], a2 = oS.ipaS[768 + tid * 3 + 2];
        oS.ipaS[960 + tid] = sqrtf(a0 * a0 + a1 * a1 + a2 * a2 + 1e-8f);
    }
    __syncthreads();
    for (int u = tid; u < FOUT; u += 256) ipab[(size_t)i * FOUT + u] = F2B(oS.ipaS[u]);
}

// Kernel DEF v2 (unchanged): 32 rows/block, 512 threads.
__global__ __launch_bounds__(512) void kDEF(const bf16* __restrict__ ipab,
                                            const unsigned short* __restrict__ woT,
                                            const float* __restrict__ bo,
                                            const float* __restrict__ ln2_s,
                                            const float* __restrict__ ln2_o,
                                            const unsigned short* __restrict__ wgT,
                                            const unsigned short* __restrict__ wvmT,
                                            const unsigned short* __restrict__ womT,
                                            float* __restrict__ dlocal,
                                            const float* __restrict__ ln3_s,
                                            const float* __restrict__ ln3_o,
                                            const float* __restrict__ wpos,
                                            const float* __restrict__ lpw,
                                            const float* __restrict__ Rw,
                                            const float* __restrict__ pos,
                                            const int* __restrict__ umask,
                                            float* __restrict__ outp) {
    int r0 = blockIdx.x * 32;
    int tid = threadIdx.x;
    __shared__ __align__(16) unsigned short xbf[32 * 264];
    __shared__ __align__(16) unsigned short hbf[32 * 520];   // reused as f32 x3F[32][259] after GEMM2
    __shared__ float statsS[32 * 8];
    __shared__ float nlS[32][15];
    int lane = tid & 63, w = tid >> 6;
    int mtile = w & 1, par = w >> 1, m = lane & 15, quad = lane >> 4;   // par in 0..3

    // GEMM0: ipa @ wo; each wave: 4 n-tiles, nt = par + 4j
    floatx4 l2[4];
#pragma unroll
    for (int j = 0; j < 4; j++) l2[j] = {0.f, 0.f, 0.f, 0.f};
    const short8* arow = reinterpret_cast<const short8*>(ipab + (size_t)(r0 + mtile * 16 + m) * 1024);
    for (int ks = 0; ks < 32; ks++) {
        short8 a = arow[ks * 4 + quad];
#pragma unroll
        for (int j = 0; j < 4; j++) {
            int nt = par + 4 * j;
            const short8* bp = reinterpret_cast<const short8*>(woT + (size_t)(nt * 16 + m) * 1024);
            l2[j] = __builtin_amdgcn_mfma_f32_16x16x32_bf16(a, bp[ks * 4 + quad], l2[j], 0, 0, 0);
        }
    }
#pragma unroll
    for (int j = 0; j < 4; j++) {
        int colg = (par + 4 * j) * 16 + m;
        float bov = bo[colg];
#pragma unroll
        for (int r = 0; r < 4; r++) {
            int row = mtile * 16 + quad * 4 + r;
            l2[j][r] += dlocal[(size_t)(r0 + row) * 256 + colg] + bov;
        }
    }
    // LN2 stats (4 partials per row)
    {
        float s[4] = {0.f, 0.f, 0.f, 0.f}, ss[4] = {0.f, 0.f, 0.f, 0.f};
#pragma unroll
        for (int j = 0; j < 4; j++)
#pragma unroll
            for (int r = 0; r < 4; r++) { s[r] += l2[j][r]; ss[r] += l2[j][r] * l2[j][r]; }
#pragma unroll
        for (int mask = 1; mask < 16; mask <<= 1)
#pragma unroll
            for (int r = 0; r < 4; r++) { s[r] += __shfl_xor(s[r], mask); ss[r] += __shfl_xor(ss[r], mask); }
        if (m == 0) {
#pragma unroll
            for (int r = 0; r < 4; r++) {
                int row = mtile * 16 + quad * 4 + r;
                statsS[row * 8 + par * 2 + 0] = s[r];
                statsS[row * 8 + par * 2 + 1] = ss[r];
            }
        }
    }
    __syncthreads();
    {
        float mu[4], rs_[4];
#pragma unroll
        for (int r = 0; r < 4; r++) {
            int row = mtile * 16 + quad * 4 + r;
            float S = statsS[row * 8 + 0] + statsS[row * 8 + 2] + statsS[row * 8 + 4] + statsS[row * 8 + 6];
            float SS = statsS[row * 8 + 1] + statsS[row * 8 + 3] + statsS[row * 8 + 5] + statsS[row * 8 + 7];
            float m_ = S * (1.f / 256.f);
            mu[r] = m_;
            rs_[r] = rsqrtf(SS * (1.f / 256.f) - m_ * m_ + 1e-5f);
        }
#pragma unroll
        for (int j = 0; j < 4; j++) {
            int colg = (par + 4 * j) * 16 + m;
            float g = ln2_s[colg], o = ln2_o[colg];
#pragma unroll
            for (int r = 0; r < 4; r++) {
                int row = mtile * 16 + quad * 4 + r;
                xbf[row * 264 + colg] = f2bs((l2[j][r] - mu[r]) * rs_[r] * g + o);
            }
        }
    }
    __syncthreads();
    // GEMM1: x @ [wg|wvm] -> h = gelu(ag)*av  (32 n-tiles, 8 per wave)
    short8 afr[8];
#pragma unroll
    for (int ks = 0; ks < 8; ks++)
        afr[ks] = *reinterpret_cast<const short8*>(&xbf[(mtile * 16 + m) * 264 + ks * 32 + quad * 8]);
    for (int nt = par; nt < 32; nt += 4) {
        floatx4 cg = {0.f, 0.f, 0.f, 0.f};
        floatx4 cv = {0.f, 0.f, 0.f, 0.f};
        const short8* bg = reinterpret_cast<const short8*>(wgT + (size_t)(nt * 16 + m) * 256);
        const short8* bv = reinterpret_cast<const short8*>(wvmT + (size_t)(nt * 16 + m) * 256);
#pragma unroll
        for (int ks = 0; ks < 8; ks++) {
            cg = __builtin_amdgcn_mfma_f32_16x16x32_bf16(afr[ks], bg[ks * 4 + quad], cg, 0, 0, 0);
            cv = __builtin_amdgcn_mfma_f32_16x16x32_bf16(afr[ks], bv[ks * 4 + quad], cv, 0, 0, 0);
        }
#pragma unroll
        for (int r = 0; r < 4; r++) {
            int row = mtile * 16 + quad * 4 + r;
            hbf[row * 520 + nt * 16 + m] = f2bs(gelu_f(cg[r]) * cv[r]);
        }
    }
    __syncthreads();
    // GEMM2: h @ wom; final = l2 + acc  (16 n-tiles, 4 per wave)
    floatx4 acc[4];
#pragma unroll
    for (int j = 0; j < 4; j++) acc[j] = {0.f, 0.f, 0.f, 0.f};
    for (int ks = 0; ks < 16; ks++) {
        short8 a = *reinterpret_cast<const short8*>(&hbf[(mtile * 16 + m) * 520 + ks * 32 + quad * 8]);
#pragma unroll
        for (int j = 0; j < 4; j++) {
            int nt = par + 4 * j;
            const short8* bp = reinterpret_cast<const short8*>(womT + (size_t)(nt * 16 + m) * 512);
            acc[j] = __builtin_amdgcn_mfma_f32_16x16x32_bf16(a, bp[ks * 4 + quad], acc[j], 0, 0, 0);
        }
    }
    // final values: write out_local, keep in regs for LN3
    float fin[4][4];
#pragma unroll
    for (int j = 0; j < 4; j++) {
        int colg = (par + 4 * j) * 16 + m;
#pragma unroll
        for (int r = 0; r < 4; r++) {
            int row = mtile * 16 + quad * 4 + r;
            float fv = l2[j][r] + acc[j][r];
            fin[j][r] = fv;
            dlocal[(size_t)(r0 + row) * 256 + colg] = fv;
        }
    }
    // ---- LN3 stats
    {
        float s[4] = {0.f, 0.f, 0.f, 0.f}, ss[4] = {0.f, 0.f, 0.f, 0.f};
#pragma unroll
        for (int j = 0; j < 4; j++)
#pragma unroll
            for (int r = 0; r < 4; r++) { s[r] += fin[j][r]; ss[r] += fin[j][r] * fin[j][r]; }
#pragma unroll
        for (int mask = 1; mask < 16; mask <<= 1)
#pragma unroll
            for (int r = 0; r < 4; r++) { s[r] += __shfl_xor(s[r], mask); ss[r] += __shfl_xor(ss[r], mask); }
        if (m == 0) {
#pragma unroll
            for (int r = 0; r < 4; r++) {
                int row = mtile * 16 + quad * 4 + r;
                statsS[row * 8 + par * 2 + 0] = s[r];
                statsS[row * 8 + par * 2 + 1] = ss[r];
            }
        }
    }
    __syncthreads();   // also fences hbf reads (GEMM2) before x3F overwrite
    float* x3F = reinterpret_cast<float*>(hbf);   // [32][259] f32 = 33152 B <= 33280 B
    {
        float mu[4], rs_[4];
#pragma unroll
        for (int r = 0; r < 4; r++) {
            int row = mtile * 16 + quad * 4 + r;
            float S = statsS[row * 8 + 0] + statsS[row * 8 + 2] + statsS[row * 8 + 4] + statsS[row * 8 + 6];
            float SS = statsS[row * 8 + 1] + statsS[row * 8 + 3] + statsS[row * 8 + 5] + statsS[row * 8 + 7];
            float m_ = S * (1.f / 256.f);
            mu[r] = m_;
            rs_[r] = rsqrtf(SS * (1.f / 256.f) - m_ * m_ + 1e-5f);
        }
#pragma unroll
        for (int j = 0; j < 4; j++) {
            int colg = (par + 4 * j) * 16 + m;
            float g = ln3_s[colg], o = ln3_o[colg];
#pragma unroll
            for (int r = 0; r < 4; r++) {
                int row = mtile * 16 + quad * 4 + r;
                x3F[row * 259 + colg] = (fin[j][r] - mu[r]) * rs_[r] * g + o;
            }
        }
    }
    __syncthreads();
    // ---- nl = lpw + x3 @ wpos  (480 outputs: row 0..31, e 0..14)
    for (int o = tid; o < 480; o += 512) {
        int row = o & 31, e = o >> 5;
        const float* xr = x3F + row * 259;
        float sum = 0.f;
        for (int f = 0; f < 256; f++) sum += xr[f] * wpos[f * 15 + e];
        nlS[row][e] = lpw[(size_t)(r0 + row) * 15 + e] + sum;
    }
    __syncthreads();
    // ---- frame transform + update_mask
    for (int o = tid; o < 480; o += 512) {
        int row = o & 31, e = o >> 5;
        int rj = r0 + row;
        int a2 = e / 3, ii = e % 3;
        float R0 = Rw[(size_t)rj * 9 + ii * 3 + 0];
        float R1 = Rw[(size_t)rj * 9 + ii * 3 + 1];
        float R2 = Rw[(size_t)rj * 9 + ii * 3 + 2];
        float tt = pos[(size_t)rj * 15 + 3 + ii];
        float np = R0 * nlS[row][a2 * 3 + 0] + R1 * nlS[row][a2 * 3 + 1] + R2 * nlS[row][a2 * 3 + 2] + tt;
        float old = pos[(size_t)rj * 15 + e];
        outp[(size_t)rj * 15 + e] = (umask[rj] != 0) ? np : old;
    }
}

extern "C" void kernel_launch(void* const* d_in, const int* in_sizes, int n_in,
                              void* d_out, int out_size, void* d_ws, size_t ws_size,
                              hipStream_t stream) {
    static const int map_dict[31] = {0, 1, 2, 3, 4, 5, 6, 7, 8, 9, 10, 11, 12, 13, 14, 15,
                                     16, 17, 18, 19, 20, 21, 22, 23, 24, 25, 26, 27, 28, 29, 30};
    static const int map_sig[31] = {0, 1, 25, 26, 27, 28, 29, 30, 2, 3, 4, 5, 6, 7, 8, 9,
                                    10, 11, 12, 13, 14, 15, 16, 17, 18, 19, 20, 21, 22, 23, 24};
    const int* M = (in_sizes[2] == FIN * DMODEL) ? map_sig : map_dict;

    const float* local = (const float*)d_in[M[0]];
    const float* pos = (const float*)d_in[M[1]];
    const int* nbr = (const int*)d_in[M[2]];
    const int* resi = (const int*)d_in[M[3]];
    const int* chain = (const int*)d_in[M[4]];
    const int* batch = (const int*)d_in[M[5]];
    const int* umask = (const int*)d_in[M[6]];
    const int* mask = (const int*)d_in[M[7]];
    const float* w_in = (const float*)d_in[M[8]];
    const float* w_pair = (const float*)d_in[M[9]];
    const float* b_pair = (const float*)d_in[M[10]];
    const float* ln1_s = (const float*)d_in[M[11]];
    const float* ln1_o = (const float*)d_in[M[12]];
    const float* wq = (const float*)d_in[M[13]];
    const float* wk = (const float*)d_in[M[14]];
    const float* wv = (const float*)d_in[M[15]];
    const float* wqp = (const float*)d_in[M[16]];
    const float* wkp = (const float*)d_in[M[17]];
    const float* wvp = (const float*)d_in[M[18]];
    const float* wbm = (const float*)d_in[M[19]];
    const float* gamma = (const float*)d_in[M[20]];
    const float* wo = (const float*)d_in[M[21]];
    const float* bo = (const float*)d_in[M[22]];
    const float* ln2_s = (const float*)d_in[M[23]];
    const float* ln2_o = (const float*)d_in[M[24]];
    const float* wg = (const float*)d_in[M[25]];
    const float* wvm = (const float*)d_in[M[26]];
    const float* wom = (const float*)d_in[M[27]];
    const float* ln3_s = (const float*)d_in[M[28]];
    const float* ln3_o = (const float*)d_in[M[29]];
    const float* wpos = (const float*)d_in[M[30]];

    int N = in_sizes[0] / DMODEL;

    float* out_local = (float*)d_out;
    float* out_pos = out_local + (size_t)N * DMODEL;

    char* wsb = (char*)d_ws;
    float* Rw = (float*)wsb;   wsb += (size_t)N * 9 * 4;
    float* lpw = (float*)wsb;  wsb += (size_t)N * 15 * 4;
    bf16* qbh = (bf16*)wsb;    wsb += (size_t)N * 256 * 2;
    bf16* kvb = (bf16*)wsb;    wsb += (size_t)N * 512 * 2;
    bf16* ipab = (bf16*)wsb;   wsb += (size_t)N * 1024 * 2;
    float* qpg = (float*)wsb;  wsb += (size_t)N * 192 * 4;
    bf16* kvpgh = (bf16*)wsb;  wsb += (size_t)N * 384 * 2;
    unsigned short* wtrans = (unsigned short*)wsb; wsb += (size_t)WT_TOTAL * 2;
    unsigned short* wAllT = wtrans + OFF_WALL;
    unsigned short* woT   = wtrans + OFF_WO;
    unsigned short* wgT   = wtrans + OFF_WG;
    unsigned short* wvmT  = wtrans + OFF_WVM;
    unsigned short* womT  = wtrans + OFF_WOM;
    unsigned short* wpT   = wtrans + OFF_WP;
    unsigned short* winT  = wtrans + OFF_WIN;
    unsigned short* wbmT  = wtrans + OFF_WBM;

    dim3 blk(256);
    dim3 blk512(512);
    hipLaunchKernelGGL(kT, dim3(512), blk, 0, stream, wq, wk, wv, wqp, wkp, wvp,
                       wo, wg, wvm, wom, w_pair, w_in, wbm, wtrans);
    hipLaunchKernelGGL(kB, dim3(N / 32), blk512, 0, stream, local, pos, ln1_s, ln1_o, wAllT, winT,
                       Rw, lpw, out_local, qbh, kvb, qpg, kvpgh);
    hipLaunchKernelGGL(kC, dim3(N), blk, 0, stream, pos, nbr, resi, chain, batch, mask, Rw,
                       w_pair, wpT, b_pair, wbmT, gamma, qbh, kvb, qpg, kvpgh, ipab, N);
    hipLaunchKernelGGL(kDEF, dim3(N / 32), blk512, 0, stream, ipab, woT, bo, ln2_s, ln2_o,
                       wgT, wvmT, womT, out_local, ln3_s, ln3_o, wpos, lpw, Rw, pos, umask, out_pos);
}